// Round 8
// baseline (761.870 us; speedup 1.0000x reference)
//
#include <hip/hip_runtime.h>

#define DEV __device__ __forceinline__

typedef __attribute__((ext_vector_type(8))) short short8;
typedef __attribute__((ext_vector_type(4))) float f32x4;

// WAGE quantizer: clip(round(x*128)/128, +-127/128). rintf = RNE = jnp.round.
DEV float wq8(float x) {
    float q = rintf(x * 128.0f) * 0.0078125f;
    return fminf(fmaxf(q, -0.9921875f), 0.9921875f);
}
DEV unsigned short f2bf(float x) {
    unsigned u = __float_as_uint(x);
    return (unsigned short)((u + 0x7FFFu + ((u >> 16) & 1u)) >> 16);
}
DEV float bf2f(unsigned short h) { return __uint_as_float(((unsigned)h) << 16); }
DEV unsigned encf(float f) { unsigned u = __float_as_uint(f); return (u & 0x80000000u) ? ~u : (u | 0x80000000u); }
DEV float decf(unsigned u) { return (u & 0x80000000u) ? __uint_as_float(u ^ 0x80000000u) : __uint_as_float(~u); }

// async global->LDS, 16B per lane, dest = uniform base + lane*16 (linear)
#define GLOAD16(g, l) __builtin_amdgcn_global_load_lds( \
    (const __attribute__((address_space(1))) void*)(g), \
    (__attribute__((address_space(3))) void*)(l), 16, 0, 0)

// ---------------- fused weight pack (all 11 layers, one launch) ----------------
// Layout: dst[(((ch32*K2)+kpos)*noct + oct)*64 + lane]; element e of group g (lane>>4)
// = cin ch32*32 + g*8 + e; oc = oct*16 + (lane&15). oc >= OC0+OC1 -> 0; cin >= CinT -> 0.
// hi|lo duplicated sources: CinT == 2*CinW, cin >= CinW reads cin-CinW.
struct PackDesc {
    const float* w0; const float* w1; uint4* dst;
    int OC0, OC1, CinW, CinT, K, nch32, noct, nthreads;
};
struct PackArgs { PackDesc d[11]; int bofs[12]; };

__global__ void __launch_bounds__(256) k_packall(PackArgs a) {
    const int b = blockIdx.x;
    int i = 0;
    #pragma unroll
    for (int j = 1; j < 11; ++j) if (b >= a.bofs[j]) i = j;
    const PackDesc D = a.d[i];
    const int gi = (b - a.bofs[i]) * 256 + threadIdx.x;
    if (gi >= D.nthreads) return;
    const int K2 = D.K * D.K;
    const int lane = gi & 63; int t = gi >> 6;
    const int oct = t % D.noct; t /= D.noct;
    const int kpos = t % K2; const int ch32 = t / K2;
    const int kh = kpos / D.K, kw = kpos % D.K;
    const int oc = oct * 16 + (lane & 15), g = lane >> 4;
    const float* src = nullptr; int oci = 0;
    if (oc < D.OC0) { src = D.w0; oci = oc; }
    else if (oc < D.OC0 + D.OC1) { src = D.w1; oci = oc - D.OC0; }
    unsigned short h[8];
    #pragma unroll
    for (int e = 0; e < 8; ++e) {
        const int cin = ch32 * 32 + g * 8 + e;
        float v = 0.f;
        if (src != nullptr && cin < D.CinT) {
            const int cw = (cin >= D.CinW) ? cin - D.CinW : cin;
            v = wq8(src[((size_t)(oci * D.CinW + cw) * D.K + kh) * D.K + kw]);
        }
        h[e] = f2bf(v);
    }
    uint4 u;
    u.x = h[0] | ((unsigned)h[1] << 16); u.y = h[2] | ((unsigned)h[3] << 16);
    u.z = h[4] | ((unsigned)h[5] << 16); u.w = h[6] | ((unsigned)h[7] << 16);
    D.dst[gi] = u;
}

// ---------------- conv1: LDS-tiled vector conv (exact fmaf chain preserved) ----------------
__global__ void __launch_bounds__(256) k_conv1(const float* __restrict__ x, const float* __restrict__ w1,
                                               unsigned short* __restrict__ cat1) {
    __shared__ float sw2[36][64];
    __shared__ float sin_[4][17][17];
    const int tid = threadIdx.x;
    const int n = blockIdx.y;
    const int oh0 = (blockIdx.x >> 4) * 8, ow0 = (blockIdx.x & 15) * 8;
    for (int i = tid; i < 2304; i += 256) sw2[i % 36][i / 36] = wq8(w1[i]);
    const int ih0 = oh0 * 2 - 1, iw0 = ow0 * 2 - 1;
    for (int i = tid; i < 4 * 289; i += 256) {
        const int c = i / 289, rem = i % 289, r = rem / 17, cc = rem % 17;
        const int ih = ih0 + r, iw = iw0 + cc;
        float v = 0.f;
        if ((unsigned)ih < 256u && (unsigned)iw < 256u) v = x[((size_t)(n * 4 + c) * 256 + ih) * 256 + iw];
        sin_[c][r][cc] = v;
    }
    __syncthreads();
    const int sp = tid & 63, ocg = tid >> 6;
    const int oh = sp >> 3, ow = sp & 7;
    float acc[16];
    #pragma unroll
    for (int j = 0; j < 16; ++j) acc[j] = 0.f;
    #pragma unroll
    for (int c = 0; c < 4; ++c)
    #pragma unroll
    for (int kh = 0; kh < 3; ++kh)
    #pragma unroll
    for (int kw = 0; kw < 3; ++kw) {
        const float v = sin_[c][oh * 2 + kh][ow * 2 + kw];
        const float4* wp4 = (const float4*)&sw2[c * 9 + kh * 3 + kw][ocg * 16];
        #pragma unroll
        for (int q = 0; q < 4; ++q) {
            const float4 wv = wp4[q];
            acc[q * 4 + 0] = fmaf(v, wv.x, acc[q * 4 + 0]);
            acc[q * 4 + 1] = fmaf(v, wv.y, acc[q * 4 + 1]);
            acc[q * 4 + 2] = fmaf(v, wv.z, acc[q * 4 + 2]);
            acc[q * 4 + 3] = fmaf(v, wv.w, acc[q * 4 + 3]);
        }
    }
    const size_t pix = ((size_t)(n * 128) + oh0 + oh) * 128 + ow0 + ow;
    unsigned uo[8];
    #pragma unroll
    for (int j = 0; j < 8; ++j)
        uo[j] = (unsigned)f2bf(wq8(acc[2 * j])) | ((unsigned)f2bf(wq8(acc[2 * j + 1])) << 16);
    uint4* dp = (uint4*)(cat1 + pix * 104 + ocg * 16);
    uint4 a0; a0.x = uo[0]; a0.y = uo[1]; a0.z = uo[2]; a0.w = uo[3];
    uint4 a1; a1.x = uo[4]; a1.y = uo[5]; a1.z = uo[6]; a1.w = uo[7];
    dp[0] = a0; dp[1] = a1;
}

// feat init + device zero-page
__global__ void k_init(unsigned* __restrict__ feat, uint4* __restrict__ zbuf) {
    feat[threadIdx.x] = encf(-2.0f);
    if (threadIdx.x < 64) { uint4 z; z.x = z.y = z.z = z.w = 0u; zbuf[threadIdx.x] = z; }
}

__global__ void k_fc(const unsigned* __restrict__ feat, const float* __restrict__ wfc,
                     float* __restrict__ out) {
    int n = threadIdx.x;
    if (n < 8) {
        float s = 0.f;
        for (int c = 0; c < 32; ++c) s += decf(feat[n * 32 + c]) * wq8(wfc[c]);
        out[n] = wq8(s);
    }
}

// ---------------- implicit-GEMM MFMA conv ----------------
// 1D grid, XCD-chunk swizzle: work = (b&7)*swzq + (b>>3) (total % 8 == 0).
// Work order: ocg innermost, then tile, then n.
// LDS layout: pixel stride UPPS = UPP+1 units (16B each); unit u of pixel pix at slot
// pix*UPPS + u (pad slot u==UPP loads zbuf). Consecutive pixels are 144B/80B apart ->
// bank-spread without XOR; read address = lane base(am,s) + compile-time imm per kpos.
// Staging: gload_lds linear dest, NBUF-deep counted-vmcnt pipeline (never 0 mid-loop).
// MODE 0: dst[pix*dstr+dch+oc]=bf16(wq8(y)); MODE 1: v=(1-wq8(y))*res -> dstf(f32,512)
// and dsthl hi/lo (stride 1024); MODE 2 (requires WN==1): feat = max over spatial.
template<int K, int STR, int WM, int WN, int BN, int CHQ, int NBUF, int MODE, int RESF>
__global__ void __launch_bounds__(256) k_mconv(
    const unsigned short* __restrict__ s0, int Ctot, int st0,
    int S, int padeff,
    const uint4* __restrict__ wqp, int noct,
    unsigned short* __restrict__ dst, int dstr, int dch,
    float* __restrict__ dstf, unsigned short* __restrict__ dsthl,
    const void* __restrict__ res, int rstr,
    unsigned* __restrict__ feat,
    const unsigned short* __restrict__ zbuf,
    int OCv, int OH, int OW, int TILES_W, int nch,
    int NT, int NOCG, int swzq)
{
    constexpr int TH = WM * 4;
    constexpr int RH = (TH - 1) * STR + K, RW = 7 * STR + K;
    constexpr int UPP = CHQ / 2, UPPS = UPP + 1, NSL = CHQ / 8;
    constexpr int K2 = K * K;
    constexpr int NUS = RH * RW * UPPS;
    constexpr int ROUNDS = (NUS + 255) / 256;
    constexpr int NUPS = ROUNDS * 256;
    constexpr int AHEAD = NBUF - 1;
    __shared__ uint4 lds[NBUF * NUPS];
    __shared__ float sred[4][2][16];

    const int tid = threadIdx.x, lane = tid & 63, w = tid >> 6;
    const int wm = w % WM, wn = w / WM;
    const int l15 = lane & 15, g = lane >> 4;

    const int b = blockIdx.x;
    const int work = (b & 7) * swzq + (b >> 3);
    const int ocg = work % NOCG; const int t2 = work / NOCG;
    const int tile = t2 % NT; const int n = t2 / NT;

    const int tileh = tile / TILES_W, tilew = tile % TILES_W;
    const int oh0 = tileh * TH, ow0 = tilew * 8;
    const int ih0 = oh0 * STR - padeff, iw0 = ow0 * STR - padeff;
    const int blk_oct0 = ocg * (WN * BN);

    // per-am lane pixel base (for A reads)
    int pixb[2];
    #pragma unroll
    for (int am = 0; am < 2; ++am) {
        const int sp = wm * 32 + am * 16 + l15;
        pixb[am] = ((sp >> 3) * STR) * RW + (sp & 7) * STR;
    }

    f32x4 acc[2][BN];
    #pragma unroll
    for (int am = 0; am < 2; ++am)
        #pragma unroll
        for (int bn = 0; bn < BN; ++bn) acc[am][bn] = (f32x4){0.f, 0.f, 0.f, 0.f};

    auto issue = [&](int ch, int buf) {
        uint4* lb = &lds[buf * NUPS];
        #pragma unroll
        for (int rd = 0; rd < ROUNDS; ++rd) {
            const int d = rd * 256 + tid;
            const unsigned short* gp = zbuf;
            if (d < NUS) {
                const int pix = d / UPPS;
                const int u = d - pix * UPPS;
                const int r = pix / RW, c = pix - r * RW;
                const int ih = ih0 + r, iw = iw0 + c;
                const int cin = ch * (CHQ * 4) + u * 8;
                if (u < UPP && (unsigned)ih < (unsigned)S && (unsigned)iw < (unsigned)S && cin < Ctot)
                    gp = s0 + (((size_t)n * S + ih) * S + iw) * st0 + cin;
            }
            GLOAD16(gp, lb + rd * 256 + (tid & ~63));
        }
    };

    #pragma unroll
    for (int i = 0; i < AHEAD; ++i) if (i < nch) issue(i, i % NBUF);

    for (int ch = 0; ch < nch; ++ch) {
        if (ch + AHEAD < nch) issue(ch + AHEAD, (ch + AHEAD) % NBUF);
        const int infl = (nch - 1 - ch < AHEAD) ? nch - 1 - ch : AHEAD;
        if (infl >= 2)      __builtin_amdgcn_s_waitcnt(0xF70 | (2 * ROUNDS));
        else if (infl == 1) __builtin_amdgcn_s_waitcnt(0xF70 | ROUNDS);
        else                __builtin_amdgcn_s_waitcnt(0xF70);
        __builtin_amdgcn_s_barrier();
        __builtin_amdgcn_sched_barrier(0);
        const int bufo = (ch % NBUF) * NUPS;
        #pragma unroll
        for (int s = 0; s < NSL; ++s) {
            const int ch32 = ch * NSL + s;
            const int pb0 = bufo + pixb[0] * UPPS + s * 4 + g;
            const int pb1 = bufo + pixb[1] * UPPS + s * 4 + g;
            const size_t wbase = ((size_t)ch32 * K2 * noct + blk_oct0 + wn * BN) * 64 + lane;
            #pragma unroll
            for (int kpos = 0; kpos < K2; ++kpos) {
                const int kh = kpos / K, kw = kpos % K;
                const int po = (kh * RW + kw) * UPPS;
                short8 bfr[BN];
                #pragma unroll
                for (int bn = 0; bn < BN; ++bn) {
                    union { uint4 u; short8 v; } bu;
                    bu.u = wqp[wbase + ((size_t)kpos * noct + bn) * 64];
                    bfr[bn] = bu.v;
                }
                union { uint4 u; short8 v; } a0, a1;
                a0.u = lds[pb0 + po];
                a1.u = lds[pb1 + po];
                #pragma unroll
                for (int bn = 0; bn < BN; ++bn) {
                    acc[0][bn] = __builtin_amdgcn_mfma_f32_16x16x32_bf16(a0.v, bfr[bn], acc[0][bn], 0, 0, 0);
                    acc[1][bn] = __builtin_amdgcn_mfma_f32_16x16x32_bf16(a1.v, bfr[bn], acc[1][bn], 0, 0, 0);
                }
            }
        }
        __builtin_amdgcn_sched_barrier(0);
        __builtin_amdgcn_s_barrier();
    }

    if (MODE == 2) {
        #pragma unroll
        for (int bn = 0; bn < BN; ++bn) {
            float m = -2.0f;
            #pragma unroll
            for (int am = 0; am < 2; ++am)
                #pragma unroll
                for (int rg = 0; rg < 4; ++rg) {
                    const int sp = wm * 32 + am * 16 + g * 4 + rg;
                    const int oh = oh0 + (sp >> 3), ow = ow0 + (sp & 7);
                    const float v = (oh < OH && ow < OW) ? wq8(acc[am][bn][rg]) : -2.0f;
                    m = fmaxf(m, v);
                }
            m = fmaxf(m, __shfl_xor(m, 16));
            m = fmaxf(m, __shfl_xor(m, 32));
            if (lane < 16) sred[w][bn][l15] = m;
        }
        __syncthreads();
        if (tid < BN * 16) {
            const int bn = tid >> 4, l = tid & 15;
            float mm = sred[0][bn][l];
            #pragma unroll
            for (int i = 1; i < WM * WN; ++i) mm = fmaxf(mm, sred[i][bn][l]);
            atomicMax(&feat[n * 32 + (blk_oct0 + bn) * 16 + l], encf(mm));
        }
    } else {
        #pragma unroll
        for (int am = 0; am < 2; ++am)
        #pragma unroll
        for (int bn = 0; bn < BN; ++bn)
        #pragma unroll
        for (int rg = 0; rg < 4; ++rg) {
            const int sp = wm * 32 + am * 16 + g * 4 + rg;
            const int oh = oh0 + (sp >> 3), ow = ow0 + (sp & 7);
            const int oc = (blk_oct0 + wn * BN + bn) * 16 + l15;
            if (oh < OH && ow < OW && oc < OCv) {
                const size_t pixo = (size_t)(n * OH + oh) * OW + ow;
                const float y = wq8(acc[am][bn][rg]);
                if (MODE == 0) {
                    dst[pixo * dstr + dch + oc] = f2bf(y);
                } else {
                    const float rv = (RESF == 1) ? bf2f(((const unsigned short*)res)[pixo * rstr + oc])
                                                 : ((const float*)res)[pixo * rstr + oc];
                    const float v = (1.0f - y) * rv;
                    if (dstf) dstf[pixo * 512 + oc] = v;
                    const unsigned short hi = f2bf(v);
                    dsthl[pixo * 1024 + oc] = hi;
                    dsthl[pixo * 1024 + 512 + oc] = f2bf(v - bf2f(hi));
                }
            }
        }
    }
}

extern "C" void kernel_launch(void* const* d_in, const int* in_sizes, int n_in,
                              void* d_out, int out_size, void* d_ws, size_t ws_size,
                              hipStream_t stream)
{
    (void)in_sizes; (void)n_in; (void)out_size; (void)ws_size;
    const float* x = (const float*)d_in[0];
    const float* wfc = (const float*)d_in[16];
    float* out = (float*)d_out;

    char* ws = (char*)d_ws;
    size_t off = 0;
    auto alloc = [&](size_t bytes) { char* p = ws + off; off += (bytes + 255) & ~(size_t)255; return p; };

    // pack descriptors: {w0 idx, OC0, w1 idx, OC1, CinW, CinT, K, nch32, noct}
    struct PH { int i0, OC0, i1, OC1, CinW, CinT, K, nch32, noct; };
    static const PH ph[11] = {
        {2, 128, -1, 0,  64,   64, 3,  2,  8},   // 0 conv2
        {3, 256, -1, 0, 128,  128, 3,  4, 16},   // 1 conv3
        {4, 512, -1, 0, 256,  256, 3,  8, 32},   // 2 conv4
        {5, 512, -1, 0, 512,  512, 3, 16, 32},   // 3 r11
        {6, 512, -1, 0, 512,  512, 3, 16, 32},   // 4 r12
        {7, 512, -1, 0, 512, 1024, 3, 32, 32},   // 5 r21 (hi|lo dup)
        {8, 512, -1, 0, 512,  512, 3, 16, 32},   // 6 r22
        {9, 128, 12, 32, 512, 1024, 4, 32, 10},  // 7 L3 = wd3|wu43 (hi|lo dup)
        {10, 64, 13, 32, 416,  416, 4, 13,  6},  // 8 L2 = wd2|wu32
        {11,  4, 14, 32, 224,  224, 4,  7,  3},  // 9 L1 = wd1|wu21 (+4 zero oc)
        {15, 32, -1, 0, 100,  100, 4,  4,  2}};  // 10 u10

    PackArgs pa;
    int bacc = 0;
    uint4* wp[11];
    for (int i = 0; i < 11; ++i) {
        const int nthr = ph[i].K * ph[i].K * ph[i].nch32 * ph[i].noct * 64;
        wp[i] = (uint4*)alloc((size_t)nthr * 16);
        pa.d[i].w0 = (const float*)d_in[ph[i].i0];
        pa.d[i].w1 = (ph[i].i1 >= 0) ? (const float*)d_in[ph[i].i1] : nullptr;
        pa.d[i].dst = wp[i];
        pa.d[i].OC0 = ph[i].OC0; pa.d[i].OC1 = ph[i].OC1;
        pa.d[i].CinW = ph[i].CinW; pa.d[i].CinT = ph[i].CinT;
        pa.d[i].K = ph[i].K; pa.d[i].nch32 = ph[i].nch32; pa.d[i].noct = ph[i].noct;
        pa.d[i].nthreads = nthr;
        pa.bofs[i] = bacc;
        bacc += (nthr + 255) / 256;
    }
    pa.bofs[11] = bacc;

    unsigned short* cat1b = (unsigned short*)alloc((size_t)8*128*128*104 * 2);  // c1|d1|f2|pad4
    unsigned short* cat2b = (unsigned short*)alloc((size_t)8*64*64*224 * 2);    // c2|d2|f3
    unsigned short* cat3b = (unsigned short*)alloc((size_t)8*32*32*416 * 2);    // c3|d3|f4
    unsigned short* c4b   = (unsigned short*)alloc((size_t)8*16*16*512 * 2);
    unsigned short* r11b  = (unsigned short*)alloc((size_t)8*16*16*512 * 2);    // also r21 out
    float*          r12f  = (float*)alloc((size_t)8*16*16*512 * 4);
    unsigned short* r12hl = (unsigned short*)alloc((size_t)8*16*16*1024 * 2);
    unsigned short* r22hl = (unsigned short*)alloc((size_t)8*16*16*1024 * 2);
    unsigned*       featb = (unsigned*)alloc(256 * 4);
    uint4*          zbuf  = (uint4*)alloc(1024);

    k_packall<<<dim3((unsigned)bacc), dim3(256), 0, stream>>>(pa);
    k_init<<<dim3(1), dim3(256), 0, stream>>>(featb, zbuf);
    k_conv1<<<dim3(256, 8), dim3(256), 0, stream>>>(x, (const float*)d_in[1], cat1b);

    const unsigned short* zb = (const unsigned short*)zbuf;

    // conv2: cat1 ch0..64 -> cat2 ch0..128      NT=64 NOCG=2 total=1024
    k_mconv<3,2,2,2,2,8,2,0,0><<<dim3(1024), 256, 0, stream>>>(
        cat1b,64,104, 128,1, wp[0],8,  cat2b,224,0, nullptr,nullptr, nullptr,0, nullptr, zb,
        128,64,64,8, 2, 64,2,128);
    // conv3: cat2 ch0..128 -> cat3 ch0..256     NT=16 NOCG=4 total=512
    k_mconv<3,2,2,2,2,8,2,0,0><<<dim3(512), 256, 0, stream>>>(
        cat2b,128,224, 64,1, wp[1],16, cat3b,416,0, nullptr,nullptr, nullptr,0, nullptr, zb,
        256,32,32,4, 4, 16,4,64);
    // conv4: cat3 ch0..256 -> c4                NT=4 NOCG=16 total=512
    k_mconv<3,2,2,2,1,8,2,0,0><<<dim3(512), 256, 0, stream>>>(
        cat3b,256,416, 32,1, wp[2],32, c4b,512,0, nullptr,nullptr, nullptr,0, nullptr, zb,
        512,16,16,2, 8, 4,16,64);
    // r11                                       NT=4 NOCG=16 total=512
    k_mconv<3,1,2,2,1,16,3,0,0><<<dim3(512), 256, 0, stream>>>(
        c4b,512,512, 16,1, wp[3],32, r11b,512,0, nullptr,nullptr, nullptr,0, nullptr, zb,
        512,16,16,2, 8, 4,16,64);
    // r12 = (1-q(conv(r11)))*c4 -> r12f + r12hl
    k_mconv<3,1,2,2,1,16,3,1,1><<<dim3(512), 256, 0, stream>>>(
        r11b,512,512, 16,1, wp[4],32, nullptr,0,0, r12f,r12hl, c4b,512, nullptr, zb,
        512,16,16,2, 8, 4,16,64);
    // r21: conv over r12 hi|lo (1024 ch) -> r11b
    k_mconv<3,1,2,2,1,16,3,0,0><<<dim3(512), 256, 0, stream>>>(
        r12hl,1024,1024, 16,1, wp[5],32, r11b,512,0, nullptr,nullptr, nullptr,0, nullptr, zb,
        512,16,16,2, 16, 4,16,64);
    // r22 = (1-q(conv(r21)))*r12 -> r22hl
    k_mconv<3,1,2,2,1,16,3,1,2><<<dim3(512), 256, 0, stream>>>(
        r11b,512,512, 16,1, wp[6],32, nullptr,0,0, nullptr,r22hl, r12f,512, nullptr, zb,
        512,16,16,2, 8, 4,16,64);
    // L3: [d3|f4] from r22 hi|lo -> cat3 ch 256..416   NT=16 NOCG=5 total=640
    k_mconv<4,1,2,2,1,16,3,0,0><<<dim3(640), 256, 0, stream>>>(
        r22hl,1024,1024, 16,10, wp[7],10, cat3b,416,256, nullptr,nullptr, nullptr,0, nullptr, zb,
        160,32,32,4, 16, 16,5,80);
    // L2: [d2|f3] from cat3 -> cat2 ch 128..224        WM=4 BN=2: NT=32 NOCG=3 total=768
    k_mconv<4,1,4,1,2,8,2,0,0><<<dim3(768), 256, 0, stream>>>(
        cat3b,416,416, 32,18, wp[8],6, cat2b,224,128, nullptr,nullptr, nullptr,0, nullptr, zb,
        96,64,64,8, 13, 32,3,96);
    // L1: [d1|f2|zero-pad] from cat2 -> cat1 ch 64..104  WM=4 BN=3: NT=128 NOCG=1 total=1024
    k_mconv<4,1,4,1,3,8,2,0,0><<<dim3(1024), 256, 0, stream>>>(
        cat2b,224,224, 64,34, wp[9],3, cat1b,104,64, nullptr,nullptr, nullptr,0, nullptr, zb,
        40,128,128,16, 7, 128,1,128);
    // u10 + fused global max-pool                WM=4 BN=2: NT=561 NOCG=1 total=4488
    k_mconv<4,1,4,1,2,8,2,2,0><<<dim3(4488), 256, 0, stream>>>(
        cat1b,104,104, 128,66, wp[10],2, nullptr,0,0, nullptr,nullptr, nullptr,0, featb, zb,
        32,257,257,33, 4, 561,1,561);
    // FC
    k_fc<<<dim3(1), dim3(64), 0, stream>>>(featb, wfc, out);
}

// Round 9
// 440.989 us; speedup vs baseline: 1.7276x; 1.7276x over previous
//
#include <hip/hip_runtime.h>

#define DEV __device__ __forceinline__

typedef __attribute__((ext_vector_type(4))) int i32x4;

// qi = 128*wq8(y) as int
DEV int wqi(float y) {
    int q = (int)rintf(y * 128.0f);
    return q < -127 ? -127 : (q > 127 ? 127 : q);
}
DEV unsigned encf(float f) { unsigned u = __float_as_uint(f); return (u & 0x80000000u) ? ~u : (u | 0x80000000u); }
DEV float decf(unsigned u) { return (u & 0x80000000u) ? __uint_as_float(u ^ 0x80000000u) : __uint_as_float(~u); }
DEV float wq8f(float x) {
    float q = rintf(x * 128.0f) * 0.0078125f;
    return fminf(fmaxf(q, -0.9921875f), 0.9921875f);
}

// async global->LDS, 16B per lane, dest = uniform base + lane*16 (linear)
#define GLOAD16(g, l) __builtin_amdgcn_global_load_lds( \
    (const __attribute__((address_space(1))) void*)(g), \
    (__attribute__((address_space(3))) void*)(l), 16, 0, 0)

// ---------------- fused i8 weight pack (11 layers, one launch) ----------------
// dst[((ch64*K2 + kpos)*noct + oct)*64 + lane] = 16 i8; byte e of group g (lane>>4)
// = w_int8(oc = oct*16 + (lane&15), cin = ch64*64 + g*16 + e). oc >= OC0+OC1 -> 0;
// cin >= CinT -> 0; duplicated slices: cw = cin % CinW.
struct PackDesc {
    const float* w0; const float* w1; uint4* dst;
    int OC0, OC1, CinW, CinT, K, noct, nthreads;
};
struct PackArgs { PackDesc d[11]; int bofs[12]; };

__global__ void __launch_bounds__(256) k_packall(PackArgs a) {
    const int b = blockIdx.x;
    int i = 0;
    #pragma unroll
    for (int j = 1; j < 11; ++j) if (b >= a.bofs[j]) i = j;
    const PackDesc D = a.d[i];
    const int gi = (b - a.bofs[i]) * 256 + threadIdx.x;
    if (gi >= D.nthreads) return;
    const int K2 = D.K * D.K;
    const int lane = gi & 63; int t = gi >> 6;
    const int oct = t % D.noct; t /= D.noct;
    const int kpos = t % K2; const int ch64 = t / K2;
    const int kh = kpos / D.K, kw = kpos % D.K;
    const int oc = oct * 16 + (lane & 15), g = lane >> 4;
    const float* src = nullptr; int oci = 0;
    if (oc < D.OC0) { src = D.w0; oci = oc; }
    else if (oc < D.OC0 + D.OC1) { src = D.w1; oci = oc - D.OC0; }
    unsigned wd[4] = {0u, 0u, 0u, 0u};
    #pragma unroll
    for (int e = 0; e < 16; ++e) {
        const int cin = ch64 * 64 + g * 16 + e;
        int v = 0;
        if (src != nullptr && cin < D.CinT) {
            const int cw = cin % D.CinW;
            v = wqi(src[((size_t)(oci * D.CinW + cw) * D.K + kh) * D.K + kw]);
        }
        wd[e >> 2] |= ((unsigned)(v & 255)) << ((e & 3) * 8);
    }
    uint4 u; u.x = wd[0]; u.y = wd[1]; u.z = wd[2]; u.w = wd[3];
    D.dst[gi] = u;
}

// ---------------- conv1: LDS-tiled f32 vector conv (exact chain), i8 out ----------------
__global__ void __launch_bounds__(256) k_conv1(const float* __restrict__ x, const float* __restrict__ w1,
                                               signed char* __restrict__ cat1) {
    __shared__ float sw2[36][64];
    __shared__ float sin_[4][17][17];
    const int tid = threadIdx.x;
    const int n = blockIdx.y;
    const int oh0 = (blockIdx.x >> 4) * 8, ow0 = (blockIdx.x & 15) * 8;
    for (int i = tid; i < 2304; i += 256) sw2[i % 36][i / 36] = wq8f(w1[i]);
    const int ih0 = oh0 * 2 - 1, iw0 = ow0 * 2 - 1;
    for (int i = tid; i < 4 * 289; i += 256) {
        const int c = i / 289, rem = i % 289, r = rem / 17, cc = rem % 17;
        const int ih = ih0 + r, iw = iw0 + cc;
        float v = 0.f;
        if ((unsigned)ih < 256u && (unsigned)iw < 256u) v = x[((size_t)(n * 4 + c) * 256 + ih) * 256 + iw];
        sin_[c][r][cc] = v;
    }
    __syncthreads();
    const int sp = tid & 63, ocg = tid >> 6;
    const int oh = sp >> 3, ow = sp & 7;
    float acc[16];
    #pragma unroll
    for (int j = 0; j < 16; ++j) acc[j] = 0.f;
    #pragma unroll
    for (int c = 0; c < 4; ++c)
    #pragma unroll
    for (int kh = 0; kh < 3; ++kh)
    #pragma unroll
    for (int kw = 0; kw < 3; ++kw) {
        const float v = sin_[c][oh * 2 + kh][ow * 2 + kw];
        const float4* wp4 = (const float4*)&sw2[c * 9 + kh * 3 + kw][ocg * 16];
        #pragma unroll
        for (int q = 0; q < 4; ++q) {
            const float4 wv = wp4[q];
            acc[q * 4 + 0] = fmaf(v, wv.x, acc[q * 4 + 0]);
            acc[q * 4 + 1] = fmaf(v, wv.y, acc[q * 4 + 1]);
            acc[q * 4 + 2] = fmaf(v, wv.z, acc[q * 4 + 2]);
            acc[q * 4 + 3] = fmaf(v, wv.w, acc[q * 4 + 3]);
        }
    }
    const size_t pix = ((size_t)(n * 128) + oh0 + oh) * 128 + ow0 + ow;
    unsigned wd[4] = {0u, 0u, 0u, 0u};
    #pragma unroll
    for (int j = 0; j < 16; ++j)
        wd[j >> 2] |= ((unsigned)(wqi(acc[j]) & 255)) << ((j & 3) * 8);
    uint4 u; u.x = wd[0]; u.y = wd[1]; u.z = wd[2]; u.w = wd[3];
    *(uint4*)(cat1 + pix * 112 + ocg * 16) = u;
}

__global__ void k_init(unsigned* __restrict__ feat, uint4* __restrict__ zbuf) {
    feat[threadIdx.x] = encf(-2.0f);
    if (threadIdx.x < 64) { uint4 z; z.x = z.y = z.z = z.w = 0u; zbuf[threadIdx.x] = z; }
}

__global__ void k_fc(const unsigned* __restrict__ feat, const float* __restrict__ wfc,
                     float* __restrict__ out) {
    int n = threadIdx.x;
    if (n < 8) {
        float s = 0.f;
        for (int c = 0; c < 32; ++c) s += decf(feat[n * 32 + c]) * wq8f(wfc[c]);
        out[n] = wq8f(s);
    }
}

// ---------------- implicit-GEMM i8 MFMA conv ----------------
// mfma_i32_16x16x64_i8: one 16B LDS read (unit g = 16 cin) per A-frag, chunk = 64 cin.
// LDS: pixel stride 5 units (80B), unit u at pix*5+u, slot 4 = pad (bank spacer).
// 1D grid, XCD-chunk swizzle work=(b&7)*swzq+(b>>3); ORD0: ocg inner/n outer (input-heavy);
// ORD1: tile inner/ocg outer (weight-heavy, per-XCD weight window L2-resident).
// NSLICE>1: slice-boundary fold acc64 = acc64*256 + acc (exact base-256 digit combine).
// MODE 0: dst=i8 qi; MODE 1: j=(128-qi)*res -> digit buffers; MODE 2: feat=max(wq8(y)).
template<int K, int STR, int WM, int WN, int BN, int NBUF, int MODE, int RESF, int NSLICE, int NCHPS>
__global__ void __launch_bounds__(256) k_mconv(
    const signed char* __restrict__ s0, int Ctot, int st0,
    int S, int padeff,
    const uint4* __restrict__ wqp, int noct,
    signed char* __restrict__ dst, int dstr, int dch,
    signed char* __restrict__ dhl, int dhlstr, short* __restrict__ dj,
    const void* __restrict__ res, int rstr,
    unsigned* __restrict__ feat,
    const signed char* __restrict__ zbuf,
    int OCv, int OH, int OW, int TILES_W, int nch,
    int NT, int NOCG, int swzq, int ORD)
{
    constexpr int TH = WM * 4;
    constexpr int RH = (TH - 1) * STR + K, RW = 7 * STR + K;
    constexpr int UPPS = 5;
    constexpr int K2 = K * K;
    constexpr int NUS = RH * RW * UPPS;
    constexpr int ROUNDS = (NUS + 255) / 256;
    constexpr int NUPS = ROUNDS * 256;
    constexpr int AHEAD = NBUF - 1;
    __shared__ uint4 lds[NBUF * NUPS];
    __shared__ float sred[4][2][16];

    const int tid = threadIdx.x, lane = tid & 63, w = tid >> 6;
    const int wm = w % WM, wn = w / WM;
    const int l15 = lane & 15, g = lane >> 4;

    const int b = blockIdx.x;
    const int work = (b & 7) * swzq + (b >> 3);
    int tile, n, ocg;
    if (ORD == 0) { ocg = work % NOCG; const int t2 = work / NOCG; tile = t2 % NT; n = t2 / NT; }
    else          { tile = work % NT; const int t2 = work / NT; n = t2 & 7; ocg = t2 >> 3; }

    const int tileh = tile / TILES_W, tilew = tile % TILES_W;
    const int oh0 = tileh * TH, ow0 = tilew * 8;
    const int ih0 = oh0 * STR - padeff, iw0 = ow0 * STR - padeff;
    const int blk_oct0 = ocg * (WN * BN);

    int pixb[2];
    #pragma unroll
    for (int am = 0; am < 2; ++am) {
        const int sp = wm * 32 + am * 16 + l15;
        pixb[am] = ((sp >> 3) * STR) * RW + (sp & 7) * STR;
    }

    i32x4 acc[2][BN];
    #pragma unroll
    for (int am = 0; am < 2; ++am)
        #pragma unroll
        for (int bn = 0; bn < BN; ++bn) acc[am][bn] = (i32x4){0, 0, 0, 0};
    long acc64[(NSLICE > 1) ? 2 * BN * 4 : 1];
    #pragma unroll
    for (int q = 0; q < ((NSLICE > 1) ? 2 * BN * 4 : 1); ++q) acc64[q] = 0;

    auto issue = [&](int ch, int buf) {
        uint4* lb = &lds[buf * NUPS];
        #pragma unroll
        for (int rd = 0; rd < ROUNDS; ++rd) {
            const int d = rd * 256 + tid;
            const signed char* gp = zbuf;
            if (d < NUS) {
                const int pix = d / UPPS;
                const int u = d - pix * UPPS;
                const int r = pix / RW, c = pix - r * RW;
                const int ih = ih0 + r, iw = iw0 + c;
                const int cin = ch * 64 + u * 16;
                if (u < 4 && (unsigned)ih < (unsigned)S && (unsigned)iw < (unsigned)S && cin < Ctot)
                    gp = s0 + (((size_t)n * S + ih) * S + iw) * st0 + cin;
            }
            GLOAD16(gp, lb + rd * 256 + (tid & ~63));
        }
    };

    #pragma unroll
    for (int i = 0; i < AHEAD; ++i) if (i < nch) issue(i, i % NBUF);

    for (int ch = 0; ch < nch; ++ch) {
        if (ch + AHEAD < nch) issue(ch + AHEAD, (ch + AHEAD) % NBUF);
        const int infl = (nch - 1 - ch < AHEAD) ? nch - 1 - ch : AHEAD;
        if (infl >= 2)      __builtin_amdgcn_s_waitcnt(0xF70 | (2 * ROUNDS));
        else if (infl == 1) __builtin_amdgcn_s_waitcnt(0xF70 | ROUNDS);
        else                __builtin_amdgcn_s_waitcnt(0xF70);
        __builtin_amdgcn_s_barrier();
        __builtin_amdgcn_sched_barrier(0);
        const int bufo = (ch % NBUF) * NUPS;
        const int pb0 = bufo + pixb[0] * UPPS + g;
        const int pb1 = bufo + pixb[1] * UPPS + g;
        const size_t wbase = ((size_t)ch * K2 * noct + blk_oct0 + wn * BN) * 64 + lane;
        #pragma unroll
        for (int kpos = 0; kpos < K2; ++kpos) {
            const int kh = kpos / K, kw = kpos % K;
            const int po = (kh * RW + kw) * UPPS;
            i32x4 bfr[BN];
            #pragma unroll
            for (int bn = 0; bn < BN; ++bn) {
                union { uint4 u; i32x4 v; } bu;
                bu.u = wqp[wbase + ((size_t)kpos * noct + bn) * 64];
                bfr[bn] = bu.v;
            }
            union { uint4 u; i32x4 v; } a0, a1;
            a0.u = lds[pb0 + po];
            a1.u = lds[pb1 + po];
            #pragma unroll
            for (int bn = 0; bn < BN; ++bn) {
                acc[0][bn] = __builtin_amdgcn_mfma_i32_16x16x64_i8(a0.v, bfr[bn], acc[0][bn], 0, 0, 0);
                acc[1][bn] = __builtin_amdgcn_mfma_i32_16x16x64_i8(a1.v, bfr[bn], acc[1][bn], 0, 0, 0);
            }
        }
        if constexpr (NSLICE > 1) {
            if (((ch + 1) & (NCHPS - 1)) == 0) {
                #pragma unroll
                for (int am = 0; am < 2; ++am)
                #pragma unroll
                for (int bn = 0; bn < BN; ++bn) {
                    #pragma unroll
                    for (int rg = 0; rg < 4; ++rg) {
                        acc64[(am * BN + bn) * 4 + rg] = acc64[(am * BN + bn) * 4 + rg] * 256 + (long)acc[am][bn][rg];
                    }
                    acc[am][bn] = (i32x4){0, 0, 0, 0};
                }
            }
        }
        __builtin_amdgcn_sched_barrier(0);
        __builtin_amdgcn_s_barrier();
    }

    if (MODE == 2) {
        #pragma unroll
        for (int bn = 0; bn < BN; ++bn) {
            float m = -2.0f;
            #pragma unroll
            for (int am = 0; am < 2; ++am)
                #pragma unroll
                for (int rg = 0; rg < 4; ++rg) {
                    const int sp = wm * 32 + am * 16 + g * 4 + rg;
                    const int oh = oh0 + (sp >> 3), ow = ow0 + (sp & 7);
                    float v = -2.0f;
                    if (oh < OH && ow < OW) {
                        const float y = (float)acc[am][bn][rg] * (1.f / 16384.f);
                        v = (float)wqi(y) * 0.0078125f;
                    }
                    m = fmaxf(m, v);
                }
            m = fmaxf(m, __shfl_xor(m, 16));
            m = fmaxf(m, __shfl_xor(m, 32));
            if (lane < 16) sred[w][bn][l15] = m;
        }
        __syncthreads();
        if (tid < BN * 16) {
            const int bn = tid >> 4, l = tid & 15;
            float mm = sred[0][bn][l];
            #pragma unroll
            for (int i = 1; i < WM * WN; ++i) mm = fmaxf(mm, sred[i][bn][l]);
            atomicMax(&feat[n * 32 + (blk_oct0 + bn) * 16 + l], encf(mm));
        }
    } else {
        #pragma unroll
        for (int am = 0; am < 2; ++am)
        #pragma unroll
        for (int bn = 0; bn < BN; ++bn)
        #pragma unroll
        for (int rg = 0; rg < 4; ++rg) {
            const int sp = wm * 32 + am * 16 + g * 4 + rg;
            const int oh = oh0 + (sp >> 3), ow = ow0 + (sp & 7);
            const int oc = (blk_oct0 + wn * BN + bn) * 16 + l15;
            if (oh < OH && ow < OW && oc < OCv) {
                const size_t pixo = (size_t)(n * OH + oh) * OW + ow;
                float y;
                if constexpr (NSLICE == 1)      y = (float)acc[am][bn][rg] * (1.f / 16384.f);
                else if constexpr (NSLICE == 2) y = (float)((double)acc64[(am * BN + bn) * 4 + rg] * (1.0 / 2097152.0));
                else                            y = (float)((double)acc64[(am * BN + bn) * 4 + rg] * (1.0 / 268435456.0));
                const int qi = wqi(y);
                if constexpr (MODE == 0) {
                    dst[pixo * dstr + dch + oc] = (signed char)qi;
                } else {
                    const int rvi = (RESF == 1) ? (int)((const signed char*)res)[pixo * rstr + oc]
                                                : (int)((const short*)res)[pixo * rstr + oc];
                    const int j = (128 - qi) * rvi;
                    const int d0 = ((j + 128) & 255) - 128;
                    const int t1 = (j - d0) >> 8;
                    if constexpr (RESF == 1) {       // r12: digits hi|lo + i16 value
                        dhl[pixo * dhlstr + oc] = (signed char)t1;
                        dhl[pixo * dhlstr + 512 + oc] = (signed char)d0;
                        dj[pixo * 512 + oc] = (short)j;
                    } else {                          // r22: 3 digits (exact)
                        const int d1 = ((t1 + 128) & 255) - 128;
                        const int d2 = (t1 - d1) >> 8;
                        dhl[pixo * dhlstr + oc] = (signed char)d2;
                        dhl[pixo * dhlstr + 512 + oc] = (signed char)d1;
                        dhl[pixo * dhlstr + 1024 + oc] = (signed char)d0;
                    }
                }
            }
        }
    }
}

extern "C" void kernel_launch(void* const* d_in, const int* in_sizes, int n_in,
                              void* d_out, int out_size, void* d_ws, size_t ws_size,
                              hipStream_t stream)
{
    (void)in_sizes; (void)n_in; (void)out_size; (void)ws_size;
    const float* x = (const float*)d_in[0];
    const float* wfc = (const float*)d_in[16];
    float* out = (float*)d_out;

    char* ws = (char*)d_ws;
    size_t off = 0;
    auto alloc = [&](size_t bytes) { char* p = ws + off; off += (bytes + 255) & ~(size_t)255; return p; };

    // {w0 idx, OC0, w1 idx, OC1, CinW, CinT, K, noct, nch64}
    struct PH { int i0, OC0, i1, OC1, CinW, CinT, K, noct, nch64; };
    static const PH ph[11] = {
        {2, 128, -1, 0,  64,   64, 3,  8,  1},   // 0 conv2
        {3, 256, -1, 0, 128,  128, 3, 16,  2},   // 1 conv3
        {4, 512, -1, 0, 256,  256, 3, 32,  4},   // 2 conv4
        {5, 512, -1, 0, 512,  512, 3, 32,  8},   // 3 r11
        {6, 512, -1, 0, 512,  512, 3, 32,  8},   // 4 r12
        {7, 512, -1, 0, 512, 1024, 3, 32, 16},   // 5 r21 (2 slices)
        {8, 512, -1, 0, 512,  512, 3, 32,  8},   // 6 r22
        {9, 128, 12, 32, 512, 1536, 4, 10, 24},  // 7 L3 = wd3|wu43 (3 slices)
        {10, 64, 13, 32, 416,  416, 4,  6,  7},  // 8 L2 = wd2|wu32
        {11,  4, 14, 32, 224,  224, 4,  3,  4},  // 9 L1 = wd1|wu21 (+12 zero oc -> cat1 pad)
        {15, 32, -1, 0, 100,  100, 4,  2,  2}};  // 10 u10

    PackArgs pa;
    int bacc = 0;
    uint4* wp[11];
    for (int i = 0; i < 11; ++i) {
        const int nthr = ph[i].nch64 * ph[i].K * ph[i].K * ph[i].noct * 64;
        wp[i] = (uint4*)alloc((size_t)nthr * 16);
        pa.d[i].w0 = (const float*)d_in[ph[i].i0];
        pa.d[i].w1 = (ph[i].i1 >= 0) ? (const float*)d_in[ph[i].i1] : nullptr;
        pa.d[i].dst = wp[i];
        pa.d[i].OC0 = ph[i].OC0; pa.d[i].OC1 = ph[i].OC1;
        pa.d[i].CinW = ph[i].CinW; pa.d[i].CinT = ph[i].CinT;
        pa.d[i].K = ph[i].K; pa.d[i].noct = ph[i].noct;
        pa.d[i].nthreads = nthr;
        pa.bofs[i] = bacc;
        bacc += (nthr + 255) / 256;
    }
    pa.bofs[11] = bacc;

    signed char* cat1b = (signed char*)alloc((size_t)8*128*128*112);  // c1|d1|f2|pad12
    signed char* cat2b = (signed char*)alloc((size_t)8*64*64*224);    // c2|d2|f3
    signed char* cat3b = (signed char*)alloc((size_t)8*32*32*416);    // c3|d3|f4
    signed char* c4b   = (signed char*)alloc((size_t)8*16*16*512);
    signed char* r11b  = (signed char*)alloc((size_t)8*16*16*512);    // also r21 out
    signed char* r12d  = (signed char*)alloc((size_t)8*16*16*1024);   // r12 digits hi|lo
    short*       r12j  = (short*)alloc((size_t)8*16*16*512 * 2);      // r12 as i16 j (gate res)
    signed char* r22d  = (signed char*)alloc((size_t)8*16*16*1536);   // r22 digits j2|j1|j0
    unsigned*    featb = (unsigned*)alloc(256 * 4);
    uint4*       zbuf  = (uint4*)alloc(1024);

    k_packall<<<dim3((unsigned)bacc), dim3(256), 0, stream>>>(pa);
    k_init<<<dim3(1), dim3(256), 0, stream>>>(featb, zbuf);
    k_conv1<<<dim3(256, 8), dim3(256), 0, stream>>>(x, (const float*)d_in[1], cat1b);

    const signed char* zb = (const signed char*)zbuf;

    // conv2: cat1 ch0..64 -> cat2 ch0..128   NT=64 NOCG=2 total=1024  ORD0
    k_mconv<3,2,2,2,2,1,0,0,1,1><<<dim3(1024), 256, 0, stream>>>(
        cat1b,64,112, 128,1, wp[0],8, cat2b,224,0, nullptr,0,nullptr, nullptr,0, nullptr, zb,
        128,64,64,8, 1, 64,2,128, 0);
    // conv3: cat2 -> cat3 ch0..256           NT=16 NOCG=4 total=512  ORD0
    k_mconv<3,2,2,2,2,2,0,0,1,1><<<dim3(512), 256, 0, stream>>>(
        cat2b,128,224, 64,1, wp[1],16, cat3b,416,0, nullptr,0,nullptr, nullptr,0, nullptr, zb,
        256,32,32,4, 2, 16,4,64, 0);
    // conv4: cat3 -> c4                      NT=4 NOCG=16 total=512  ORD1
    k_mconv<3,2,2,2,1,2,0,0,1,1><<<dim3(512), 256, 0, stream>>>(
        cat3b,256,416, 32,1, wp[2],32, c4b,512,0, nullptr,0,nullptr, nullptr,0, nullptr, zb,
        512,16,16,2, 4, 4,16,64, 1);
    // r11                                    NT=4 NOCG=16 total=512  ORD1
    k_mconv<3,1,2,2,1,3,0,0,1,1><<<dim3(512), 256, 0, stream>>>(
        c4b,512,512, 16,1, wp[3],32, r11b,512,0, nullptr,0,nullptr, nullptr,0, nullptr, zb,
        512,16,16,2, 8, 4,16,64, 1);
    // r12 = (1-q(conv(r11)))*c4 -> digits + i16
    k_mconv<3,1,2,2,1,3,1,1,1,1><<<dim3(512), 256, 0, stream>>>(
        r11b,512,512, 16,1, wp[4],32, nullptr,0,0, r12d,1024,r12j, c4b,512, nullptr, zb,
        512,16,16,2, 8, 4,16,64, 1);
    // r21: conv over r12 digits (1024 ch, 2 slices) -> r11b
    k_mconv<3,1,2,2,1,3,0,0,2,8><<<dim3(512), 256, 0, stream>>>(
        r12d,1024,1024, 16,1, wp[5],32, r11b,512,0, nullptr,0,nullptr, nullptr,0, nullptr, zb,
        512,16,16,2, 16, 4,16,64, 1);
    // r22 = (1-q(conv(r21)))*r12 -> 3 digits (exact)
    k_mconv<3,1,2,2,1,3,1,2,1,1><<<dim3(512), 256, 0, stream>>>(
        r11b,512,512, 16,1, wp[6],32, nullptr,0,0, r22d,1536,nullptr, r12j,512, nullptr, zb,
        512,16,16,2, 8, 4,16,64, 1);
    // L3: [d3|f4] from r22 digits (3 slices) -> cat3 ch 256..416   NT=16 NOCG=5 total=640 ORD1
    k_mconv<4,1,2,2,1,3,0,0,3,8><<<dim3(640), 256, 0, stream>>>(
        r22d,1536,1536, 16,10, wp[7],10, cat3b,416,256, nullptr,0,nullptr, nullptr,0, nullptr, zb,
        160,32,32,4, 24, 16,5,80, 1);
    // L2: [d2|f3] from cat3 -> cat2 ch 128..224   WM4 BN2: NT=32 NOCG=3 total=768 ORD0
    k_mconv<4,1,4,1,2,2,0,0,1,1><<<dim3(768), 256, 0, stream>>>(
        cat3b,416,416, 32,18, wp[8],6, cat2b,224,128, nullptr,0,nullptr, nullptr,0, nullptr, zb,
        96,64,64,8, 7, 32,3,96, 0);
    // L1: [d1|f2|pad] from cat2 -> cat1 ch 64..112   WM4 BN3: NT=128 NOCG=1 total=1024 ORD0
    k_mconv<4,1,4,1,3,2,0,0,1,1><<<dim3(1024), 256, 0, stream>>>(
        cat2b,224,224, 64,34, wp[9],3, cat1b,112,64, nullptr,0,nullptr, nullptr,0, nullptr, zb,
        48,128,128,16, 4, 128,1,128, 0);
    // u10 + fused global max-pool   WM4 BN2: NT=561 total=4488 ORD0
    k_mconv<4,1,4,1,2,2,2,0,1,1><<<dim3(4488), 256, 0, stream>>>(
        cat1b,112,112, 128,66, wp[10],2, nullptr,0,0, nullptr,0,nullptr, nullptr,0, featb, zb,
        32,257,257,33, 2, 561,1,561, 0);
    // FC
    k_fc<<<dim3(1), dim3(64), 0, stream>>>(featb, wfc, out);
}

// Round 10
// 379.727 us; speedup vs baseline: 2.0064x; 1.1613x over previous
//
#include <hip/hip_runtime.h>

#define DEV __device__ __forceinline__

typedef __attribute__((ext_vector_type(4))) int i32x4;

// qi = 128*wq8(y) as int
DEV int wqi(float y) {
    int q = (int)rintf(y * 128.0f);
    return q < -127 ? -127 : (q > 127 ? 127 : q);
}
DEV unsigned encf(float f) { unsigned u = __float_as_uint(f); return (u & 0x80000000u) ? ~u : (u | 0x80000000u); }
DEV float decf(unsigned u) { return (u & 0x80000000u) ? __uint_as_float(u ^ 0x80000000u) : __uint_as_float(~u); }
DEV float wq8f(float x) {
    float q = rintf(x * 128.0f) * 0.0078125f;
    return fminf(fmaxf(q, -0.9921875f), 0.9921875f);
}

// async global->LDS, 16B per lane, dest = uniform base + lane*16 (linear)
#define GLOAD16(g, l) __builtin_amdgcn_global_load_lds( \
    (const __attribute__((address_space(1))) void*)(g), \
    (__attribute__((address_space(3))) void*)(l), 16, 0, 0)

// ---------------- i8 weight pack, LDS-staged coalesced transpose ----------------
// One block per (layer, oct, ch64u-window). Stage: 16 oc-rows x 64 cin x K2 f32,
// contiguous float4 per row, quantize -> LDS bytes [row][cin_local*K2 + kpos]
// (row stride +4 -> odd dword stride, conflict-light gather). Gather: each output
// uint4 (kpos, lane) collects 16 bytes (cin g*16+e, oc l15); duplicated slices
// (CinT = ndup*CinW) are staged once, written ndup times.
struct PackDesc {
    const float* w0; const float* w1; uint4* dst;
    int OC0, OC1, CinW, K, noct, nch64u, ndup;
};
struct PackArgs { PackDesc d[11]; int bofs[12]; };

__global__ void __launch_bounds__(256) k_packall(PackArgs a) {
    __shared__ unsigned char sb[16 * (64 * 16 + 4)];
    const int b = blockIdx.x;
    int i = 0;
    #pragma unroll
    for (int j = 1; j < 11; ++j) if (b >= a.bofs[j]) i = j;
    const PackDesc D = a.d[i];
    const int b2 = b - a.bofs[i];
    const int oct = b2 % D.noct;
    const int ch64u = b2 / D.noct;
    const int K2 = D.K * D.K;
    const int row_elems = 64 * K2;
    const int SSTR = row_elems + 4;
    const int QR = row_elems / 4;
    const int NQ = 16 * QR;
    const int cin0 = ch64u * 64;
    const int tid = threadIdx.x;

    for (int q = tid; q < NQ; q += 256) {
        const int r = q / QR, j = q - r * QR;
        const int oc = oct * 16 + r;
        const float* src = nullptr; int oci = 0;
        if (oc < D.OC0) { src = D.w0; oci = oc; }
        else if (oc < D.OC0 + D.OC1) { src = D.w1; oci = oc - D.OC0; }
        const int e0 = j * 4;
        float v[4] = {0.f, 0.f, 0.f, 0.f};
        if (src != nullptr) {
            const float* p = src + ((size_t)oci * D.CinW + cin0) * K2 + e0;
            const int cin_last = cin0 + (e0 + 3) / K2;
            if (cin_last < D.CinW) {
                const float4 f4 = *(const float4*)p;
                v[0] = f4.x; v[1] = f4.y; v[2] = f4.z; v[3] = f4.w;
            } else {
                #pragma unroll
                for (int e = 0; e < 4; ++e) {
                    const int cin = cin0 + (e0 + e) / K2;
                    if (cin < D.CinW) v[e] = p[e];
                }
            }
        }
        unsigned pk = 0;
        #pragma unroll
        for (int e = 0; e < 4; ++e) pk |= ((unsigned)(wqi(v[e]) & 255)) << (e * 8);
        *(unsigned*)&sb[r * SSTR + e0] = pk;
    }
    __syncthreads();

    const int outN = K2 * 64;
    for (int idx = tid; idx < outN; idx += 256) {
        const int kpos = idx >> 6, lane = idx & 63;
        const int l15 = lane & 15, g = lane >> 4;
        unsigned wd[4] = {0u, 0u, 0u, 0u};
        #pragma unroll
        for (int e = 0; e < 16; ++e) {
            const unsigned bval = sb[l15 * SSTR + (g * 16 + e) * K2 + kpos];
            wd[e >> 2] |= bval << ((e & 3) * 8);
        }
        uint4 u; u.x = wd[0]; u.y = wd[1]; u.z = wd[2]; u.w = wd[3];
        for (int d = 0; d < D.ndup; ++d) {
            const int ch64 = ch64u + d * D.nch64u;
            D.dst[((size_t)(ch64 * K2 + kpos) * D.noct + oct) * 64 + lane] = u;
        }
    }
}

// ---------------- conv1: LDS-tiled f32 vector conv (exact chain), i8 out ----------------
__global__ void __launch_bounds__(256) k_conv1(const float* __restrict__ x, const float* __restrict__ w1,
                                               signed char* __restrict__ cat1) {
    __shared__ float sw2[36][64];
    __shared__ float sin_[4][17][17];
    const int tid = threadIdx.x;
    const int n = blockIdx.y;
    const int oh0 = (blockIdx.x >> 4) * 8, ow0 = (blockIdx.x & 15) * 8;
    for (int i = tid; i < 2304; i += 256) sw2[i % 36][i / 36] = wq8f(w1[i]);
    const int ih0 = oh0 * 2 - 1, iw0 = ow0 * 2 - 1;
    for (int i = tid; i < 4 * 289; i += 256) {
        const int c = i / 289, rem = i % 289, r = rem / 17, cc = rem % 17;
        const int ih = ih0 + r, iw = iw0 + cc;
        float v = 0.f;
        if ((unsigned)ih < 256u && (unsigned)iw < 256u) v = x[((size_t)(n * 4 + c) * 256 + ih) * 256 + iw];
        sin_[c][r][cc] = v;
    }
    __syncthreads();
    const int sp = tid & 63, ocg = tid >> 6;
    const int oh = sp >> 3, ow = sp & 7;
    float acc[16];
    #pragma unroll
    for (int j = 0; j < 16; ++j) acc[j] = 0.f;
    #pragma unroll
    for (int c = 0; c < 4; ++c)
    #pragma unroll
    for (int kh = 0; kh < 3; ++kh)
    #pragma unroll
    for (int kw = 0; kw < 3; ++kw) {
        const float v = sin_[c][oh * 2 + kh][ow * 2 + kw];
        const float4* wp4 = (const float4*)&sw2[c * 9 + kh * 3 + kw][ocg * 16];
        #pragma unroll
        for (int q = 0; q < 4; ++q) {
            const float4 wv = wp4[q];
            acc[q * 4 + 0] = fmaf(v, wv.x, acc[q * 4 + 0]);
            acc[q * 4 + 1] = fmaf(v, wv.y, acc[q * 4 + 1]);
            acc[q * 4 + 2] = fmaf(v, wv.z, acc[q * 4 + 2]);
            acc[q * 4 + 3] = fmaf(v, wv.w, acc[q * 4 + 3]);
        }
    }
    const size_t pix = ((size_t)(n * 128) + oh0 + oh) * 128 + ow0 + ow;
    unsigned wd[4] = {0u, 0u, 0u, 0u};
    #pragma unroll
    for (int j = 0; j < 16; ++j)
        wd[j >> 2] |= ((unsigned)(wqi(acc[j]) & 255)) << ((j & 3) * 8);
    uint4 u; u.x = wd[0]; u.y = wd[1]; u.z = wd[2]; u.w = wd[3];
    *(uint4*)(cat1 + pix * 112 + ocg * 16) = u;
}

__global__ void k_init(unsigned* __restrict__ feat, uint4* __restrict__ zbuf) {
    feat[threadIdx.x] = encf(-2.0f);
    if (threadIdx.x < 64) { uint4 z; z.x = z.y = z.z = z.w = 0u; zbuf[threadIdx.x] = z; }
}

__global__ void k_fc(const unsigned* __restrict__ feat, const float* __restrict__ wfc,
                     float* __restrict__ out) {
    int n = threadIdx.x;
    if (n < 8) {
        float s = 0.f;
        for (int c = 0; c < 32; ++c) s += decf(feat[n * 32 + c]) * wq8f(wfc[c]);
        out[n] = wq8f(s);
    }
}

// ---------------- implicit-GEMM i8 MFMA conv (unchanged from R9) ----------------
template<int K, int STR, int WM, int WN, int BN, int NBUF, int MODE, int RESF, int NSLICE, int NCHPS>
__global__ void __launch_bounds__(256) k_mconv(
    const signed char* __restrict__ s0, int Ctot, int st0,
    int S, int padeff,
    const uint4* __restrict__ wqp, int noct,
    signed char* __restrict__ dst, int dstr, int dch,
    signed char* __restrict__ dhl, int dhlstr, short* __restrict__ dj,
    const void* __restrict__ res, int rstr,
    unsigned* __restrict__ feat,
    const signed char* __restrict__ zbuf,
    int OCv, int OH, int OW, int TILES_W, int nch,
    int NT, int NOCG, int swzq, int ORD)
{
    constexpr int TH = WM * 4;
    constexpr int RH = (TH - 1) * STR + K, RW = 7 * STR + K;
    constexpr int UPPS = 5;
    constexpr int K2 = K * K;
    constexpr int NUS = RH * RW * UPPS;
    constexpr int ROUNDS = (NUS + 255) / 256;
    constexpr int NUPS = ROUNDS * 256;
    constexpr int AHEAD = NBUF - 1;
    __shared__ uint4 lds[NBUF * NUPS];
    __shared__ float sred[4][2][16];

    const int tid = threadIdx.x, lane = tid & 63, w = tid >> 6;
    const int wm = w % WM, wn = w / WM;
    const int l15 = lane & 15, g = lane >> 4;

    const int b = blockIdx.x;
    const int work = (b & 7) * swzq + (b >> 3);
    int tile, n, ocg;
    if (ORD == 0) { ocg = work % NOCG; const int t2 = work / NOCG; tile = t2 % NT; n = t2 / NT; }
    else          { tile = work % NT; const int t2 = work / NT; n = t2 & 7; ocg = t2 >> 3; }

    const int tileh = tile / TILES_W, tilew = tile % TILES_W;
    const int oh0 = tileh * TH, ow0 = tilew * 8;
    const int ih0 = oh0 * STR - padeff, iw0 = ow0 * STR - padeff;
    const int blk_oct0 = ocg * (WN * BN);

    int pixb[2];
    #pragma unroll
    for (int am = 0; am < 2; ++am) {
        const int sp = wm * 32 + am * 16 + l15;
        pixb[am] = ((sp >> 3) * STR) * RW + (sp & 7) * STR;
    }

    i32x4 acc[2][BN];
    #pragma unroll
    for (int am = 0; am < 2; ++am)
        #pragma unroll
        for (int bn = 0; bn < BN; ++bn) acc[am][bn] = (i32x4){0, 0, 0, 0};
    long acc64[(NSLICE > 1) ? 2 * BN * 4 : 1];
    #pragma unroll
    for (int q = 0; q < ((NSLICE > 1) ? 2 * BN * 4 : 1); ++q) acc64[q] = 0;

    auto issue = [&](int ch, int buf) {
        uint4* lb = &lds[buf * NUPS];
        #pragma unroll
        for (int rd = 0; rd < ROUNDS; ++rd) {
            const int d = rd * 256 + tid;
            const signed char* gp = zbuf;
            if (d < NUS) {
                const int pix = d / UPPS;
                const int u = d - pix * UPPS;
                const int r = pix / RW, c = pix - r * RW;
                const int ih = ih0 + r, iw = iw0 + c;
                const int cin = ch * 64 + u * 16;
                if (u < 4 && (unsigned)ih < (unsigned)S && (unsigned)iw < (unsigned)S && cin < Ctot)
                    gp = s0 + (((size_t)n * S + ih) * S + iw) * st0 + cin;
            }
            GLOAD16(gp, lb + rd * 256 + (tid & ~63));
        }
    };

    #pragma unroll
    for (int i = 0; i < AHEAD; ++i) if (i < nch) issue(i, i % NBUF);

    for (int ch = 0; ch < nch; ++ch) {
        if (ch + AHEAD < nch) issue(ch + AHEAD, (ch + AHEAD) % NBUF);
        const int infl = (nch - 1 - ch < AHEAD) ? nch - 1 - ch : AHEAD;
        if (infl >= 2)      __builtin_amdgcn_s_waitcnt(0xF70 | (2 * ROUNDS));
        else if (infl == 1) __builtin_amdgcn_s_waitcnt(0xF70 | ROUNDS);
        else                __builtin_amdgcn_s_waitcnt(0xF70);
        __builtin_amdgcn_s_barrier();
        __builtin_amdgcn_sched_barrier(0);
        const int bufo = (ch % NBUF) * NUPS;
        const int pb0 = bufo + pixb[0] * UPPS + g;
        const int pb1 = bufo + pixb[1] * UPPS + g;
        const size_t wbase = ((size_t)ch * K2 * noct + blk_oct0 + wn * BN) * 64 + lane;
        #pragma unroll
        for (int kpos = 0; kpos < K2; ++kpos) {
            const int kh = kpos / K, kw = kpos % K;
            const int po = (kh * RW + kw) * UPPS;
            i32x4 bfr[BN];
            #pragma unroll
            for (int bn = 0; bn < BN; ++bn) {
                union { uint4 u; i32x4 v; } bu;
                bu.u = wqp[wbase + ((size_t)kpos * noct + bn) * 64];
                bfr[bn] = bu.v;
            }
            union { uint4 u; i32x4 v; } a0, a1;
            a0.u = lds[pb0 + po];
            a1.u = lds[pb1 + po];
            #pragma unroll
            for (int bn = 0; bn < BN; ++bn) {
                acc[0][bn] = __builtin_amdgcn_mfma_i32_16x16x64_i8(a0.v, bfr[bn], acc[0][bn], 0, 0, 0);
                acc[1][bn] = __builtin_amdgcn_mfma_i32_16x16x64_i8(a1.v, bfr[bn], acc[1][bn], 0, 0, 0);
            }
        }
        if constexpr (NSLICE > 1) {
            if (((ch + 1) & (NCHPS - 1)) == 0) {
                #pragma unroll
                for (int am = 0; am < 2; ++am)
                #pragma unroll
                for (int bn = 0; bn < BN; ++bn) {
                    #pragma unroll
                    for (int rg = 0; rg < 4; ++rg) {
                        acc64[(am * BN + bn) * 4 + rg] = acc64[(am * BN + bn) * 4 + rg] * 256 + (long)acc[am][bn][rg];
                    }
                    acc[am][bn] = (i32x4){0, 0, 0, 0};
                }
            }
        }
        __builtin_amdgcn_sched_barrier(0);
        __builtin_amdgcn_s_barrier();
    }

    if (MODE == 2) {
        #pragma unroll
        for (int bn = 0; bn < BN; ++bn) {
            float m = -2.0f;
            #pragma unroll
            for (int am = 0; am < 2; ++am)
                #pragma unroll
                for (int rg = 0; rg < 4; ++rg) {
                    const int sp = wm * 32 + am * 16 + g * 4 + rg;
                    const int oh = oh0 + (sp >> 3), ow = ow0 + (sp & 7);
                    float v = -2.0f;
                    if (oh < OH && ow < OW) {
                        const float y = (float)acc[am][bn][rg] * (1.f / 16384.f);
                        v = (float)wqi(y) * 0.0078125f;
                    }
                    m = fmaxf(m, v);
                }
            m = fmaxf(m, __shfl_xor(m, 16));
            m = fmaxf(m, __shfl_xor(m, 32));
            if (lane < 16) sred[w][bn][l15] = m;
        }
        __syncthreads();
        if (tid < BN * 16) {
            const int bn = tid >> 4, l = tid & 15;
            float mm = sred[0][bn][l];
            #pragma unroll
            for (int i = 1; i < WM * WN; ++i) mm = fmaxf(mm, sred[i][bn][l]);
            atomicMax(&feat[n * 32 + (blk_oct0 + bn) * 16 + l], encf(mm));
        }
    } else {
        #pragma unroll
        for (int am = 0; am < 2; ++am)
        #pragma unroll
        for (int bn = 0; bn < BN; ++bn)
        #pragma unroll
        for (int rg = 0; rg < 4; ++rg) {
            const int sp = wm * 32 + am * 16 + g * 4 + rg;
            const int oh = oh0 + (sp >> 3), ow = ow0 + (sp & 7);
            const int oc = (blk_oct0 + wn * BN + bn) * 16 + l15;
            if (oh < OH && ow < OW && oc < OCv) {
                const size_t pixo = (size_t)(n * OH + oh) * OW + ow;
                float y;
                if constexpr (NSLICE == 1)      y = (float)acc[am][bn][rg] * (1.f / 16384.f);
                else if constexpr (NSLICE == 2) y = (float)((double)acc64[(am * BN + bn) * 4 + rg] * (1.0 / 2097152.0));
                else                            y = (float)((double)acc64[(am * BN + bn) * 4 + rg] * (1.0 / 268435456.0));
                const int qi = wqi(y);
                if constexpr (MODE == 0) {
                    dst[pixo * dstr + dch + oc] = (signed char)qi;
                } else {
                    const int rvi = (RESF == 1) ? (int)((const signed char*)res)[pixo * rstr + oc]
                                                : (int)((const short*)res)[pixo * rstr + oc];
                    const int j = (128 - qi) * rvi;
                    const int d0 = ((j + 128) & 255) - 128;
                    const int t1 = (j - d0) >> 8;
                    if constexpr (RESF == 1) {
                        dhl[pixo * dhlstr + oc] = (signed char)t1;
                        dhl[pixo * dhlstr + 512 + oc] = (signed char)d0;
                        dj[pixo * 512 + oc] = (short)j;
                    } else {
                        const int d1 = ((t1 + 128) & 255) - 128;
                        const int d2 = (t1 - d1) >> 8;
                        dhl[pixo * dhlstr + oc] = (signed char)d2;
                        dhl[pixo * dhlstr + 512 + oc] = (signed char)d1;
                        dhl[pixo * dhlstr + 1024 + oc] = (signed char)d0;
                    }
                }
            }
        }
    }
}

extern "C" void kernel_launch(void* const* d_in, const int* in_sizes, int n_in,
                              void* d_out, int out_size, void* d_ws, size_t ws_size,
                              hipStream_t stream)
{
    (void)in_sizes; (void)n_in; (void)out_size; (void)ws_size;
    const float* x = (const float*)d_in[0];
    const float* wfc = (const float*)d_in[16];
    float* out = (float*)d_out;

    char* ws = (char*)d_ws;
    size_t off = 0;
    auto alloc = [&](size_t bytes) { char* p = ws + off; off += (bytes + 255) & ~(size_t)255; return p; };

    // {w0 idx, OC0, w1 idx, OC1, CinW, K, noct, nch64u, ndup}
    struct PH { int i0, OC0, i1, OC1, CinW, K, noct, nch64u, ndup; };
    static const PH ph[11] = {
        {2, 128, -1, 0,  64, 3,  8, 1, 1},   // 0 conv2
        {3, 256, -1, 0, 128, 3, 16, 2, 1},   // 1 conv3
        {4, 512, -1, 0, 256, 3, 32, 4, 1},   // 2 conv4
        {5, 512, -1, 0, 512, 3, 32, 8, 1},   // 3 r11
        {6, 512, -1, 0, 512, 3, 32, 8, 1},   // 4 r12
        {7, 512, -1, 0, 512, 3, 32, 8, 2},   // 5 r21 (2 slices)
        {8, 512, -1, 0, 512, 3, 32, 8, 1},   // 6 r22
        {9, 128, 12, 32, 512, 4, 10, 8, 3},  // 7 L3 = wd3|wu43 (3 slices)
        {10, 64, 13, 32, 416, 4,  6, 7, 1},  // 8 L2 = wd2|wu32
        {11,  4, 14, 32, 224, 4,  3, 4, 1},  // 9 L1 = wd1|wu21 (+12 zero oc)
        {15, 32, -1, 0, 100, 4,  2, 2, 1}};  // 10 u10

    PackArgs pa;
    int bacc = 0;
    uint4* wp[11];
    for (int i = 0; i < 11; ++i) {
        const int nch64 = ph[i].nch64u * ph[i].ndup;
        const int nel = nch64 * ph[i].K * ph[i].K * ph[i].noct * 64;
        wp[i] = (uint4*)alloc((size_t)nel * 16);
        pa.d[i].w0 = (const float*)d_in[ph[i].i0];
        pa.d[i].w1 = (ph[i].i1 >= 0) ? (const float*)d_in[ph[i].i1] : nullptr;
        pa.d[i].dst = wp[i];
        pa.d[i].OC0 = ph[i].OC0; pa.d[i].OC1 = ph[i].OC1;
        pa.d[i].CinW = ph[i].CinW; pa.d[i].K = ph[i].K; pa.d[i].noct = ph[i].noct;
        pa.d[i].nch64u = ph[i].nch64u; pa.d[i].ndup = ph[i].ndup;
        pa.bofs[i] = bacc;
        bacc += ph[i].noct * ph[i].nch64u;
    }
    pa.bofs[11] = bacc;

    signed char* cat1b = (signed char*)alloc((size_t)8*128*128*112);  // c1|d1|f2|pad12
    signed char* cat2b = (signed char*)alloc((size_t)8*64*64*224);    // c2|d2|f3
    signed char* cat3b = (signed char*)alloc((size_t)8*32*32*416);    // c3|d3|f4
    signed char* c4b   = (signed char*)alloc((size_t)8*16*16*512);
    signed char* r11b  = (signed char*)alloc((size_t)8*16*16*512);    // also r21 out
    signed char* r12d  = (signed char*)alloc((size_t)8*16*16*1024);   // r12 digits hi|lo
    short*       r12j  = (short*)alloc((size_t)8*16*16*512 * 2);      // r12 as i16 j (gate res)
    signed char* r22d  = (signed char*)alloc((size_t)8*16*16*1536);   // r22 digits j2|j1|j0
    unsigned*    featb = (unsigned*)alloc(256 * 4);
    uint4*       zbuf  = (uint4*)alloc(1024);

    k_packall<<<dim3((unsigned)bacc), dim3(256), 0, stream>>>(pa);
    k_init<<<dim3(1), dim3(256), 0, stream>>>(featb, zbuf);
    k_conv1<<<dim3(256, 8), dim3(256), 0, stream>>>(x, (const float*)d_in[1], cat1b);

    const signed char* zb = (const signed char*)zbuf;

    // conv2: cat1 ch0..64 -> cat2 ch0..128   NT=64 NOCG=2 total=1024  ORD0
    k_mconv<3,2,2,2,2,1,0,0,1,1><<<dim3(1024), 256, 0, stream>>>(
        cat1b,64,112, 128,1, wp[0],8, cat2b,224,0, nullptr,0,nullptr, nullptr,0, nullptr, zb,
        128,64,64,8, 1, 64,2,128, 0);
    // conv3: cat2 -> cat3 ch0..256           NT=16 NOCG=4 total=512  ORD0
    k_mconv<3,2,2,2,2,2,0,0,1,1><<<dim3(512), 256, 0, stream>>>(
        cat2b,128,224, 64,1, wp[1],16, cat3b,416,0, nullptr,0,nullptr, nullptr,0, nullptr, zb,
        256,32,32,4, 2, 16,4,64, 0);
    // conv4: cat3 -> c4                      NT=4 NOCG=16 total=512  ORD1
    k_mconv<3,2,2,2,1,2,0,0,1,1><<<dim3(512), 256, 0, stream>>>(
        cat3b,256,416, 32,1, wp[2],32, c4b,512,0, nullptr,0,nullptr, nullptr,0, nullptr, zb,
        512,16,16,2, 4, 4,16,64, 1);
    // r11                                    NT=4 NOCG=16 total=512  ORD1
    k_mconv<3,1,2,2,1,3,0,0,1,1><<<dim3(512), 256, 0, stream>>>(
        c4b,512,512, 16,1, wp[3],32, r11b,512,0, nullptr,0,nullptr, nullptr,0, nullptr, zb,
        512,16,16,2, 8, 4,16,64, 1);
    // r12 = (1-q(conv(r11)))*c4 -> digits + i16
    k_mconv<3,1,2,2,1,3,1,1,1,1><<<dim3(512), 256, 0, stream>>>(
        r11b,512,512, 16,1, wp[4],32, nullptr,0,0, r12d,1024,r12j, c4b,512, nullptr, zb,
        512,16,16,2, 8, 4,16,64, 1);
    // r21: conv over r12 digits (1024 ch, 2 slices) -> r11b
    k_mconv<3,1,2,2,1,3,0,0,2,8><<<dim3(512), 256, 0, stream>>>(
        r12d,1024,1024, 16,1, wp[5],32, r11b,512,0, nullptr,0,nullptr, nullptr,0, nullptr, zb,
        512,16,16,2, 16, 4,16,64, 1);
    // r22 = (1-q(conv(r21)))*r12 -> 3 digits (exact)
    k_mconv<3,1,2,2,1,3,1,2,1,1><<<dim3(512), 256, 0, stream>>>(
        r11b,512,512, 16,1, wp[6],32, nullptr,0,0, r22d,1536,nullptr, r12j,512, nullptr, zb,
        512,16,16,2, 8, 4,16,64, 1);
    // L3: [d3|f4] from r22 digits (3 slices) -> cat3 ch 256..416   NT=16 NOCG=5 total=640 ORD1
    k_mconv<4,1,2,2,1,3,0,0,3,8><<<dim3(640), 256, 0, stream>>>(
        r22d,1536,1536, 16,10, wp[7],10, cat3b,416,256, nullptr,0,nullptr, nullptr,0, nullptr, zb,
        160,32,32,4, 24, 16,5,80, 1);
    // L2: [d2|f3] from cat3 -> cat2 ch 128..224   WM4 BN2: NT=32 NOCG=3 total=768 ORD0
    k_mconv<4,1,4,1,2,2,0,0,1,1><<<dim3(768), 256, 0, stream>>>(
        cat3b,416,416, 32,18, wp[8],6, cat2b,224,128, nullptr,0,nullptr, nullptr,0, nullptr, zb,
        96,64,64,8, 7, 32,3,96, 0);
    // L1: [d1|f2|pad] from cat2 -> cat1 ch 64..112   WM4 BN3: NT=128 NOCG=1 total=1024 ORD0
    k_mconv<4,1,4,1,3,2,0,0,1,1><<<dim3(1024), 256, 0, stream>>>(
        cat2b,224,224, 64,34, wp[9],3, cat1b,112,64, nullptr,0,nullptr, nullptr,0, nullptr, zb,
        48,128,128,16, 4, 128,1,128, 0);
    // u10 + fused global max-pool   WM4 BN2: NT=561 total=4488 ORD0
    k_mconv<4,1,4,1,2,2,2,0,1,1><<<dim3(4488), 256, 0, stream>>>(
        cat1b,112,112, 128,66, wp[10],2, nullptr,0,0, nullptr,0,nullptr, nullptr,0, featb, zb,
        32,257,257,33, 2, 561,1,561, 0);
    // FC
    k_fc<<<dim3(1), dim3(64), 0, stream>>>(featb, wfc, out);
}

// Round 11
// 355.355 us; speedup vs baseline: 2.1440x; 1.0686x over previous
//
#include <hip/hip_runtime.h>

#define DEV __device__ __forceinline__

typedef __attribute__((ext_vector_type(4))) int i32x4;

// qi = 128*wq8(y) as int
DEV int wqi(float y) {
    int q = (int)rintf(y * 128.0f);
    return q < -127 ? -127 : (q > 127 ? 127 : q);
}
DEV unsigned encf(float f) { unsigned u = __float_as_uint(f); return (u & 0x80000000u) ? ~u : (u | 0x80000000u); }
DEV float decf(unsigned u) { return (u & 0x80000000u) ? __uint_as_float(u ^ 0x80000000u) : __uint_as_float(~u); }
DEV float wq8f(float x) {
    float q = rintf(x * 128.0f) * 0.0078125f;
    return fminf(fmaxf(q, -0.9921875f), 0.9921875f);
}

// async global->LDS, 16B per lane, dest = uniform base + lane*16 (linear)
#define GLOAD16(g, l) __builtin_amdgcn_global_load_lds( \
    (const __attribute__((address_space(1))) void*)(g), \
    (__attribute__((address_space(3))) void*)(l), 16, 0, 0)

// ---------------- i8 weight pack, LDS-staged coalesced transpose ----------------
struct PackDesc {
    const float* w0; const float* w1; uint4* dst;
    int OC0, OC1, CinW, K, noct, nch64u, ndup;
};
struct PackArgs { PackDesc d[11]; int bofs[12]; };

__global__ void __launch_bounds__(256) k_packall(PackArgs a) {
    __shared__ unsigned char sb[16 * (64 * 16 + 4)];
    const int b = blockIdx.x;
    int i = 0;
    #pragma unroll
    for (int j = 1; j < 11; ++j) if (b >= a.bofs[j]) i = j;
    const PackDesc D = a.d[i];
    const int b2 = b - a.bofs[i];
    const int oct = b2 % D.noct;
    const int ch64u = b2 / D.noct;
    const int K2 = D.K * D.K;
    const int row_elems = 64 * K2;
    const int SSTR = row_elems + 4;
    const int QR = row_elems / 4;
    const int NQ = 16 * QR;
    const int cin0 = ch64u * 64;
    const int tid = threadIdx.x;

    for (int q = tid; q < NQ; q += 256) {
        const int r = q / QR, j = q - r * QR;
        const int oc = oct * 16 + r;
        const float* src = nullptr; int oci = 0;
        if (oc < D.OC0) { src = D.w0; oci = oc; }
        else if (oc < D.OC0 + D.OC1) { src = D.w1; oci = oc - D.OC0; }
        const int e0 = j * 4;
        float v[4] = {0.f, 0.f, 0.f, 0.f};
        if (src != nullptr) {
            const float* p = src + ((size_t)oci * D.CinW + cin0) * K2 + e0;
            const int cin_last = cin0 + (e0 + 3) / K2;
            if (cin_last < D.CinW) {
                const float4 f4 = *(const float4*)p;
                v[0] = f4.x; v[1] = f4.y; v[2] = f4.z; v[3] = f4.w;
            } else {
                #pragma unroll
                for (int e = 0; e < 4; ++e) {
                    const int cin = cin0 + (e0 + e) / K2;
                    if (cin < D.CinW) v[e] = p[e];
                }
            }
        }
        unsigned pk = 0;
        #pragma unroll
        for (int e = 0; e < 4; ++e) pk |= ((unsigned)(wqi(v[e]) & 255)) << (e * 8);
        *(unsigned*)&sb[r * SSTR + e0] = pk;
    }
    __syncthreads();

    const int outN = K2 * 64;
    for (int idx = tid; idx < outN; idx += 256) {
        const int kpos = idx >> 6, lane = idx & 63;
        const int l15 = lane & 15, g = lane >> 4;
        unsigned wd[4] = {0u, 0u, 0u, 0u};
        #pragma unroll
        for (int e = 0; e < 16; ++e) {
            const unsigned bval = sb[l15 * SSTR + (g * 16 + e) * K2 + kpos];
            wd[e >> 2] |= bval << ((e & 3) * 8);
        }
        uint4 u; u.x = wd[0]; u.y = wd[1]; u.z = wd[2]; u.w = wd[3];
        for (int d = 0; d < D.ndup; ++d) {
            const int ch64 = ch64u + d * D.nch64u;
            D.dst[((size_t)(ch64 * K2 + kpos) * D.noct + oct) * 64 + lane] = u;
        }
    }
}

// ---------------- conv1: LDS-tiled f32 vector conv (exact chain), i8 out ----------------
__global__ void __launch_bounds__(256) k_conv1(const float* __restrict__ x, const float* __restrict__ w1,
                                               signed char* __restrict__ cat1) {
    __shared__ float sw2[36][64];
    __shared__ float sin_[4][17][17];
    const int tid = threadIdx.x;
    const int n = blockIdx.y;
    const int oh0 = (blockIdx.x >> 4) * 8, ow0 = (blockIdx.x & 15) * 8;
    for (int i = tid; i < 2304; i += 256) sw2[i % 36][i / 36] = wq8f(w1[i]);
    const int ih0 = oh0 * 2 - 1, iw0 = ow0 * 2 - 1;
    for (int i = tid; i < 4 * 289; i += 256) {
        const int c = i / 289, rem = i % 289, r = rem / 17, cc = rem % 17;
        const int ih = ih0 + r, iw = iw0 + cc;
        float v = 0.f;
        if ((unsigned)ih < 256u && (unsigned)iw < 256u) v = x[((size_t)(n * 4 + c) * 256 + ih) * 256 + iw];
        sin_[c][r][cc] = v;
    }
    __syncthreads();
    const int sp = tid & 63, ocg = tid >> 6;
    const int oh = sp >> 3, ow = sp & 7;
    float acc[16];
    #pragma unroll
    for (int j = 0; j < 16; ++j) acc[j] = 0.f;
    #pragma unroll
    for (int c = 0; c < 4; ++c)
    #pragma unroll
    for (int kh = 0; kh < 3; ++kh)
    #pragma unroll
    for (int kw = 0; kw < 3; ++kw) {
        const float v = sin_[c][oh * 2 + kh][ow * 2 + kw];
        const float4* wp4 = (const float4*)&sw2[c * 9 + kh * 3 + kw][ocg * 16];
        #pragma unroll
        for (int q = 0; q < 4; ++q) {
            const float4 wv = wp4[q];
            acc[q * 4 + 0] = fmaf(v, wv.x, acc[q * 4 + 0]);
            acc[q * 4 + 1] = fmaf(v, wv.y, acc[q * 4 + 1]);
            acc[q * 4 + 2] = fmaf(v, wv.z, acc[q * 4 + 2]);
            acc[q * 4 + 3] = fmaf(v, wv.w, acc[q * 4 + 3]);
        }
    }
    const size_t pix = ((size_t)(n * 128) + oh0 + oh) * 128 + ow0 + ow;
    unsigned wd[4] = {0u, 0u, 0u, 0u};
    #pragma unroll
    for (int j = 0; j < 16; ++j)
        wd[j >> 2] |= ((unsigned)(wqi(acc[j]) & 255)) << ((j & 3) * 8);
    uint4 u; u.x = wd[0]; u.y = wd[1]; u.z = wd[2]; u.w = wd[3];
    *(uint4*)(cat1 + pix * 112 + ocg * 16) = u;
}

__global__ void k_init(unsigned* __restrict__ feat, uint4* __restrict__ zbuf) {
    feat[threadIdx.x] = encf(-2.0f);
    if (threadIdx.x < 64) { uint4 z; z.x = z.y = z.z = z.w = 0u; zbuf[threadIdx.x] = z; }
}

__global__ void k_fc(const unsigned* __restrict__ feat, const float* __restrict__ wfc,
                     float* __restrict__ out) {
    int n = threadIdx.x;
    if (n < 8) {
        float s = 0.f;
        for (int c = 0; c < 32; ++c) s += decf(feat[n * 32 + c]) * wq8f(wfc[c]);
        out[n] = wq8f(s);
    }
}

// ---------------- K-split partial combiner ----------------
// val = sum_s p[s]*radix^(nsl-1-s); y = (float)((double)val*inv); dst = i8 wqi(y).
// radix=1 -> plain K-split sum (identical to old single-acc path: power-of-2 scale
// commutes with int->float rounding). 4 oc per thread.
__global__ void __launch_bounds__(256) k_comb(const int* __restrict__ ps, int nsl, int radix,
                                              int NP, int OC, double inv,
                                              signed char* __restrict__ dst, int dstr, int dch) {
    const int t = blockIdx.x * 256 + threadIdx.x;
    const int total = NP * (OC / 4);
    if (t >= total) return;
    const int opc = OC / 4;
    const int pix = t / opc, oc0 = (t - pix * opc) * 4;
    const size_t base = (size_t)pix * OC + oc0;
    const size_t NPOC = (size_t)NP * OC;
    long v0 = 0, v1 = 0, v2 = 0, v3 = 0;
    for (int s = 0; s < nsl; ++s) {
        const int4 p = *(const int4*)(ps + s * NPOC + base);
        v0 = v0 * radix + p.x; v1 = v1 * radix + p.y;
        v2 = v2 * radix + p.z; v3 = v3 * radix + p.w;
    }
    unsigned pk = 0;
    pk |= (unsigned)(wqi((float)((double)v0 * inv)) & 255);
    pk |= (unsigned)(wqi((float)((double)v1 * inv)) & 255) << 8;
    pk |= (unsigned)(wqi((float)((double)v2 * inv)) & 255) << 16;
    pk |= (unsigned)(wqi((float)((double)v3 * inv)) & 255) << 24;
    *(unsigned*)(dst + (size_t)pix * dstr + dch + oc0) = pk;
}

// ---------------- implicit-GEMM i8 MFMA conv ----------------
// Grid adds a K-slice axis: ORD0: work -> ocg, tile, n, slice; ORD1: tile, n, ocg, slice.
// Slice offsets: input cin += slice*nch*64; weights += slice*nch*K2*noct*64.
// MODE 0: dst=i8; MODE 1: gate digits; MODE 2: feat max; MODE 3: i32 partial to
// ps[((slice*8+n)*OH*OW + pix)*OCv + oc] (exclusive writes, combined by k_comb).
template<int K, int STR, int WM, int WN, int BN, int NBUF, int MODE, int RESF, int NSLICE, int NCHPS>
__global__ void __launch_bounds__(256) k_mconv(
    const signed char* __restrict__ s0, int Ctot, int st0,
    int S, int padeff,
    const uint4* __restrict__ wqp, int noct,
    signed char* __restrict__ dst, int dstr, int dch,
    signed char* __restrict__ dhl, int dhlstr, short* __restrict__ dj,
    const void* __restrict__ res, int rstr,
    unsigned* __restrict__ feat, int* __restrict__ ps,
    const signed char* __restrict__ zbuf,
    int OCv, int OH, int OW, int TILES_W, int nch,
    int NT, int NOCG, int swzq, int ORD)
{
    constexpr int TH = WM * 4;
    constexpr int RH = (TH - 1) * STR + K, RW = 7 * STR + K;
    constexpr int UPPS = 5;
    constexpr int K2 = K * K;
    constexpr int NUS = RH * RW * UPPS;
    constexpr int ROUNDS = (NUS + 255) / 256;
    constexpr int NUPS = ROUNDS * 256;
    constexpr int AHEAD = NBUF - 1;
    __shared__ uint4 lds[NBUF * NUPS];
    __shared__ float sred[4][2][16];

    const int tid = threadIdx.x, lane = tid & 63, w = tid >> 6;
    const int wm = w % WM, wn = w / WM;
    const int l15 = lane & 15, g = lane >> 4;

    const int b = blockIdx.x;
    const int work = (b & 7) * swzq + (b >> 3);
    int tile, n, ocg, slice;
    if (ORD == 0) {
        ocg = work % NOCG; const int t2 = work / NOCG;
        tile = t2 % NT; const int t3 = t2 / NT;
        n = t3 & 7; slice = t3 >> 3;
    } else {
        tile = work % NT; const int t2 = work / NT;
        n = t2 & 7; const int t3 = t2 >> 3;
        ocg = t3 % NOCG; slice = t3 / NOCG;
    }
    const int cin_off = slice * nch * 64;
    const uint4* wqpS = wqp + (size_t)slice * nch * K2 * noct * 64;

    const int tileh = tile / TILES_W, tilew = tile % TILES_W;
    const int oh0 = tileh * TH, ow0 = tilew * 8;
    const int ih0 = oh0 * STR - padeff, iw0 = ow0 * STR - padeff;
    const int blk_oct0 = ocg * (WN * BN);

    int pixb[2];
    #pragma unroll
    for (int am = 0; am < 2; ++am) {
        const int sp = wm * 32 + am * 16 + l15;
        pixb[am] = ((sp >> 3) * STR) * RW + (sp & 7) * STR;
    }

    i32x4 acc[2][BN];
    #pragma unroll
    for (int am = 0; am < 2; ++am)
        #pragma unroll
        for (int bn = 0; bn < BN; ++bn) acc[am][bn] = (i32x4){0, 0, 0, 0};
    long acc64[(NSLICE > 1) ? 2 * BN * 4 : 1];
    #pragma unroll
    for (int q = 0; q < ((NSLICE > 1) ? 2 * BN * 4 : 1); ++q) acc64[q] = 0;

    auto issue = [&](int ch, int buf) {
        uint4* lb = &lds[buf * NUPS];
        #pragma unroll
        for (int rd = 0; rd < ROUNDS; ++rd) {
            const int d = rd * 256 + tid;
            const signed char* gp = zbuf;
            if (d < NUS) {
                const int pix = d / UPPS;
                const int u = d - pix * UPPS;
                const int r = pix / RW, c = pix - r * RW;
                const int ih = ih0 + r, iw = iw0 + c;
                const int cin = cin_off + ch * 64 + u * 16;
                if (u < 4 && (unsigned)ih < (unsigned)S && (unsigned)iw < (unsigned)S && cin < Ctot)
                    gp = s0 + (((size_t)n * S + ih) * S + iw) * st0 + cin;
            }
            GLOAD16(gp, lb + rd * 256 + (tid & ~63));
        }
    };

    #pragma unroll
    for (int i = 0; i < AHEAD; ++i) if (i < nch) issue(i, i % NBUF);

    for (int ch = 0; ch < nch; ++ch) {
        if (ch + AHEAD < nch) issue(ch + AHEAD, (ch + AHEAD) % NBUF);
        const int infl = (nch - 1 - ch < AHEAD) ? nch - 1 - ch : AHEAD;
        if (infl >= 2)      __builtin_amdgcn_s_waitcnt(0xF70 | (2 * ROUNDS));
        else if (infl == 1) __builtin_amdgcn_s_waitcnt(0xF70 | ROUNDS);
        else                __builtin_amdgcn_s_waitcnt(0xF70);
        __builtin_amdgcn_s_barrier();
        __builtin_amdgcn_sched_barrier(0);
        const int bufo = (ch % NBUF) * NUPS;
        const int pb0 = bufo + pixb[0] * UPPS + g;
        const int pb1 = bufo + pixb[1] * UPPS + g;
        const size_t wbase = ((size_t)ch * K2 * noct + blk_oct0 + wn * BN) * 64 + lane;
        #pragma unroll
        for (int kpos = 0; kpos < K2; ++kpos) {
            const int kh = kpos / K, kw = kpos % K;
            const int po = (kh * RW + kw) * UPPS;
            i32x4 bfr[BN];
            #pragma unroll
            for (int bn = 0; bn < BN; ++bn) {
                union { uint4 u; i32x4 v; } bu;
                bu.u = wqpS[wbase + ((size_t)kpos * noct + bn) * 64];
                bfr[bn] = bu.v;
            }
            union { uint4 u; i32x4 v; } a0, a1;
            a0.u = lds[pb0 + po];
            a1.u = lds[pb1 + po];
            #pragma unroll
            for (int bn = 0; bn < BN; ++bn) {
                acc[0][bn] = __builtin_amdgcn_mfma_i32_16x16x64_i8(a0.v, bfr[bn], acc[0][bn], 0, 0, 0);
                acc[1][bn] = __builtin_amdgcn_mfma_i32_16x16x64_i8(a1.v, bfr[bn], acc[1][bn], 0, 0, 0);
            }
        }
        if constexpr (NSLICE > 1) {
            if (((ch + 1) & (NCHPS - 1)) == 0) {
                #pragma unroll
                for (int am = 0; am < 2; ++am)
                #pragma unroll
                for (int bn = 0; bn < BN; ++bn) {
                    #pragma unroll
                    for (int rg = 0; rg < 4; ++rg) {
                        acc64[(am * BN + bn) * 4 + rg] = acc64[(am * BN + bn) * 4 + rg] * 256 + (long)acc[am][bn][rg];
                    }
                    acc[am][bn] = (i32x4){0, 0, 0, 0};
                }
            }
        }
        __builtin_amdgcn_sched_barrier(0);
        __builtin_amdgcn_s_barrier();
    }

    if constexpr (MODE == 2) {
        #pragma unroll
        for (int bn = 0; bn < BN; ++bn) {
            float m = -2.0f;
            #pragma unroll
            for (int am = 0; am < 2; ++am)
                #pragma unroll
                for (int rg = 0; rg < 4; ++rg) {
                    const int sp = wm * 32 + am * 16 + g * 4 + rg;
                    const int oh = oh0 + (sp >> 3), ow = ow0 + (sp & 7);
                    float v = -2.0f;
                    if (oh < OH && ow < OW) {
                        const float y = (float)acc[am][bn][rg] * (1.f / 16384.f);
                        v = (float)wqi(y) * 0.0078125f;
                    }
                    m = fmaxf(m, v);
                }
            m = fmaxf(m, __shfl_xor(m, 16));
            m = fmaxf(m, __shfl_xor(m, 32));
            if (lane < 16) sred[w][bn][l15] = m;
        }
        __syncthreads();
        if (tid < BN * 16) {
            const int bn = tid >> 4, l = tid & 15;
            float mm = sred[0][bn][l];
            #pragma unroll
            for (int i = 1; i < WM * WN; ++i) mm = fmaxf(mm, sred[i][bn][l]);
            atomicMax(&feat[n * 32 + (blk_oct0 + bn) * 16 + l], encf(mm));
        }
    } else if constexpr (MODE == 3) {
        #pragma unroll
        for (int am = 0; am < 2; ++am)
        #pragma unroll
        for (int bn = 0; bn < BN; ++bn)
        #pragma unroll
        for (int rg = 0; rg < 4; ++rg) {
            const int sp = wm * 32 + am * 16 + g * 4 + rg;
            const int oh = oh0 + (sp >> 3), ow = ow0 + (sp & 7);
            const int oc = (blk_oct0 + wn * BN + bn) * 16 + l15;
            if (oh < OH && ow < OW && oc < OCv) {
                ps[(((size_t)slice * 8 + n) * OH * OW + (size_t)oh * OW + ow) * OCv + oc] = acc[am][bn][rg];
            }
        }
    } else {
        #pragma unroll
        for (int am = 0; am < 2; ++am)
        #pragma unroll
        for (int bn = 0; bn < BN; ++bn)
        #pragma unroll
        for (int rg = 0; rg < 4; ++rg) {
            const int sp = wm * 32 + am * 16 + g * 4 + rg;
            const int oh = oh0 + (sp >> 3), ow = ow0 + (sp & 7);
            const int oc = (blk_oct0 + wn * BN + bn) * 16 + l15;
            if (oh < OH && ow < OW && oc < OCv) {
                const size_t pixo = (size_t)(n * OH + oh) * OW + ow;
                float y;
                if constexpr (NSLICE == 1)      y = (float)acc[am][bn][rg] * (1.f / 16384.f);
                else if constexpr (NSLICE == 2) y = (float)((double)acc64[(am * BN + bn) * 4 + rg] * (1.0 / 2097152.0));
                else                            y = (float)((double)acc64[(am * BN + bn) * 4 + rg] * (1.0 / 268435456.0));
                const int qi = wqi(y);
                if constexpr (MODE == 0) {
                    dst[pixo * dstr + dch + oc] = (signed char)qi;
                } else {
                    const int rvi = (RESF == 1) ? (int)((const signed char*)res)[pixo * rstr + oc]
                                                : (int)((const short*)res)[pixo * rstr + oc];
                    const int j = (128 - qi) * rvi;
                    const int d0 = ((j + 128) & 255) - 128;
                    const int t1 = (j - d0) >> 8;
                    if constexpr (RESF == 1) {
                        dhl[pixo * dhlstr + oc] = (signed char)t1;
                        dhl[pixo * dhlstr + 512 + oc] = (signed char)d0;
                        dj[pixo * 512 + oc] = (short)j;
                    } else {
                        const int d1 = ((t1 + 128) & 255) - 128;
                        const int d2 = (t1 - d1) >> 8;
                        dhl[pixo * dhlstr + oc] = (signed char)d2;
                        dhl[pixo * dhlstr + 512 + oc] = (signed char)d1;
                        dhl[pixo * dhlstr + 1024 + oc] = (signed char)d0;
                    }
                }
            }
        }
    }
}

extern "C" void kernel_launch(void* const* d_in, const int* in_sizes, int n_in,
                              void* d_out, int out_size, void* d_ws, size_t ws_size,
                              hipStream_t stream)
{
    (void)in_sizes; (void)n_in; (void)out_size; (void)ws_size;
    const float* x = (const float*)d_in[0];
    const float* wfc = (const float*)d_in[16];
    float* out = (float*)d_out;

    char* ws = (char*)d_ws;
    size_t off = 0;
    auto alloc = [&](size_t bytes) { char* p = ws + off; off += (bytes + 255) & ~(size_t)255; return p; };

    // {w0 idx, OC0, w1 idx, OC1, CinW, K, noct, nch64u, ndup}
    struct PH { int i0, OC0, i1, OC1, CinW, K, noct, nch64u, ndup; };
    static const PH ph[11] = {
        {2, 128, -1, 0,  64, 3,  8, 1, 1},   // 0 conv2
        {3, 256, -1, 0, 128, 3, 16, 2, 1},   // 1 conv3
        {4, 512, -1, 0, 256, 3, 32, 4, 1},   // 2 conv4
        {5, 512, -1, 0, 512, 3, 32, 8, 1},   // 3 r11
        {6, 512, -1, 0, 512, 3, 32, 8, 1},   // 4 r12
        {7, 512, -1, 0, 512, 3, 32, 8, 2},   // 5 r21 (2 slices)
        {8, 512, -1, 0, 512, 3, 32, 8, 1},   // 6 r22
        {9, 128, 12, 32, 512, 4, 10, 8, 3},  // 7 L3 = wd3|wu43 (3 slices)
        {10, 64, 13, 32, 416, 4,  6, 7, 1},  // 8 L2 = wd2|wu32
        {11,  4, 14, 32, 224, 4,  3, 4, 1},  // 9 L1 = wd1|wu21 (+12 zero oc)
        {15, 32, -1, 0, 100, 4,  2, 2, 1}};  // 10 u10

    PackArgs pa;
    int bacc = 0;
    uint4* wp[11];
    for (int i = 0; i < 11; ++i) {
        const int nch64 = ph[i].nch64u * ph[i].ndup;
        const int nel = nch64 * ph[i].K * ph[i].K * ph[i].noct * 64;
        wp[i] = (uint4*)alloc((size_t)nel * 16);
        pa.d[i].w0 = (const float*)d_in[ph[i].i0];
        pa.d[i].w1 = (ph[i].i1 >= 0) ? (const float*)d_in[ph[i].i1] : nullptr;
        pa.d[i].dst = wp[i];
        pa.d[i].OC0 = ph[i].OC0; pa.d[i].OC1 = ph[i].OC1;
        pa.d[i].CinW = ph[i].CinW; pa.d[i].K = ph[i].K; pa.d[i].noct = ph[i].noct;
        pa.d[i].nch64u = ph[i].nch64u; pa.d[i].ndup = ph[i].ndup;
        pa.bofs[i] = bacc;
        bacc += ph[i].noct * ph[i].nch64u;
    }
    pa.bofs[11] = bacc;

    signed char* cat1b = (signed char*)alloc((size_t)8*128*128*112);  // c1|d1|f2|pad12
    signed char* cat2b = (signed char*)alloc((size_t)8*64*64*224);    // c2|d2|f3
    signed char* cat3b = (signed char*)alloc((size_t)8*32*32*416);    // c3|d3|f4
    signed char* c4b   = (signed char*)alloc((size_t)8*16*16*512);
    signed char* r11b  = (signed char*)alloc((size_t)8*16*16*512);    // also r21 out
    signed char* r12d  = (signed char*)alloc((size_t)8*16*16*1024);   // r12 digits hi|lo
    short*       r12j  = (short*)alloc((size_t)8*16*16*512 * 2);      // r12 as i16 j (gate res)
    signed char* r22d  = (signed char*)alloc((size_t)8*16*16*1536);   // r22 digits j2|j1|j0
    int*         psum  = (int*)alloc((size_t)3*8*32*32*160 * 4);      // K-split partials (16MB)
    unsigned*    featb = (unsigned*)alloc(256 * 4);
    uint4*       zbuf  = (uint4*)alloc(1024);

    k_packall<<<dim3((unsigned)bacc), dim3(256), 0, stream>>>(pa);
    k_init<<<dim3(1), dim3(256), 0, stream>>>(featb, zbuf);
    k_conv1<<<dim3(256, 8), dim3(256), 0, stream>>>(x, (const float*)d_in[1], cat1b);

    const signed char* zb = (const signed char*)zbuf;

    // conv2: cat1 ch0..64 -> cat2 ch0..128   NT=64 NOCG=2 total=1024  ORD0
    k_mconv<3,2,2,2,2,1,0,0,1,1><<<dim3(1024), 256, 0, stream>>>(
        cat1b,64,112, 128,1, wp[0],8, cat2b,224,0, nullptr,0,nullptr, nullptr,0, nullptr,nullptr, zb,
        128,64,64,8, 1, 64,2,128, 0);
    // conv3: cat2 -> cat3 ch0..256           NT=16 NOCG=4 total=512  ORD0
    k_mconv<3,2,2,2,2,2,0,0,1,1><<<dim3(512), 256, 0, stream>>>(
        cat2b,128,224, 64,1, wp[1],16, cat3b,416,0, nullptr,0,nullptr, nullptr,0, nullptr,nullptr, zb,
        256,32,32,4, 2, 16,4,64, 0);
    // conv4: cat3 -> psum (2-way K-split)    NT=4 NOCG=16 NSLC=2 total=1024  ORD1
    k_mconv<3,2,2,2,1,2,3,0,1,1><<<dim3(1024), 256, 0, stream>>>(
        cat3b,256,416, 32,1, wp[2],32, nullptr,0,0, nullptr,0,nullptr, nullptr,0, nullptr,psum, zb,
        512,16,16,2, 2, 4,16,128, 1);
    k_comb<<<dim3(1024), 256, 0, stream>>>(psum, 2, 1, 2048, 512, 1.0/16384.0, c4b, 512, 0);
    // r11 (2-way K-split)
    k_mconv<3,1,2,2,1,3,3,0,1,1><<<dim3(1024), 256, 0, stream>>>(
        c4b,512,512, 16,1, wp[3],32, nullptr,0,0, nullptr,0,nullptr, nullptr,0, nullptr,psum, zb,
        512,16,16,2, 4, 4,16,128, 1);
    k_comb<<<dim3(1024), 256, 0, stream>>>(psum, 2, 1, 2048, 512, 1.0/16384.0, r11b, 512, 0);
    // r12 = (1-q(conv(r11)))*c4 -> digits + i16
    k_mconv<3,1,2,2,1,3,1,1,1,1><<<dim3(512), 256, 0, stream>>>(
        r11b,512,512, 16,1, wp[4],32, nullptr,0,0, r12d,1024,r12j, c4b,512, nullptr,nullptr, zb,
        512,16,16,2, 8, 4,16,64, 1);
    // r21: conv over r12 digits, 2 slice-groups -> psum
    k_mconv<3,1,2,2,1,3,3,0,1,1><<<dim3(1024), 256, 0, stream>>>(
        r12d,1024,1024, 16,1, wp[5],32, nullptr,0,0, nullptr,0,nullptr, nullptr,0, nullptr,psum, zb,
        512,16,16,2, 8, 4,16,128, 1);
    k_comb<<<dim3(1024), 256, 0, stream>>>(psum, 2, 256, 2048, 512, 1.0/2097152.0, r11b, 512, 0);
    // r22 = (1-q(conv(r21)))*r12 -> 3 digits (exact)
    k_mconv<3,1,2,2,1,3,1,2,1,1><<<dim3(512), 256, 0, stream>>>(
        r11b,512,512, 16,1, wp[6],32, nullptr,0,0, r22d,1536,nullptr, r12j,512, nullptr,nullptr, zb,
        512,16,16,2, 8, 4,16,64, 1);
    // L3: [d3|f4] from r22 digits, 3 slice-groups -> psum   NT=16 NOCG=5 NSLC=3 total=1920
    k_mconv<4,1,2,2,1,3,3,0,1,1><<<dim3(1920), 256, 0, stream>>>(
        r22d,1536,1536, 16,10, wp[7],10, nullptr,0,0, nullptr,0,nullptr, nullptr,0, nullptr,psum, zb,
        160,32,32,4, 8, 16,5,240, 1);
    k_comb<<<dim3(1280), 256, 0, stream>>>(psum, 3, 256, 8192, 160, 1.0/268435456.0, cat3b, 416, 256);
    // L2: [d2|f3] from cat3 -> cat2 ch 128..224   WM4 BN2: NT=32 NOCG=3 total=768 ORD0
    k_mconv<4,1,4,1,2,2,0,0,1,1><<<dim3(768), 256, 0, stream>>>(
        cat3b,416,416, 32,18, wp[8],6, cat2b,224,128, nullptr,0,nullptr, nullptr,0, nullptr,nullptr, zb,
        96,64,64,8, 7, 32,3,96, 0);
    // L1: [d1|f2|pad] from cat2 -> cat1 ch 64..112   WM4 BN3: NT=128 NOCG=1 total=1024 ORD0
    k_mconv<4,1,4,1,3,2,0,0,1,1><<<dim3(1024), 256, 0, stream>>>(
        cat2b,224,224, 64,34, wp[9],3, cat1b,112,64, nullptr,0,nullptr, nullptr,0, nullptr,nullptr, zb,
        48,128,128,16, 4, 128,1,128, 0);
    // u10 + fused global max-pool   WM4 BN2: NT=561 total=4488 ORD0
    k_mconv<4,1,4,1,2,2,2,0,1,1><<<dim3(4488), 256, 0, stream>>>(
        cat1b,112,112, 128,66, wp[10],2, nullptr,0,0, nullptr,0,nullptr, nullptr,0, featb,nullptr, zb,
        32,257,257,33, 2, 561,1,561, 0);
    // FC
    k_fc<<<dim3(1), dim3(64), 0, stream>>>(featb, wfc, out);
}

// Round 12
// 344.833 us; speedup vs baseline: 2.2094x; 1.0305x over previous
//
#include <hip/hip_runtime.h>

#define DEV __device__ __forceinline__

typedef __attribute__((ext_vector_type(4))) int i32x4;

// qi = 128*wq8(y) as int
DEV int wqi(float y) {
    int q = (int)rintf(y * 128.0f);
    return q < -127 ? -127 : (q > 127 ? 127 : q);
}
DEV unsigned encf(float f) { unsigned u = __float_as_uint(f); return (u & 0x80000000u) ? ~u : (u | 0x80000000u); }
DEV float decf(unsigned u) { return (u & 0x80000000u) ? __uint_as_float(u ^ 0x80000000u) : __uint_as_float(~u); }
DEV float wq8f(float x) {
    float q = rintf(x * 128.0f) * 0.0078125f;
    return fminf(fmaxf(q, -0.9921875f), 0.9921875f);
}

// async global->LDS, 16B per lane, dest = uniform base + lane*16 (linear)
#define GLOAD16(g, l) __builtin_amdgcn_global_load_lds( \
    (const __attribute__((address_space(1))) void*)(g), \
    (__attribute__((address_space(3))) void*)(l), 16, 0, 0)

// ---------------- i8 weight pack, LDS-staged coalesced transpose ----------------
struct PackDesc {
    const float* w0; const float* w1; uint4* dst;
    int OC0, OC1, CinW, K, noct, nch64u, ndup;
};
struct PackArgs { PackDesc d[11]; int bofs[12]; };

__global__ void __launch_bounds__(256) k_packall(PackArgs a) {
    __shared__ unsigned char sb[16 * (64 * 16 + 4)];
    const int b = blockIdx.x;
    int i = 0;
    #pragma unroll
    for (int j = 1; j < 11; ++j) if (b >= a.bofs[j]) i = j;
    const PackDesc D = a.d[i];
    const int b2 = b - a.bofs[i];
    const int oct = b2 % D.noct;
    const int ch64u = b2 / D.noct;
    const int K2 = D.K * D.K;
    const int row_elems = 64 * K2;
    const int SSTR = row_elems + 4;
    const int QR = row_elems / 4;
    const int NQ = 16 * QR;
    const int cin0 = ch64u * 64;
    const int tid = threadIdx.x;

    for (int q = tid; q < NQ; q += 256) {
        const int r = q / QR, j = q - r * QR;
        const int oc = oct * 16 + r;
        const float* src = nullptr; int oci = 0;
        if (oc < D.OC0) { src = D.w0; oci = oc; }
        else if (oc < D.OC0 + D.OC1) { src = D.w1; oci = oc - D.OC0; }
        const int e0 = j * 4;
        float v[4] = {0.f, 0.f, 0.f, 0.f};
        if (src != nullptr) {
            const float* p = src + ((size_t)oci * D.CinW + cin0) * K2 + e0;
            const int cin_last = cin0 + (e0 + 3) / K2;
            if (cin_last < D.CinW) {
                const float4 f4 = *(const float4*)p;
                v[0] = f4.x; v[1] = f4.y; v[2] = f4.z; v[3] = f4.w;
            } else {
                #pragma unroll
                for (int e = 0; e < 4; ++e) {
                    const int cin = cin0 + (e0 + e) / K2;
                    if (cin < D.CinW) v[e] = p[e];
                }
            }
        }
        unsigned pk = 0;
        #pragma unroll
        for (int e = 0; e < 4; ++e) pk |= ((unsigned)(wqi(v[e]) & 255)) << (e * 8);
        *(unsigned*)&sb[r * SSTR + e0] = pk;
    }
    __syncthreads();

    const int outN = K2 * 64;
    for (int idx = tid; idx < outN; idx += 256) {
        const int kpos = idx >> 6, lane = idx & 63;
        const int l15 = lane & 15, g = lane >> 4;
        unsigned wd[4] = {0u, 0u, 0u, 0u};
        #pragma unroll
        for (int e = 0; e < 16; ++e) {
            const unsigned bval = sb[l15 * SSTR + (g * 16 + e) * K2 + kpos];
            wd[e >> 2] |= bval << ((e & 3) * 8);
        }
        uint4 u; u.x = wd[0]; u.y = wd[1]; u.z = wd[2]; u.w = wd[3];
        for (int d = 0; d < D.ndup; ++d) {
            const int ch64 = ch64u + d * D.nch64u;
            D.dst[((size_t)(ch64 * K2 + kpos) * D.noct + oct) * 64 + lane] = u;
        }
    }
}

// ---------------- conv1: LDS-tiled f32 vector conv (exact chain), i8 out ----------------
__global__ void __launch_bounds__(256) k_conv1(const float* __restrict__ x, const float* __restrict__ w1,
                                               signed char* __restrict__ cat1) {
    __shared__ float sw2[36][64];
    __shared__ float sin_[4][17][17];
    const int tid = threadIdx.x;
    const int n = blockIdx.y;
    const int oh0 = (blockIdx.x >> 4) * 8, ow0 = (blockIdx.x & 15) * 8;
    for (int i = tid; i < 2304; i += 256) sw2[i % 36][i / 36] = wq8f(w1[i]);
    const int ih0 = oh0 * 2 - 1, iw0 = ow0 * 2 - 1;
    for (int i = tid; i < 4 * 289; i += 256) {
        const int c = i / 289, rem = i % 289, r = rem / 17, cc = rem % 17;
        const int ih = ih0 + r, iw = iw0 + cc;
        float v = 0.f;
        if ((unsigned)ih < 256u && (unsigned)iw < 256u) v = x[((size_t)(n * 4 + c) * 256 + ih) * 256 + iw];
        sin_[c][r][cc] = v;
    }
    __syncthreads();
    const int sp = tid & 63, ocg = tid >> 6;
    const int oh = sp >> 3, ow = sp & 7;
    float acc[16];
    #pragma unroll
    for (int j = 0; j < 16; ++j) acc[j] = 0.f;
    #pragma unroll
    for (int c = 0; c < 4; ++c)
    #pragma unroll
    for (int kh = 0; kh < 3; ++kh)
    #pragma unroll
    for (int kw = 0; kw < 3; ++kw) {
        const float v = sin_[c][oh * 2 + kh][ow * 2 + kw];
        const float4* wp4 = (const float4*)&sw2[c * 9 + kh * 3 + kw][ocg * 16];
        #pragma unroll
        for (int q = 0; q < 4; ++q) {
            const float4 wv = wp4[q];
            acc[q * 4 + 0] = fmaf(v, wv.x, acc[q * 4 + 0]);
            acc[q * 4 + 1] = fmaf(v, wv.y, acc[q * 4 + 1]);
            acc[q * 4 + 2] = fmaf(v, wv.z, acc[q * 4 + 2]);
            acc[q * 4 + 3] = fmaf(v, wv.w, acc[q * 4 + 3]);
        }
    }
    const size_t pix = ((size_t)(n * 128) + oh0 + oh) * 128 + ow0 + ow;
    unsigned wd[4] = {0u, 0u, 0u, 0u};
    #pragma unroll
    for (int j = 0; j < 16; ++j)
        wd[j >> 2] |= ((unsigned)(wqi(acc[j]) & 255)) << ((j & 3) * 8);
    uint4 u; u.x = wd[0]; u.y = wd[1]; u.z = wd[2]; u.w = wd[3];
    *(uint4*)(cat1 + pix * 112 + ocg * 16) = u;
}

__global__ void k_init(unsigned* __restrict__ feat, uint4* __restrict__ zbuf) {
    feat[threadIdx.x] = encf(-2.0f);
    if (threadIdx.x < 64) { uint4 z; z.x = z.y = z.z = z.w = 0u; zbuf[threadIdx.x] = z; }
}

__global__ void k_fc(const unsigned* __restrict__ feat, const float* __restrict__ wfc,
                     float* __restrict__ out) {
    int n = threadIdx.x;
    if (n < 8) {
        float s = 0.f;
        for (int c = 0; c < 32; ++c) s += decf(feat[n * 32 + c]) * wq8f(wfc[c]);
        out[n] = wq8f(s);
    }
}

// ---------------- K-split partial combiner (D digits x G same-scale groups) ----------------
// v = sum over digits: v = v*256 + (sum of G slice partials); y = (float)((double)v*inv).
// CMODE 0: dst i8 = wqi(y).
// CMODE 1 (r12 gate): rv = i8 res; j=(128-qi)*rv; digits hi/lo -> dhl, i16 j -> dj.
// CMODE 2 (r22 gate): rv = i16 res; j=(128-qi)*rv; 3 digits -> dhl.
template<int CMODE>
__global__ void __launch_bounds__(256) k_comb(const int* __restrict__ ps, int D, int G,
                                              int NP, int OC, double inv,
                                              signed char* __restrict__ dst, int dstr, int dch,
                                              const void* __restrict__ res, int rstr,
                                              signed char* __restrict__ dhl, int dhlstr,
                                              short* __restrict__ dj) {
    const int t = blockIdx.x * 256 + threadIdx.x;
    const int opc = OC / 4;
    const int total = NP * opc;
    if (t >= total) return;
    const int pix = t / opc, oc0 = (t - pix * opc) * 4;
    const size_t base = (size_t)pix * OC + oc0;
    const size_t NPOC = (size_t)NP * OC;
    long v[4] = {0, 0, 0, 0};
    int sidx = 0;
    for (int d = 0; d < D; ++d) {
        long s0 = 0, s1 = 0, s2 = 0, s3 = 0;
        for (int g = 0; g < G; ++g, ++sidx) {
            const int4 p = *(const int4*)(ps + sidx * NPOC + base);
            s0 += p.x; s1 += p.y; s2 += p.z; s3 += p.w;
        }
        v[0] = v[0] * 256 + s0; v[1] = v[1] * 256 + s1;
        v[2] = v[2] * 256 + s2; v[3] = v[3] * 256 + s3;
    }
    if constexpr (CMODE == 0) {
        unsigned pk = 0;
        #pragma unroll
        for (int j = 0; j < 4; ++j)
            pk |= (unsigned)(wqi((float)((double)v[j] * inv)) & 255) << (j * 8);
        *(unsigned*)(dst + (size_t)pix * dstr + dch + oc0) = pk;
    } else {
        #pragma unroll
        for (int j = 0; j < 4; ++j) {
            const int qi = wqi((float)((double)v[j] * inv));
            const int oc = oc0 + j;
            if constexpr (CMODE == 1) {
                const int rv = (int)((const signed char*)res)[(size_t)pix * rstr + oc];
                const int jj = (128 - qi) * rv;
                const int d0 = ((jj + 128) & 255) - 128;
                const int t1 = (jj - d0) >> 8;
                dhl[(size_t)pix * dhlstr + oc] = (signed char)t1;
                dhl[(size_t)pix * dhlstr + 512 + oc] = (signed char)d0;
                dj[(size_t)pix * 512 + oc] = (short)jj;
            } else {
                const int rv = (int)((const short*)res)[(size_t)pix * rstr + oc];
                const int jj = (128 - qi) * rv;
                const int d0 = ((jj + 128) & 255) - 128;
                const int t1 = (jj - d0) >> 8;
                const int d1 = ((t1 + 128) & 255) - 128;
                const int d2 = (t1 - d1) >> 8;
                dhl[(size_t)pix * dhlstr + oc] = (signed char)d2;
                dhl[(size_t)pix * dhlstr + 512 + oc] = (signed char)d1;
                dhl[(size_t)pix * dhlstr + 1024 + oc] = (signed char)d0;
            }
        }
    }
}

// ---------------- implicit-GEMM i8 MFMA conv ----------------
// Grid has a K-slice axis. ORD0: work -> ocg, tile, n, slice; ORD1: tile, n, ocg, slice.
// Slice offsets: input cin += slice*nch*64; weights += slice*nch*K2*noct*64.
// BN>=2 so each A-fragment ds_read feeds BN MFMAs (LDS-read-bound fix).
// MODE 0: dst=i8; MODE 2: feat max; MODE 3: i32 partial -> ps[((slice*8+n)*OHW+pix)*OCv+oc].
template<int K, int STR, int WM, int WN, int BN, int NBUF, int MODE>
__global__ void __launch_bounds__(256) k_mconv(
    const signed char* __restrict__ s0, int Ctot, int st0,
    int S, int padeff,
    const uint4* __restrict__ wqp, int noct,
    signed char* __restrict__ dst, int dstr, int dch,
    unsigned* __restrict__ feat, int* __restrict__ ps,
    const signed char* __restrict__ zbuf,
    int OCv, int OH, int OW, int TILES_W, int nch,
    int NT, int NOCG, int swzq, int ORD)
{
    constexpr int TH = WM * 4;
    constexpr int RH = (TH - 1) * STR + K, RW = 7 * STR + K;
    constexpr int UPPS = 5;
    constexpr int K2 = K * K;
    constexpr int NUS = RH * RW * UPPS;
    constexpr int ROUNDS = (NUS + 255) / 256;
    constexpr int NUPS = ROUNDS * 256;
    constexpr int AHEAD = NBUF - 1;
    __shared__ uint4 lds[NBUF * NUPS];
    __shared__ float sred[4][2][16];

    const int tid = threadIdx.x, lane = tid & 63, w = tid >> 6;
    const int wm = w % WM, wn = w / WM;
    const int l15 = lane & 15, g = lane >> 4;

    const int b = blockIdx.x;
    const int work = (b & 7) * swzq + (b >> 3);
    int tile, n, ocg, slice;
    if (ORD == 0) {
        ocg = work % NOCG; const int t2 = work / NOCG;
        tile = t2 % NT; const int t3 = t2 / NT;
        n = t3 & 7; slice = t3 >> 3;
    } else {
        tile = work % NT; const int t2 = work / NT;
        n = t2 & 7; const int t3 = t2 >> 3;
        ocg = t3 % NOCG; slice = t3 / NOCG;
    }
    const int cin_off = slice * nch * 64;
    const uint4* wqpS = wqp + (size_t)slice * nch * K2 * noct * 64;

    const int tileh = tile / TILES_W, tilew = tile % TILES_W;
    const int oh0 = tileh * TH, ow0 = tilew * 8;
    const int ih0 = oh0 * STR - padeff, iw0 = ow0 * STR - padeff;
    const int blk_oct0 = ocg * (WN * BN);

    int pixb[2];
    #pragma unroll
    for (int am = 0; am < 2; ++am) {
        const int sp = wm * 32 + am * 16 + l15;
        pixb[am] = ((sp >> 3) * STR) * RW + (sp & 7) * STR;
    }

    i32x4 acc[2][BN];
    #pragma unroll
    for (int am = 0; am < 2; ++am)
        #pragma unroll
        for (int bn = 0; bn < BN; ++bn) acc[am][bn] = (i32x4){0, 0, 0, 0};

    auto issue = [&](int ch, int buf) {
        uint4* lb = &lds[buf * NUPS];
        #pragma unroll
        for (int rd = 0; rd < ROUNDS; ++rd) {
            const int d = rd * 256 + tid;
            const signed char* gp = zbuf;
            if (d < NUS) {
                const int pix = d / UPPS;
                const int u = d - pix * UPPS;
                const int r = pix / RW, c = pix - r * RW;
                const int ih = ih0 + r, iw = iw0 + c;
                const int cin = cin_off + ch * 64 + u * 16;
                if (u < 4 && (unsigned)ih < (unsigned)S && (unsigned)iw < (unsigned)S && cin < Ctot)
                    gp = s0 + (((size_t)n * S + ih) * S + iw) * st0 + cin;
            }
            GLOAD16(gp, lb + rd * 256 + (tid & ~63));
        }
    };

    #pragma unroll
    for (int i = 0; i < AHEAD; ++i) if (i < nch) issue(i, i % NBUF);

    for (int ch = 0; ch < nch; ++ch) {
        if (ch + AHEAD < nch) issue(ch + AHEAD, (ch + AHEAD) % NBUF);
        const int infl = (nch - 1 - ch < AHEAD) ? nch - 1 - ch : AHEAD;
        if (infl >= 2)      __builtin_amdgcn_s_waitcnt(0xF70 | (2 * ROUNDS));
        else if (infl == 1) __builtin_amdgcn_s_waitcnt(0xF70 | ROUNDS);
        else                __builtin_amdgcn_s_waitcnt(0xF70);
        __builtin_amdgcn_s_barrier();
        __builtin_amdgcn_sched_barrier(0);
        const int bufo = (ch % NBUF) * NUPS;
        const int pb0 = bufo + pixb[0] * UPPS + g;
        const int pb1 = bufo + pixb[1] * UPPS + g;
        const size_t wbase = ((size_t)ch * K2 * noct + blk_oct0 + wn * BN) * 64 + lane;
        #pragma unroll
        for (int kpos = 0; kpos < K2; ++kpos) {
            const int kh = kpos / K, kw = kpos % K;
            const int po = (kh * RW + kw) * UPPS;
            i32x4 bfr[BN];
            #pragma unroll
            for (int bn = 0; bn < BN; ++bn) {
                union { uint4 u; i32x4 v; } bu;
                bu.u = wqpS[wbase + ((size_t)kpos * noct + bn) * 64];
                bfr[bn] = bu.v;
            }
            union { uint4 u; i32x4 v; } a0, a1;
            a0.u = lds[pb0 + po];
            a1.u = lds[pb1 + po];
            #pragma unroll
            for (int bn = 0; bn < BN; ++bn) {
                acc[0][bn] = __builtin_amdgcn_mfma_i32_16x16x64_i8(a0.v, bfr[bn], acc[0][bn], 0, 0, 0);
                acc[1][bn] = __builtin_amdgcn_mfma_i32_16x16x64_i8(a1.v, bfr[bn], acc[1][bn], 0, 0, 0);
            }
        }
        __builtin_amdgcn_sched_barrier(0);
        __builtin_amdgcn_s_barrier();
    }

    if constexpr (MODE == 2) {
        #pragma unroll
        for (int bn = 0; bn < BN; ++bn) {
            float m = -2.0f;
            #pragma unroll
            for (int am = 0; am < 2; ++am)
                #pragma unroll
                for (int rg = 0; rg < 4; ++rg) {
                    const int sp = wm * 32 + am * 16 + g * 4 + rg;
                    const int oh = oh0 + (sp >> 3), ow = ow0 + (sp & 7);
                    float v = -2.0f;
                    if (oh < OH && ow < OW) {
                        const float y = (float)acc[am][bn][rg] * (1.f / 16384.f);
                        v = (float)wqi(y) * 0.0078125f;
                    }
                    m = fmaxf(m, v);
                }
            m = fmaxf(m, __shfl_xor(m, 16));
            m = fmaxf(m, __shfl_xor(m, 32));
            if (lane < 16) sred[w][bn][l15] = m;
        }
        __syncthreads();
        if (tid < BN * 16) {
            const int bn = tid >> 4, l = tid & 15;
            float mm = sred[0][bn][l];
            #pragma unroll
            for (int i = 1; i < WM * WN; ++i) mm = fmaxf(mm, sred[i][bn][l]);
            atomicMax(&feat[n * 32 + (blk_oct0 + bn) * 16 + l], encf(mm));
        }
    } else if constexpr (MODE == 3) {
        #pragma unroll
        for (int am = 0; am < 2; ++am)
        #pragma unroll
        for (int bn = 0; bn < BN; ++bn)
        #pragma unroll
        for (int rg = 0; rg < 4; ++rg) {
            const int sp = wm * 32 + am * 16 + g * 4 + rg;
            const int oh = oh0 + (sp >> 3), ow = ow0 + (sp & 7);
            const int oc = (blk_oct0 + wn * BN + bn) * 16 + l15;
            if (oh < OH && ow < OW && oc < OCv) {
                ps[(((size_t)slice * 8 + n) * OH * OW + (size_t)oh * OW + ow) * OCv + oc] = acc[am][bn][rg];
            }
        }
    } else {
        #pragma unroll
        for (int am = 0; am < 2; ++am)
        #pragma unroll
        for (int bn = 0; bn < BN; ++bn)
        #pragma unroll
        for (int rg = 0; rg < 4; ++rg) {
            const int sp = wm * 32 + am * 16 + g * 4 + rg;
            const int oh = oh0 + (sp >> 3), ow = ow0 + (sp & 7);
            const int oc = (blk_oct0 + wn * BN + bn) * 16 + l15;
            if (oh < OH && ow < OW && oc < OCv) {
                const size_t pixo = (size_t)(n * OH + oh) * OW + ow;
                const float y = (float)acc[am][bn][rg] * (1.f / 16384.f);
                dst[pixo * dstr + dch + oc] = (signed char)wqi(y);
            }
        }
    }
}

extern "C" void kernel_launch(void* const* d_in, const int* in_sizes, int n_in,
                              void* d_out, int out_size, void* d_ws, size_t ws_size,
                              hipStream_t stream)
{
    (void)in_sizes; (void)n_in; (void)out_size; (void)ws_size;
    const float* x = (const float*)d_in[0];
    const float* wfc = (const float*)d_in[16];
    float* out = (float*)d_out;

    char* ws = (char*)d_ws;
    size_t off = 0;
    auto alloc = [&](size_t bytes) { char* p = ws + off; off += (bytes + 255) & ~(size_t)255; return p; };

    // {w0 idx, OC0, w1 idx, OC1, CinW, K, noct, nch64u, ndup}
    struct PH { int i0, OC0, i1, OC1, CinW, K, noct, nch64u, ndup; };
    static const PH ph[11] = {
        {2, 128, -1, 0,  64, 3,  8, 1, 1},   // 0 conv2
        {3, 256, -1, 0, 128, 3, 16, 2, 1},   // 1 conv3
        {4, 512, -1, 0, 256, 3, 32, 4, 1},   // 2 conv4
        {5, 512, -1, 0, 512, 3, 32, 8, 1},   // 3 r11
        {6, 512, -1, 0, 512, 3, 32, 8, 1},   // 4 r12
        {7, 512, -1, 0, 512, 3, 32, 8, 2},   // 5 r21 (2 digit copies)
        {8, 512, -1, 0, 512, 3, 32, 8, 1},   // 6 r22
        {9, 128, 12, 32, 512, 4, 10, 8, 3},  // 7 L3 = wd3|wu43 (3 digit copies)
        {10, 64, 13, 32, 416, 4,  6, 7, 1},  // 8 L2 = wd2|wu32
        {11,  4, 14, 32, 224, 4,  3, 4, 1},  // 9 L1 = wd1|wu21 (+12 zero oc)
        {15, 32, -1, 0, 100, 4,  2, 2, 1}};  // 10 u10

    PackArgs pa;
    int bacc = 0;
    uint4* wp[11];
    for (int i = 0; i < 11; ++i) {
        const int nch64 = ph[i].nch64u * ph[i].ndup;
        const int nel = nch64 * ph[i].K * ph[i].K * ph[i].noct * 64;
        wp[i] = (uint4*)alloc((size_t)nel * 16);
        pa.d[i].w0 = (const float*)d_in[ph[i].i0];
        pa.d[i].w1 = (ph[i].i1 >= 0) ? (const float*)d_in[ph[i].i1] : nullptr;
        pa.d[i].dst = wp[i];
        pa.d[i].OC0 = ph[i].OC0; pa.d[i].OC1 = ph[i].OC1;
        pa.d[i].CinW = ph[i].CinW; pa.d[i].K = ph[i].K; pa.d[i].noct = ph[i].noct;
        pa.d[i].nch64u = ph[i].nch64u; pa.d[i].ndup = ph[i].ndup;
        pa.bofs[i] = bacc;
        bacc += ph[i].noct * ph[i].nch64u;
    }
    pa.bofs[11] = bacc;

    signed char* cat1b = (signed char*)alloc((size_t)8*128*128*112);  // c1|d1|f2|pad12
    signed char* cat2b = (signed char*)alloc((size_t)8*64*64*224);    // c2|d2|f3
    signed char* cat3b = (signed char*)alloc((size_t)8*32*32*416);    // c3|d3|f4
    signed char* c4b   = (signed char*)alloc((size_t)8*16*16*512);
    signed char* r11b  = (signed char*)alloc((size_t)8*16*16*512);    // also r21 out
    signed char* r12d  = (signed char*)alloc((size_t)8*16*16*1024);   // r12 digits hi|lo
    short*       r12j  = (short*)alloc((size_t)8*16*16*512 * 2);      // r12 as i16 j (gate res)
    signed char* r22d  = (signed char*)alloc((size_t)8*16*16*1536);   // r22 digits j2|j1|j0
    int*         psum  = (int*)alloc((size_t)4*8*16*16*512 * 4);      // K-split partials (~17MB)
    unsigned*    featb = (unsigned*)alloc(256 * 4);
    uint4*       zbuf  = (uint4*)alloc(1024);

    k_packall<<<dim3((unsigned)bacc), dim3(256), 0, stream>>>(pa);
    k_init<<<dim3(1), dim3(256), 0, stream>>>(featb, zbuf);
    k_conv1<<<dim3(256, 8), dim3(256), 0, stream>>>(x, (const float*)d_in[1], cat1b);

    const signed char* zb = (const signed char*)zbuf;
    const void* nv = nullptr;

    // conv2: cat1 ch0..64 -> cat2 ch0..128   NT=64 NOCG=2 total=1024  ORD0
    k_mconv<3,2,2,2,2,1,0><<<dim3(1024), 256, 0, stream>>>(
        cat1b,64,112, 128,1, wp[0],8, cat2b,224,0, nullptr,nullptr, zb,
        128,64,64,8, 1, 64,2,128, 0);
    // conv3: cat2 -> cat3 ch0..256           NT=16 NOCG=4 total=512  ORD0
    k_mconv<3,2,2,2,2,2,0><<<dim3(512), 256, 0, stream>>>(
        cat2b,128,224, 64,1, wp[1],16, cat3b,416,0, nullptr,nullptr, zb,
        256,32,32,4, 2, 16,4,64, 0);
    // conv4 -> psum (4-way K-split, BN2)     NT=4 NOCG=8 NSLC=4 total=1024  ORD1
    k_mconv<3,2,2,2,2,1,3><<<dim3(1024), 256, 0, stream>>>(
        cat3b,256,416, 32,1, wp[2],32, nullptr,0,0, nullptr,(int*)psum, zb,
        512,16,16,2, 1, 4,8,128, 1);
    k_comb<0><<<dim3(1024), 256, 0, stream>>>(psum,1,4, 2048,512, 1.0/16384.0, c4b,512,0, nv,0, nullptr,0,nullptr);
    // r11 (WM4, BN2, 4-way K-split)          NT=2 NOCG=16 NSLC=4 total=1024  ORD1
    k_mconv<3,1,4,1,2,2,3><<<dim3(1024), 256, 0, stream>>>(
        c4b,512,512, 16,1, wp[3],32, nullptr,0,0, nullptr,psum, zb,
        512,16,16,2, 2, 2,16,128, 1);
    k_comb<0><<<dim3(1024), 256, 0, stream>>>(psum,1,4, 2048,512, 1.0/16384.0, r11b,512,0, nv,0, nullptr,0,nullptr);
    // r12 conv -> psum (2-way), gate in comb
    k_mconv<3,1,4,1,2,3,3><<<dim3(512), 256, 0, stream>>>(
        r11b,512,512, 16,1, wp[4],32, nullptr,0,0, nullptr,psum, zb,
        512,16,16,2, 4, 2,16,64, 1);
    k_comb<1><<<dim3(1024), 256, 0, stream>>>(psum,1,2, 2048,512, 1.0/16384.0, nullptr,0,0, c4b,512, r12d,1024,r12j);
    // r21: digits input, 4 slices = 2 digits x 2
    k_mconv<3,1,4,1,2,2,3><<<dim3(1024), 256, 0, stream>>>(
        r12d,1024,1024, 16,1, wp[5],32, nullptr,0,0, nullptr,psum, zb,
        512,16,16,2, 4, 2,16,128, 1);
    k_comb<0><<<dim3(1024), 256, 0, stream>>>(psum,2,2, 2048,512, 1.0/2097152.0, r11b,512,0, nv,0, nullptr,0,nullptr);
    // r22 conv -> psum (2-way), gate in comb (3 digits)
    k_mconv<3,1,4,1,2,3,3><<<dim3(512), 256, 0, stream>>>(
        r11b,512,512, 16,1, wp[6],32, nullptr,0,0, nullptr,psum, zb,
        512,16,16,2, 4, 2,16,64, 1);
    k_comb<2><<<dim3(1024), 256, 0, stream>>>(psum,1,2, 2048,512, 1.0/16384.0, nullptr,0,0, r12j,512, r22d,1536,nullptr);
    // L3: [d3|f4], WM4 BN2, 3 digit-slices   NT=8 NOCG=5 NSLC=3 total=960  ORD1
    k_mconv<4,1,4,1,2,2,3><<<dim3(960), 256, 0, stream>>>(
        r22d,1536,1536, 16,10, wp[7],10, nullptr,0,0, nullptr,psum, zb,
        160,32,32,4, 8, 8,5,120, 1);
    k_comb<0><<<dim3(1280), 256, 0, stream>>>(psum,3,1, 8192,160, 1.0/268435456.0, cat3b,416,256, nv,0, nullptr,0,nullptr);
    // L2: [d2|f3] from cat3 -> cat2 ch 128..224   WM4 BN2: NT=32 NOCG=3 total=768 ORD0
    k_mconv<4,1,4,1,2,2,0><<<dim3(768), 256, 0, stream>>>(
        cat3b,416,416, 32,18, wp[8],6, cat2b,224,128, nullptr,nullptr, zb,
        96,64,64,8, 7, 32,3,96, 0);
    // L1: [d1|f2|pad] from cat2 -> cat1 ch 64..112   WM4 BN3: NT=128 NOCG=1 total=1024 ORD0
    k_mconv<4,1,4,1,3,2,0><<<dim3(1024), 256, 0, stream>>>(
        cat2b,224,224, 64,34, wp[9],3, cat1b,112,64, nullptr,nullptr, zb,
        48,128,128,16, 4, 128,1,128, 0);
    // u10 + fused global max-pool   WM4 BN2: NT=561 total=4488 ORD0
    k_mconv<4,1,4,1,2,2,2><<<dim3(4488), 256, 0, stream>>>(
        cat1b,112,112, 128,66, wp[10],2, nullptr,0,0, featb,nullptr, zb,
        32,257,257,33, 2, 561,1,561, 0);
    // FC
    k_fc<<<dim3(1), dim3(64), 0, stream>>>(featb, wfc, out);
}

// Round 13
// 333.357 us; speedup vs baseline: 2.2854x; 1.0344x over previous
//
#include <hip/hip_runtime.h>

#define DEV __device__ __forceinline__

typedef __attribute__((ext_vector_type(4))) int i32x4;

// qi = 128*wq8(y) as int
DEV int wqi(float y) {
    int q = (int)rintf(y * 128.0f);
    return q < -127 ? -127 : (q > 127 ? 127 : q);
}
DEV unsigned encf(float f) { unsigned u = __float_as_uint(f); return (u & 0x80000000u) ? ~u : (u | 0x80000000u); }
DEV float decf(unsigned u) { return (u & 0x80000000u) ? __uint_as_float(u ^ 0x80000000u) : __uint_as_float(~u); }
DEV float wq8f(float x) {
    float q = rintf(x * 128.0f) * 0.0078125f;
    return fminf(fmaxf(q, -0.9921875f), 0.9921875f);
}

// async global->LDS, 16B per lane, dest = uniform base + lane*16 (linear)
#define GLOAD16(g, l) __builtin_amdgcn_global_load_lds( \
    (const __attribute__((address_space(1))) void*)(g), \
    (__attribute__((address_space(3))) void*)(l), 16, 0, 0)

// ---------------- i8 weight pack, LDS-staged coalesced transpose ----------------
// Output layout (block-contiguous): idx = (((oct/GSZ)*(NCHT*K2) + ch64*K2 + kpos)*GSZ
//   + oct%GSZ)*64 + lane, NCHT = nch64u*ndup. Each conv-block's per-chunk weight
//   window is one contiguous K2*GSZ KB region (compile-time-foldable offsets).
struct PackDesc {
    const float* w0; const float* w1; uint4* dst;
    int OC0, OC1, CinW, K, noct, nch64u, ndup, gsz;
};
struct PackArgs { PackDesc d[11]; int bofs[12]; };

__global__ void __launch_bounds__(256) k_packall(PackArgs a) {
    __shared__ unsigned char sb[16 * (64 * 16 + 4)];
    const int b = blockIdx.x;
    int i = 0;
    #pragma unroll
    for (int j = 1; j < 11; ++j) if (b >= a.bofs[j]) i = j;
    const PackDesc D = a.d[i];
    const int b2 = b - a.bofs[i];
    const int oct = b2 % D.noct;
    const int ch64u = b2 / D.noct;
    const int K2 = D.K * D.K;
    const int NCHT = D.nch64u * D.ndup;
    const int row_elems = 64 * K2;
    const int SSTR = row_elems + 4;
    const int QR = row_elems / 4;
    const int NQ = 16 * QR;
    const int cin0 = ch64u * 64;
    const int tid = threadIdx.x;
    const int og = oct / D.gsz, ol = oct % D.gsz;

    for (int q = tid; q < NQ; q += 256) {
        const int r = q / QR, j = q - r * QR;
        const int oc = oct * 16 + r;
        const float* src = nullptr; int oci = 0;
        if (oc < D.OC0) { src = D.w0; oci = oc; }
        else if (oc < D.OC0 + D.OC1) { src = D.w1; oci = oc - D.OC0; }
        const int e0 = j * 4;
        float v[4] = {0.f, 0.f, 0.f, 0.f};
        if (src != nullptr) {
            const float* p = src + ((size_t)oci * D.CinW + cin0) * K2 + e0;
            const int cin_last = cin0 + (e0 + 3) / K2;
            if (cin_last < D.CinW) {
                const float4 f4 = *(const float4*)p;
                v[0] = f4.x; v[1] = f4.y; v[2] = f4.z; v[3] = f4.w;
            } else {
                #pragma unroll
                for (int e = 0; e < 4; ++e) {
                    const int cin = cin0 + (e0 + e) / K2;
                    if (cin < D.CinW) v[e] = p[e];
                }
            }
        }
        unsigned pk = 0;
        #pragma unroll
        for (int e = 0; e < 4; ++e) pk |= ((unsigned)(wqi(v[e]) & 255)) << (e * 8);
        *(unsigned*)&sb[r * SSTR + e0] = pk;
    }
    __syncthreads();

    const int outN = K2 * 64;
    for (int idx = tid; idx < outN; idx += 256) {
        const int kpos = idx >> 6, lane = idx & 63;
        const int l15 = lane & 15, g = lane >> 4;
        unsigned wd[4] = {0u, 0u, 0u, 0u};
        #pragma unroll
        for (int e = 0; e < 16; ++e) {
            const unsigned bval = sb[l15 * SSTR + (g * 16 + e) * K2 + kpos];
            wd[e >> 2] |= bval << ((e & 3) * 8);
        }
        uint4 u; u.x = wd[0]; u.y = wd[1]; u.z = wd[2]; u.w = wd[3];
        for (int d = 0; d < D.ndup; ++d) {
            const int ch64 = ch64u + d * D.nch64u;
            D.dst[((size_t)((og * NCHT + ch64) * K2 + kpos) * D.gsz + ol) * 64 + lane] = u;
        }
    }
}

// ---------------- conv1: LDS-tiled f32 vector conv (exact chain), i8 out ----------------
__global__ void __launch_bounds__(256) k_conv1(const float* __restrict__ x, const float* __restrict__ w1,
                                               signed char* __restrict__ cat1) {
    __shared__ float sw2[36][64];
    __shared__ float sin_[4][17][17];
    const int tid = threadIdx.x;
    const int n = blockIdx.y;
    const int oh0 = (blockIdx.x >> 4) * 8, ow0 = (blockIdx.x & 15) * 8;
    for (int i = tid; i < 2304; i += 256) sw2[i % 36][i / 36] = wq8f(w1[i]);
    const int ih0 = oh0 * 2 - 1, iw0 = ow0 * 2 - 1;
    for (int i = tid; i < 4 * 289; i += 256) {
        const int c = i / 289, rem = i % 289, r = rem / 17, cc = rem % 17;
        const int ih = ih0 + r, iw = iw0 + cc;
        float v = 0.f;
        if ((unsigned)ih < 256u && (unsigned)iw < 256u) v = x[((size_t)(n * 4 + c) * 256 + ih) * 256 + iw];
        sin_[c][r][cc] = v;
    }
    __syncthreads();
    const int sp = tid & 63, ocg = tid >> 6;
    const int oh = sp >> 3, ow = sp & 7;
    float acc[16];
    #pragma unroll
    for (int j = 0; j < 16; ++j) acc[j] = 0.f;
    #pragma unroll
    for (int c = 0; c < 4; ++c)
    #pragma unroll
    for (int kh = 0; kh < 3; ++kh)
    #pragma unroll
    for (int kw = 0; kw < 3; ++kw) {
        const float v = sin_[c][oh * 2 + kh][ow * 2 + kw];
        const float4* wp4 = (const float4*)&sw2[c * 9 + kh * 3 + kw][ocg * 16];
        #pragma unroll
        for (int q = 0; q < 4; ++q) {
            const float4 wv = wp4[q];
            acc[q * 4 + 0] = fmaf(v, wv.x, acc[q * 4 + 0]);
            acc[q * 4 + 1] = fmaf(v, wv.y, acc[q * 4 + 1]);
            acc[q * 4 + 2] = fmaf(v, wv.z, acc[q * 4 + 2]);
            acc[q * 4 + 3] = fmaf(v, wv.w, acc[q * 4 + 3]);
        }
    }
    const size_t pix = ((size_t)(n * 128) + oh0 + oh) * 128 + ow0 + ow;
    unsigned wd[4] = {0u, 0u, 0u, 0u};
    #pragma unroll
    for (int j = 0; j < 16; ++j)
        wd[j >> 2] |= ((unsigned)(wqi(acc[j]) & 255)) << ((j & 3) * 8);
    uint4 u; u.x = wd[0]; u.y = wd[1]; u.z = wd[2]; u.w = wd[3];
    *(uint4*)(cat1 + pix * 112 + ocg * 16) = u;
}

__global__ void k_init(unsigned* __restrict__ feat, uint4* __restrict__ zbuf) {
    feat[threadIdx.x] = encf(-2.0f);
    if (threadIdx.x < 64) { uint4 z; z.x = z.y = z.z = z.w = 0u; zbuf[threadIdx.x] = z; }
}

__global__ void k_fc(const unsigned* __restrict__ feat, const float* __restrict__ wfc,
                     float* __restrict__ out) {
    int n = threadIdx.x;
    if (n < 8) {
        float s = 0.f;
        for (int c = 0; c < 32; ++c) s += decf(feat[n * 32 + c]) * wq8f(wfc[c]);
        out[n] = wq8f(s);
    }
}

// ---------------- K-split partial combiner (D digits x G same-scale groups) ----------------
template<int CMODE>
__global__ void __launch_bounds__(256) k_comb(const int* __restrict__ ps, int D, int G,
                                              int NP, int OC, double inv,
                                              signed char* __restrict__ dst, int dstr, int dch,
                                              const void* __restrict__ res, int rstr,
                                              signed char* __restrict__ dhl, int dhlstr,
                                              short* __restrict__ dj) {
    const int t = blockIdx.x * 256 + threadIdx.x;
    const int opc = OC / 4;
    const int total = NP * opc;
    if (t >= total) return;
    const int pix = t / opc, oc0 = (t - pix * opc) * 4;
    const size_t base = (size_t)pix * OC + oc0;
    const size_t NPOC = (size_t)NP * OC;
    long v[4] = {0, 0, 0, 0};
    int sidx = 0;
    for (int d = 0; d < D; ++d) {
        long s0 = 0, s1 = 0, s2 = 0, s3 = 0;
        for (int g = 0; g < G; ++g, ++sidx) {
            const int4 p = *(const int4*)(ps + sidx * NPOC + base);
            s0 += p.x; s1 += p.y; s2 += p.z; s3 += p.w;
        }
        v[0] = v[0] * 256 + s0; v[1] = v[1] * 256 + s1;
        v[2] = v[2] * 256 + s2; v[3] = v[3] * 256 + s3;
    }
    if constexpr (CMODE == 0) {
        unsigned pk = 0;
        #pragma unroll
        for (int j = 0; j < 4; ++j)
            pk |= (unsigned)(wqi((float)((double)v[j] * inv)) & 255) << (j * 8);
        *(unsigned*)(dst + (size_t)pix * dstr + dch + oc0) = pk;
    } else {
        #pragma unroll
        for (int j = 0; j < 4; ++j) {
            const int qi = wqi((float)((double)v[j] * inv));
            const int oc = oc0 + j;
            if constexpr (CMODE == 1) {
                const int rv = (int)((const signed char*)res)[(size_t)pix * rstr + oc];
                const int jj = (128 - qi) * rv;
                const int d0 = ((jj + 128) & 255) - 128;
                const int t1 = (jj - d0) >> 8;
                dhl[(size_t)pix * dhlstr + oc] = (signed char)t1;
                dhl[(size_t)pix * dhlstr + 512 + oc] = (signed char)d0;
                dj[(size_t)pix * 512 + oc] = (short)jj;
            } else {
                const int rv = (int)((const short*)res)[(size_t)pix * rstr + oc];
                const int jj = (128 - qi) * rv;
                const int d0 = ((jj + 128) & 255) - 128;
                const int t1 = (jj - d0) >> 8;
                const int d1 = ((t1 + 128) & 255) - 128;
                const int d2 = (t1 - d1) >> 8;
                dhl[(size_t)pix * dhlstr + oc] = (signed char)d2;
                dhl[(size_t)pix * dhlstr + 512 + oc] = (signed char)d1;
                dhl[(size_t)pix * dhlstr + 1024 + oc] = (signed char)d0;
            }
        }
    }
}

// ---------------- implicit-GEMM i8 MFMA conv ----------------
// Grid has a K-slice axis. ORD0: work -> ocg, tile, n, slice; ORD1: tile, n, ocg, slice.
// Staging addresses hoisted: per-rd (gp_base, climit) computed once; per chunk
// gp = (ch*64 < climit) ? gp_base + ch*64 : zbuf.
// Weights block-contiguous: wqp[((group*nchtot + slice*nch + ch)*K2 + kpos)*BN + bn].
// MODE 0: dst=i8; MODE 2: feat max (integer max reduce, wq8 once at end — monotone);
// MODE 3: i32 partial -> ps[((slice*8+n)*OHW+pix)*OCv+oc].
template<int K, int STR, int WM, int WN, int BN, int NBUF, int MODE>
__global__ void __launch_bounds__(256) k_mconv(
    const signed char* __restrict__ s0, int Ctot, int st0,
    int S, int padeff,
    const uint4* __restrict__ wqp, int nchtot,
    signed char* __restrict__ dst, int dstr, int dch,
    unsigned* __restrict__ feat, int* __restrict__ ps,
    const signed char* __restrict__ zbuf,
    int OCv, int OH, int OW, int TILES_W, int nch,
    int NT, int NOCG, int swzq, int ORD)
{
    constexpr int TH = WM * 4;
    constexpr int RH = (TH - 1) * STR + K, RW = 7 * STR + K;
    constexpr int UPPS = 5;
    constexpr int K2 = K * K;
    constexpr int NUS = RH * RW * UPPS;
    constexpr int ROUNDS = (NUS + 255) / 256;
    constexpr int NUPS = ROUNDS * 256;
    constexpr int AHEAD = NBUF - 1;
    __shared__ uint4 lds[NBUF * NUPS];
    __shared__ int sred[4][2][16];

    const int tid = threadIdx.x, lane = tid & 63, w = tid >> 6;
    const int wm = w % WM, wn = w / WM;
    const int l15 = lane & 15, g = lane >> 4;

    const int b = blockIdx.x;
    const int work = (b & 7) * swzq + (b >> 3);
    int tile, n, ocg, slice;
    if (ORD == 0) {
        ocg = work % NOCG; const int t2 = work / NOCG;
        tile = t2 % NT; const int t3 = t2 / NT;
        n = t3 & 7; slice = t3 >> 3;
    } else {
        tile = work % NT; const int t2 = work / NT;
        n = t2 & 7; const int t3 = t2 >> 3;
        ocg = t3 % NOCG; slice = t3 / NOCG;
    }
    const int cin_off = slice * nch * 64;
    const int group = ocg * WN + wn;

    const int tileh = tile / TILES_W, tilew = tile % TILES_W;
    const int oh0 = tileh * TH, ow0 = tilew * 8;
    const int ih0 = oh0 * STR - padeff, iw0 = ow0 * STR - padeff;
    const int blk_oct0 = ocg * (WN * BN);

    int pixb[2];
    #pragma unroll
    for (int am = 0; am < 2; ++am) {
        const int sp = wm * 32 + am * 16 + l15;
        pixb[am] = ((sp >> 3) * STR) * RW + (sp & 7) * STR;
    }

    // hoisted staging addresses: per-rd base pointer + channel-limit
    int climit[ROUNDS];
    const signed char* gpb[ROUNDS];
    #pragma unroll
    for (int rd = 0; rd < ROUNDS; ++rd) {
        const int d = rd * 256 + tid;
        int cl = -1;
        const signed char* gb = zbuf;
        if (d < NUS) {
            const int pix = d / UPPS;
            const int u = d - pix * UPPS;
            const int r = pix / RW, c = pix - r * RW;
            const int ih = ih0 + r, iw = iw0 + c;
            if (u < 4 && (unsigned)ih < (unsigned)S && (unsigned)iw < (unsigned)S) {
                cl = Ctot - cin_off - u * 16;
                gb = s0 + (((size_t)n * S + ih) * S + iw) * st0 + cin_off + u * 16;
            }
        }
        climit[rd] = cl; gpb[rd] = gb;
    }

    i32x4 acc[2][BN];
    #pragma unroll
    for (int am = 0; am < 2; ++am)
        #pragma unroll
        for (int bn = 0; bn < BN; ++bn) acc[am][bn] = (i32x4){0, 0, 0, 0};

    auto issue = [&](int ch, int buf) {
        uint4* lb = &lds[buf * NUPS];
        const int ch64v = ch * 64;
        #pragma unroll
        for (int rd = 0; rd < ROUNDS; ++rd) {
            const signed char* gp = (ch64v < climit[rd]) ? (gpb[rd] + ch64v) : zbuf;
            GLOAD16(gp, lb + rd * 256 + (tid & ~63));
        }
    };

    #pragma unroll
    for (int i = 0; i < AHEAD; ++i) if (i < nch) issue(i, i % NBUF);

    for (int ch = 0; ch < nch; ++ch) {
        if (ch + AHEAD < nch) issue(ch + AHEAD, (ch + AHEAD) % NBUF);
        const int infl = (nch - 1 - ch < AHEAD) ? nch - 1 - ch : AHEAD;
        if (infl >= 2)      __builtin_amdgcn_s_waitcnt(0xF70 | (2 * ROUNDS));
        else if (infl == 1) __builtin_amdgcn_s_waitcnt(0xF70 | ROUNDS);
        else                __builtin_amdgcn_s_waitcnt(0xF70);
        __builtin_amdgcn_s_barrier();
        __builtin_amdgcn_sched_barrier(0);
        const int bufo = (ch % NBUF) * NUPS;
        const int pb0 = bufo + pixb[0] * UPPS + g;
        const int pb1 = bufo + pixb[1] * UPPS + g;
        const uint4* wrow = wqp + ((size_t)(group * nchtot + slice * nch + ch) * K2 * BN) * 64 + lane;
        #pragma unroll
        for (int kpos = 0; kpos < K2; ++kpos) {
            const int kh = kpos / K, kw = kpos % K;
            const int po = (kh * RW + kw) * UPPS;
            i32x4 bfr[BN];
            #pragma unroll
            for (int bn = 0; bn < BN; ++bn) {
                union { uint4 u; i32x4 v; } bu;
                bu.u = wrow[(kpos * BN + bn) * 64];
                bfr[bn] = bu.v;
            }
            union { uint4 u; i32x4 v; } a0, a1;
            a0.u = lds[pb0 + po];
            a1.u = lds[pb1 + po];
            #pragma unroll
            for (int bn = 0; bn < BN; ++bn) {
                acc[0][bn] = __builtin_amdgcn_mfma_i32_16x16x64_i8(a0.v, bfr[bn], acc[0][bn], 0, 0, 0);
                acc[1][bn] = __builtin_amdgcn_mfma_i32_16x16x64_i8(a1.v, bfr[bn], acc[1][bn], 0, 0, 0);
            }
        }
        __builtin_amdgcn_sched_barrier(0);
        __builtin_amdgcn_s_barrier();
    }

    if constexpr (MODE == 2) {
        // integer max over spatial (wqi(scale*x) monotone -> max commutes), wq8 once.
        #pragma unroll
        for (int bn = 0; bn < BN; ++bn) {
            int m = (int)0x80000000;
            #pragma unroll
            for (int am = 0; am < 2; ++am)
                #pragma unroll
                for (int rg = 0; rg < 4; ++rg) {
                    const int sp = wm * 32 + am * 16 + g * 4 + rg;
                    const int oh = oh0 + (sp >> 3), ow = ow0 + (sp & 7);
                    const int v = acc[am][bn][rg];
                    if (oh < OH && ow < OW && v > m) m = v;
                }
            int o = __shfl_xor(m, 16); if (o > m) m = o;
            o = __shfl_xor(m, 32); if (o > m) m = o;
            if (lane < 16) sred[w][bn][l15] = m;
        }
        __syncthreads();
        if (tid < BN * 16) {
            const int bn = tid >> 4, l = tid & 15;
            int mm = sred[0][bn][l];
            #pragma unroll
            for (int i = 1; i < WM * WN; ++i) { const int o = sred[i][bn][l]; if (o > mm) mm = o; }
            const float y = (float)mm * (1.f / 16384.f);
            const float v = (float)wqi(y) * 0.0078125f;
            atomicMax(&feat[n * 32 + (blk_oct0 + bn) * 16 + l], encf(v));
        }
    } else if constexpr (MODE == 3) {
        #pragma unroll
        for (int am = 0; am < 2; ++am)
        #pragma unroll
        for (int bn = 0; bn < BN; ++bn)
        #pragma unroll
        for (int rg = 0; rg < 4; ++rg) {
            const int sp = wm * 32 + am * 16 + g * 4 + rg;
            const int oh = oh0 + (sp >> 3), ow = ow0 + (sp & 7);
            const int oc = (blk_oct0 + wn * BN + bn) * 16 + l15;
            if (oh < OH && ow < OW && oc < OCv) {
                ps[(((size_t)slice * 8 + n) * OH * OW + (size_t)oh * OW + ow) * OCv + oc] = acc[am][bn][rg];
            }
        }
    } else {
        #pragma unroll
        for (int am = 0; am < 2; ++am)
        #pragma unroll
        for (int bn = 0; bn < BN; ++bn)
        #pragma unroll
        for (int rg = 0; rg < 4; ++rg) {
            const int sp = wm * 32 + am * 16 + g * 4 + rg;
            const int oh = oh0 + (sp >> 3), ow = ow0 + (sp & 7);
            const int oc = (blk_oct0 + wn * BN + bn) * 16 + l15;
            if (oh < OH && ow < OW && oc < OCv) {
                const size_t pixo = (size_t)(n * OH + oh) * OW + ow;
                const float y = (float)acc[am][bn][rg] * (1.f / 16384.f);
                dst[pixo * dstr + dch + oc] = (signed char)wqi(y);
            }
        }
    }
}

extern "C" void kernel_launch(void* const* d_in, const int* in_sizes, int n_in,
                              void* d_out, int out_size, void* d_ws, size_t ws_size,
                              hipStream_t stream)
{
    (void)in_sizes; (void)n_in; (void)out_size; (void)ws_size;
    const float* x = (const float*)d_in[0];
    const float* wfc = (const float*)d_in[16];
    float* out = (float*)d_out;

    char* ws = (char*)d_ws;
    size_t off = 0;
    auto alloc = [&](size_t bytes) { char* p = ws + off; off += (bytes + 255) & ~(size_t)255; return p; };

    // {w0 idx, OC0, w1 idx, OC1, CinW, K, noct, nch64u, ndup, gsz(=BN)}
    struct PH { int i0, OC0, i1, OC1, CinW, K, noct, nch64u, ndup, gsz; };
    static const PH ph[11] = {
        {2, 128, -1, 0,  64, 3,  8, 1, 1, 2},   // 0 conv2
        {3, 256, -1, 0, 128, 3, 16, 2, 1, 2},   // 1 conv3
        {4, 512, -1, 0, 256, 3, 32, 4, 1, 2},   // 2 conv4
        {5, 512, -1, 0, 512, 3, 32, 8, 1, 2},   // 3 r11
        {6, 512, -1, 0, 512, 3, 32, 8, 1, 2},   // 4 r12
        {7, 512, -1, 0, 512, 3, 32, 8, 2, 2},   // 5 r21 (2 digit copies)
        {8, 512, -1, 0, 512, 3, 32, 8, 1, 2},   // 6 r22
        {9, 128, 12, 32, 512, 4, 10, 8, 3, 2},  // 7 L3 = wd3|wu43 (3 digit copies)
        {10, 64, 13, 32, 416, 4,  6, 7, 1, 2},  // 8 L2 = wd2|wu32
        {11,  4, 14, 32, 224, 4,  3, 4, 1, 3},  // 9 L1 = wd1|wu21 (+12 zero oc)
        {15, 32, -1, 0, 100, 4,  2, 2, 1, 2}};  // 10 u10

    PackArgs pa;
    int bacc = 0;
    uint4* wp[11];
    for (int i = 0; i < 11; ++i) {
        const int nch64 = ph[i].nch64u * ph[i].ndup;
        const int nel = nch64 * ph[i].K * ph[i].K * ph[i].noct * 64;
        wp[i] = (uint4*)alloc((size_t)nel * 16);
        pa.d[i].w0 = (const float*)d_in[ph[i].i0];
        pa.d[i].w1 = (ph[i].i1 >= 0) ? (const float*)d_in[ph[i].i1] : nullptr;
        pa.d[i].dst = wp[i];
        pa.d[i].OC0 = ph[i].OC0; pa.d[i].OC1 = ph[i].OC1;
        pa.d[i].CinW = ph[i].CinW; pa.d[i].K = ph[i].K; pa.d[i].noct = ph[i].noct;
        pa.d[i].nch64u = ph[i].nch64u; pa.d[i].ndup = ph[i].ndup;
        pa.d[i].gsz = ph[i].gsz;
        pa.bofs[i] = bacc;
        bacc += ph[i].noct * ph[i].nch64u;
    }
    pa.bofs[11] = bacc;

    signed char* cat1b = (signed char*)alloc((size_t)8*128*128*112);  // c1|d1|f2|pad12
    signed char* cat2b = (signed char*)alloc((size_t)8*64*64*224);    // c2|d2|f3
    signed char* cat3b = (signed char*)alloc((size_t)8*32*32*416);    // c3|d3|f4
    signed char* c4b   = (signed char*)alloc((size_t)8*16*16*512);
    signed char* r11b  = (signed char*)alloc((size_t)8*16*16*512);    // also r21 out
    signed char* r12d  = (signed char*)alloc((size_t)8*16*16*1024);   // r12 digits hi|lo
    short*       r12j  = (short*)alloc((size_t)8*16*16*512 * 2);      // r12 as i16 j (gate res)
    signed char* r22d  = (signed char*)alloc((size_t)8*16*16*1536);   // r22 digits j2|j1|j0
    int*         psum  = (int*)alloc((size_t)4*8*16*16*512 * 4);      // K-split partials (~17MB)
    unsigned*    featb = (unsigned*)alloc(256 * 4);
    uint4*       zbuf  = (uint4*)alloc(1024);

    k_packall<<<dim3((unsigned)bacc), dim3(256), 0, stream>>>(pa);
    k_init<<<dim3(1), dim3(256), 0, stream>>>(featb, zbuf);
    k_conv1<<<dim3(256, 8), dim3(256), 0, stream>>>(x, (const float*)d_in[1], cat1b);

    const signed char* zb = (const signed char*)zbuf;
    const void* nv = nullptr;

    // conv2: cat1 ch0..64 -> cat2 ch0..128   NT=64 NOCG=2 total=1024  ORD0
    k_mconv<3,2,2,2,2,1,0><<<dim3(1024), 256, 0, stream>>>(
        cat1b,64,112, 128,1, wp[0],1, cat2b,224,0, nullptr,nullptr, zb,
        128,64,64,8, 1, 64,2,128, 0);
    // conv3: cat2 -> cat3 ch0..256           NT=16 NOCG=4 total=512  ORD0
    k_mconv<3,2,2,2,2,2,0><<<dim3(512), 256, 0, stream>>>(
        cat2b,128,224, 64,1, wp[1],2, cat3b,416,0, nullptr,nullptr, zb,
        256,32,32,4, 2, 16,4,64, 0);
    // conv4 -> psum (4-way K-split, BN2)     NT=4 NOCG=8 NSLC=4 total=1024  ORD1
    k_mconv<3,2,2,2,2,1,3><<<dim3(1024), 256, 0, stream>>>(
        cat3b,256,416, 32,1, wp[2],4, nullptr,0,0, nullptr,(int*)psum, zb,
        512,16,16,2, 1, 4,8,128, 1);
    k_comb<0><<<dim3(1024), 256, 0, stream>>>(psum,1,4, 2048,512, 1.0/16384.0, c4b,512,0, nv,0, nullptr,0,nullptr);
    // r11 (WM4, BN2, 4-way K-split)          NT=2 NOCG=16 NSLC=4 total=1024  ORD1
    k_mconv<3,1,4,1,2,2,3><<<dim3(1024), 256, 0, stream>>>(
        c4b,512,512, 16,1, wp[3],8, nullptr,0,0, nullptr,psum, zb,
        512,16,16,2, 2, 2,16,128, 1);
    k_comb<0><<<dim3(1024), 256, 0, stream>>>(psum,1,4, 2048,512, 1.0/16384.0, r11b,512,0, nv,0, nullptr,0,nullptr);
    // r12 conv -> psum (2-way), gate in comb
    k_mconv<3,1,4,1,2,3,3><<<dim3(512), 256, 0, stream>>>(
        r11b,512,512, 16,1, wp[4],8, nullptr,0,0, nullptr,psum, zb,
        512,16,16,2, 4, 2,16,64, 1);
    k_comb<1><<<dim3(1024), 256, 0, stream>>>(psum,1,2, 2048,512, 1.0/16384.0, nullptr,0,0, c4b,512, r12d,1024,r12j);
    // r21: digits input, 4 slices = 2 digits x 2
    k_mconv<3,1,4,1,2,2,3><<<dim3(1024), 256, 0, stream>>>(
        r12d,1024,1024, 16,1, wp[5],16, nullptr,0,0, nullptr,psum, zb,
        512,16,16,2, 4, 2,16,128, 1);
    k_comb<0><<<dim3(1024), 256, 0, stream>>>(psum,2,2, 2048,512, 1.0/2097152.0, r11b,512,0, nv,0, nullptr,0,nullptr);
    // r22 conv -> psum (2-way), gate in comb (3 digits)
    k_mconv<3,1,4,1,2,3,3><<<dim3(512), 256, 0, stream>>>(
        r11b,512,512, 16,1, wp[6],8, nullptr,0,0, nullptr,psum, zb,
        512,16,16,2, 4, 2,16,64, 1);
    k_comb<2><<<dim3(1024), 256, 0, stream>>>(psum,1,2, 2048,512, 1.0/16384.0, nullptr,0,0, r12j,512, r22d,1536,nullptr);
    // L3: [d3|f4], WM4 BN2, 3 digit-slices   NT=8 NOCG=5 NSLC=3 total=960  ORD1
    k_mconv<4,1,4,1,2,2,3><<<dim3(960), 256, 0, stream>>>(
        r22d,1536,1536, 16,10, wp[7],24, nullptr,0,0, nullptr,psum, zb,
        160,32,32,4, 8, 8,5,120, 1);
    k_comb<0><<<dim3(1280), 256, 0, stream>>>(psum,3,1, 8192,160, 1.0/268435456.0, cat3b,416,256, nv,0, nullptr,0,nullptr);
    // L2: [d2|f3] from cat3 -> cat2 ch 128..224   WM4 BN2: NT=32 NOCG=3 total=768 ORD0
    k_mconv<4,1,4,1,2,2,0><<<dim3(768), 256, 0, stream>>>(
        cat3b,416,416, 32,18, wp[8],7, cat2b,224,128, nullptr,nullptr, zb,
        96,64,64,8, 7, 32,3,96, 0);
    // L1: [d1|f2|pad] from cat2 -> cat1 ch 64..112   WM4 BN3: NT=128 NOCG=1 total=1024 ORD0
    k_mconv<4,1,4,1,3,2,0><<<dim3(1024), 256, 0, stream>>>(
        cat2b,224,224, 64,34, wp[9],4, cat1b,112,64, nullptr,nullptr, zb,
        48,128,128,16, 4, 128,1,128, 0);
    // u10 + fused global max-pool   WM4 BN2: NT=561 total=4488 ORD0
    k_mconv<4,1,4,1,2,2,2><<<dim3(4488), 256, 0, stream>>>(
        cat1b,112,112, 128,66, wp[10],2, nullptr,0,0, featb,nullptr, zb,
        32,257,257,33, 2, 561,1,561, 0);
    // FC
    k_fc<<<dim3(1), dim3(64), 0, stream>>>(featb, wfc, out);
}

// Round 14
// 329.382 us; speedup vs baseline: 2.3130x; 1.0121x over previous
//
#include <hip/hip_runtime.h>

#define DEV __device__ __forceinline__

typedef __attribute__((ext_vector_type(4))) int i32x4;

// qi = 128*wq8(y) as int
DEV int wqi(float y) {
    int q = (int)rintf(y * 128.0f);
    return q < -127 ? -127 : (q > 127 ? 127 : q);
}
DEV unsigned encf(float f) { unsigned u = __float_as_uint(f); return (u & 0x80000000u) ? ~u : (u | 0x80000000u); }
DEV float decf(unsigned u) { return (u & 0x80000000u) ? __uint_as_float(u ^ 0x80000000u) : __uint_as_float(~u); }
DEV float wq8f(float x) {
    float q = rintf(x * 128.0f) * 0.0078125f;
    return fminf(fmaxf(q, -0.9921875f), 0.9921875f);
}

// async global->LDS, 16B per lane, dest = uniform base + lane*16 (linear)
#define GLOAD16(g, l) __builtin_amdgcn_global_load_lds( \
    (const __attribute__((address_space(1))) void*)(g), \
    (__attribute__((address_space(3))) void*)(l), 16, 0, 0)

// ---------------- i8 weight pack, LDS-staged coalesced transpose ----------------
// Output layout (block-contiguous): idx = (((oct/GSZ)*(NCHT*K2) + ch64*K2 + kpos)*GSZ
//   + oct%GSZ)*64 + lane, NCHT = nch64u*ndup.
struct PackDesc {
    const float* w0; const float* w1; uint4* dst;
    int OC0, OC1, CinW, K, noct, nch64u, ndup, gsz;
};
struct PackArgs { PackDesc d[11]; int bofs[12]; };

__global__ void __launch_bounds__(256) k_packall(PackArgs a) {
    __shared__ unsigned char sb[16 * (64 * 16 + 4)];
    const int b = blockIdx.x;
    int i = 0;
    #pragma unroll
    for (int j = 1; j < 11; ++j) if (b >= a.bofs[j]) i = j;
    const PackDesc D = a.d[i];
    const int b2 = b - a.bofs[i];
    const int oct = b2 % D.noct;
    const int ch64u = b2 / D.noct;
    const int K2 = D.K * D.K;
    const int NCHT = D.nch64u * D.ndup;
    const int row_elems = 64 * K2;
    const int SSTR = row_elems + 4;
    const int QR = row_elems / 4;
    const int NQ = 16 * QR;
    const int cin0 = ch64u * 64;
    const int tid = threadIdx.x;
    const int og = oct / D.gsz, ol = oct % D.gsz;

    for (int q = tid; q < NQ; q += 256) {
        const int r = q / QR, j = q - r * QR;
        const int oc = oct * 16 + r;
        const float* src = nullptr; int oci = 0;
        if (oc < D.OC0) { src = D.w0; oci = oc; }
        else if (oc < D.OC0 + D.OC1) { src = D.w1; oci = oc - D.OC0; }
        const int e0 = j * 4;
        float v[4] = {0.f, 0.f, 0.f, 0.f};
        if (src != nullptr) {
            const float* p = src + ((size_t)oci * D.CinW + cin0) * K2 + e0;
            const int cin_last = cin0 + (e0 + 3) / K2;
            if (cin_last < D.CinW) {
                const float4 f4 = *(const float4*)p;
                v[0] = f4.x; v[1] = f4.y; v[2] = f4.z; v[3] = f4.w;
            } else {
                #pragma unroll
                for (int e = 0; e < 4; ++e) {
                    const int cin = cin0 + (e0 + e) / K2;
                    if (cin < D.CinW) v[e] = p[e];
                }
            }
        }
        unsigned pk = 0;
        #pragma unroll
        for (int e = 0; e < 4; ++e) pk |= ((unsigned)(wqi(v[e]) & 255)) << (e * 8);
        *(unsigned*)&sb[r * SSTR + e0] = pk;
    }
    __syncthreads();

    const int outN = K2 * 64;
    for (int idx = tid; idx < outN; idx += 256) {
        const int kpos = idx >> 6, lane = idx & 63;
        const int l15 = lane & 15, g = lane >> 4;
        unsigned wd[4] = {0u, 0u, 0u, 0u};
        #pragma unroll
        for (int e = 0; e < 16; ++e) {
            const unsigned bval = sb[l15 * SSTR + (g * 16 + e) * K2 + kpos];
            wd[e >> 2] |= bval << ((e & 3) * 8);
        }
        uint4 u; u.x = wd[0]; u.y = wd[1]; u.z = wd[2]; u.w = wd[3];
        for (int d = 0; d < D.ndup; ++d) {
            const int ch64 = ch64u + d * D.nch64u;
            D.dst[((size_t)((og * NCHT + ch64) * K2 + kpos) * D.gsz + ol) * 64 + lane] = u;
        }
    }
}

// ---------------- conv1: LDS-tiled f32 vector conv (exact chain), i8 out ----------------
__global__ void __launch_bounds__(256) k_conv1(const float* __restrict__ x, const float* __restrict__ w1,
                                               signed char* __restrict__ cat1) {
    __shared__ float sw2[36][64];
    __shared__ float sin_[4][17][17];
    const int tid = threadIdx.x;
    const int n = blockIdx.y;
    const int oh0 = (blockIdx.x >> 4) * 8, ow0 = (blockIdx.x & 15) * 8;
    for (int i = tid; i < 2304; i += 256) sw2[i % 36][i / 36] = wq8f(w1[i]);
    const int ih0 = oh0 * 2 - 1, iw0 = ow0 * 2 - 1;
    for (int i = tid; i < 4 * 289; i += 256) {
        const int c = i / 289, rem = i % 289, r = rem / 17, cc = rem % 17;
        const int ih = ih0 + r, iw = iw0 + cc;
        float v = 0.f;
        if ((unsigned)ih < 256u && (unsigned)iw < 256u) v = x[((size_t)(n * 4 + c) * 256 + ih) * 256 + iw];
        sin_[c][r][cc] = v;
    }
    __syncthreads();
    const int sp = tid & 63, ocg = tid >> 6;
    const int oh = sp >> 3, ow = sp & 7;
    float acc[16];
    #pragma unroll
    for (int j = 0; j < 16; ++j) acc[j] = 0.f;
    #pragma unroll
    for (int c = 0; c < 4; ++c)
    #pragma unroll
    for (int kh = 0; kh < 3; ++kh)
    #pragma unroll
    for (int kw = 0; kw < 3; ++kw) {
        const float v = sin_[c][oh * 2 + kh][ow * 2 + kw];
        const float4* wp4 = (const float4*)&sw2[c * 9 + kh * 3 + kw][ocg * 16];
        #pragma unroll
        for (int q = 0; q < 4; ++q) {
            const float4 wv = wp4[q];
            acc[q * 4 + 0] = fmaf(v, wv.x, acc[q * 4 + 0]);
            acc[q * 4 + 1] = fmaf(v, wv.y, acc[q * 4 + 1]);
            acc[q * 4 + 2] = fmaf(v, wv.z, acc[q * 4 + 2]);
            acc[q * 4 + 3] = fmaf(v, wv.w, acc[q * 4 + 3]);
        }
    }
    const size_t pix = ((size_t)(n * 128) + oh0 + oh) * 128 + ow0 + ow;
    unsigned wd[4] = {0u, 0u, 0u, 0u};
    #pragma unroll
    for (int j = 0; j < 16; ++j)
        wd[j >> 2] |= ((unsigned)(wqi(acc[j]) & 255)) << ((j & 3) * 8);
    uint4 u; u.x = wd[0]; u.y = wd[1]; u.z = wd[2]; u.w = wd[3];
    *(uint4*)(cat1 + pix * 112 + ocg * 16) = u;
}

__global__ void k_init(unsigned* __restrict__ feat, uint4* __restrict__ zbuf) {
    feat[threadIdx.x] = encf(-2.0f);
    if (threadIdx.x < 64) { uint4 z; z.x = z.y = z.z = z.w = 0u; zbuf[threadIdx.x] = z; }
}

__global__ void k_fc(const unsigned* __restrict__ feat, const float* __restrict__ wfc,
                     float* __restrict__ out) {
    int n = threadIdx.x;
    if (n < 8) {
        float s = 0.f;
        for (int c = 0; c < 32; ++c) s += decf(feat[n * 32 + c]) * wq8f(wfc[c]);
        out[n] = wq8f(s);
    }
}

// ---------------- K-split partial combiner (D digits x G same-scale groups) ----------------
template<int CMODE>
__global__ void __launch_bounds__(256) k_comb(const int* __restrict__ ps, int D, int G,
                                              int NP, int OC, double inv,
                                              signed char* __restrict__ dst, int dstr, int dch,
                                              const void* __restrict__ res, int rstr,
                                              signed char* __restrict__ dhl, int dhlstr,
                                              short* __restrict__ dj) {
    const int t = blockIdx.x * 256 + threadIdx.x;
    const int opc = OC / 4;
    const int total = NP * opc;
    if (t >= total) return;
    const int pix = t / opc, oc0 = (t - pix * opc) * 4;
    const size_t base = (size_t)pix * OC + oc0;
    const size_t NPOC = (size_t)NP * OC;
    long v[4] = {0, 0, 0, 0};
    int sidx = 0;
    for (int d = 0; d < D; ++d) {
        long s0 = 0, s1 = 0, s2 = 0, s3 = 0;
        for (int g = 0; g < G; ++g, ++sidx) {
            const int4 p = *(const int4*)(ps + sidx * NPOC + base);
            s0 += p.x; s1 += p.y; s2 += p.z; s3 += p.w;
        }
        v[0] = v[0] * 256 + s0; v[1] = v[1] * 256 + s1;
        v[2] = v[2] * 256 + s2; v[3] = v[3] * 256 + s3;
    }
    if constexpr (CMODE == 0) {
        unsigned pk = 0;
        #pragma unroll
        for (int j = 0; j < 4; ++j)
            pk |= (unsigned)(wqi((float)((double)v[j] * inv)) & 255) << (j * 8);
        *(unsigned*)(dst + (size_t)pix * dstr + dch + oc0) = pk;
    } else {
        #pragma unroll
        for (int j = 0; j < 4; ++j) {
            const int qi = wqi((float)((double)v[j] * inv));
            const int oc = oc0 + j;
            if constexpr (CMODE == 1) {
                const int rv = (int)((const signed char*)res)[(size_t)pix * rstr + oc];
                const int jj = (128 - qi) * rv;
                const int d0 = ((jj + 128) & 255) - 128;
                const int t1 = (jj - d0) >> 8;
                dhl[(size_t)pix * dhlstr + oc] = (signed char)t1;
                dhl[(size_t)pix * dhlstr + 512 + oc] = (signed char)d0;
                dj[(size_t)pix * 512 + oc] = (short)jj;
            } else {
                const int rv = (int)((const short*)res)[(size_t)pix * rstr + oc];
                const int jj = (128 - qi) * rv;
                const int d0 = ((jj + 128) & 255) - 128;
                const int t1 = (jj - d0) >> 8;
                const int d1 = ((t1 + 128) & 255) - 128;
                const int d2 = (t1 - d1) >> 8;
                dhl[(size_t)pix * dhlstr + oc] = (signed char)d2;
                dhl[(size_t)pix * dhlstr + 512 + oc] = (signed char)d1;
                dhl[(size_t)pix * dhlstr + 1024 + oc] = (signed char)d0;
            }
        }
    }
}

// ---------------- implicit-GEMM i8 MFMA conv ----------------
// CHQ = cin per staged chunk (64 or 128); UNITS = CHQ/16 16B-units + 1 pad per pixel.
// NKC = CHQ/64 MFMA k-subchunks per kpos. Weight pack is in 64-cin blocks:
// packed ch64 = (slice*nch + ch)*NKC + kc. CHQ=128 + nch=1 = one-shot staging
// (single vmcnt(0)+barrier, max TLP). Staging addresses hoisted per-rd.
// MODE 0: dst=i8; MODE 2: feat max (integer max, wq8 once); MODE 3: i32 partial.
template<int K, int STR, int WM, int WN, int BN, int CHQ, int NBUF, int MODE>
__global__ void __launch_bounds__(256) k_mconv(
    const signed char* __restrict__ s0, int Ctot, int st0,
    int S, int padeff,
    const uint4* __restrict__ wqp, int nchtot,
    signed char* __restrict__ dst, int dstr, int dch,
    unsigned* __restrict__ feat, int* __restrict__ ps,
    const signed char* __restrict__ zbuf,
    int OCv, int OH, int OW, int TILES_W, int nch,
    int NT, int NOCG, int swzq, int ORD)
{
    constexpr int TH = WM * 4;
    constexpr int RH = (TH - 1) * STR + K, RW = 7 * STR + K;
    constexpr int UNITS = CHQ / 16;
    constexpr int UPPS = UNITS + 1;
    constexpr int NKC = CHQ / 64;
    constexpr int K2 = K * K;
    constexpr int NUS = RH * RW * UPPS;
    constexpr int ROUNDS = (NUS + 255) / 256;
    constexpr int NUPS = ROUNDS * 256;
    constexpr int AHEAD = NBUF - 1;
    __shared__ uint4 lds[NBUF * NUPS];
    __shared__ int sred[4][2][16];

    const int tid = threadIdx.x, lane = tid & 63, w = tid >> 6;
    const int wm = w % WM, wn = w / WM;
    const int l15 = lane & 15, g = lane >> 4;

    const int b = blockIdx.x;
    const int work = (b & 7) * swzq + (b >> 3);
    int tile, n, ocg, slice;
    if (ORD == 0) {
        ocg = work % NOCG; const int t2 = work / NOCG;
        tile = t2 % NT; const int t3 = t2 / NT;
        n = t3 & 7; slice = t3 >> 3;
    } else {
        tile = work % NT; const int t2 = work / NT;
        n = t2 & 7; const int t3 = t2 >> 3;
        ocg = t3 % NOCG; slice = t3 / NOCG;
    }
    const int cin_off = slice * nch * CHQ;
    const int group = ocg * WN + wn;

    const int tileh = tile / TILES_W, tilew = tile % TILES_W;
    const int oh0 = tileh * TH, ow0 = tilew * 8;
    const int ih0 = oh0 * STR - padeff, iw0 = ow0 * STR - padeff;
    const int blk_oct0 = ocg * (WN * BN);

    int pixb[2];
    #pragma unroll
    for (int am = 0; am < 2; ++am) {
        const int sp = wm * 32 + am * 16 + l15;
        pixb[am] = ((sp >> 3) * STR) * RW + (sp & 7) * STR;
    }

    // hoisted staging addresses: per-rd base pointer + channel-limit
    int climit[ROUNDS];
    const signed char* gpb[ROUNDS];
    #pragma unroll
    for (int rd = 0; rd < ROUNDS; ++rd) {
        const int d = rd * 256 + tid;
        int cl = -1;
        const signed char* gb = zbuf;
        if (d < NUS) {
            const int pix = d / UPPS;
            const int u = d - pix * UPPS;
            const int r = pix / RW, c = pix - r * RW;
            const int ih = ih0 + r, iw = iw0 + c;
            if (u < UNITS && (unsigned)ih < (unsigned)S && (unsigned)iw < (unsigned)S) {
                cl = Ctot - cin_off - u * 16;
                gb = s0 + (((size_t)n * S + ih) * S + iw) * st0 + cin_off + u * 16;
            }
        }
        climit[rd] = cl; gpb[rd] = gb;
    }

    i32x4 acc[2][BN];
    #pragma unroll
    for (int am = 0; am < 2; ++am)
        #pragma unroll
        for (int bn = 0; bn < BN; ++bn) acc[am][bn] = (i32x4){0, 0, 0, 0};

    auto issue = [&](int ch, int buf) {
        uint4* lb = &lds[buf * NUPS];
        const int chv = ch * CHQ;
        #pragma unroll
        for (int rd = 0; rd < ROUNDS; ++rd) {
            const signed char* gp = (chv < climit[rd]) ? (gpb[rd] + chv) : zbuf;
            GLOAD16(gp, lb + rd * 256 + (tid & ~63));
        }
    };

    #pragma unroll
    for (int i = 0; i < AHEAD; ++i) if (i < nch) issue(i, i % NBUF);

    for (int ch = 0; ch < nch; ++ch) {
        if (ch + AHEAD < nch) issue(ch + AHEAD, (ch + AHEAD) % NBUF);
        const int infl = (nch - 1 - ch < AHEAD) ? nch - 1 - ch : AHEAD;
        if (infl >= 2)      __builtin_amdgcn_s_waitcnt(0xF70 | (2 * ROUNDS));
        else if (infl == 1) __builtin_amdgcn_s_waitcnt(0xF70 | ROUNDS);
        else                __builtin_amdgcn_s_waitcnt(0xF70);
        __builtin_amdgcn_s_barrier();
        __builtin_amdgcn_sched_barrier(0);
        const int bufo = (ch % NBUF) * NUPS;
        const int pb0 = bufo + pixb[0] * UPPS + g;
        const int pb1 = bufo + pixb[1] * UPPS + g;
        const uint4* wrow = wqp + ((size_t)(group * nchtot + (slice * nch + ch) * NKC) * K2 * BN) * 64 + lane;
        #pragma unroll
        for (int kpos = 0; kpos < K2; ++kpos) {
            const int kh = kpos / K, kw = kpos % K;
            const int po = (kh * RW + kw) * UPPS;
            #pragma unroll
            for (int kc = 0; kc < NKC; ++kc) {
                i32x4 bfr[BN];
                #pragma unroll
                for (int bn = 0; bn < BN; ++bn) {
                    union { uint4 u; i32x4 v; } bu;
                    bu.u = wrow[(kc * K2 * BN + kpos * BN + bn) * 64];
                    bfr[bn] = bu.v;
                }
                union { uint4 u; i32x4 v; } a0, a1;
                a0.u = lds[pb0 + po + kc * 4];
                a1.u = lds[pb1 + po + kc * 4];
                #pragma unroll
                for (int bn = 0; bn < BN; ++bn) {
                    acc[0][bn] = __builtin_amdgcn_mfma_i32_16x16x64_i8(a0.v, bfr[bn], acc[0][bn], 0, 0, 0);
                    acc[1][bn] = __builtin_amdgcn_mfma_i32_16x16x64_i8(a1.v, bfr[bn], acc[1][bn], 0, 0, 0);
                }
            }
        }
        __builtin_amdgcn_sched_barrier(0);
        __builtin_amdgcn_s_barrier();
    }

    if constexpr (MODE == 2) {
        // integer max over spatial (wqi(scale*x) monotone -> max commutes), wq8 once.
        #pragma unroll
        for (int bn = 0; bn < BN; ++bn) {
            int m = (int)0x80000000;
            #pragma unroll
            for (int am = 0; am < 2; ++am)
                #pragma unroll
                for (int rg = 0; rg < 4; ++rg) {
                    const int sp = wm * 32 + am * 16 + g * 4 + rg;
                    const int oh = oh0 + (sp >> 3), ow = ow0 + (sp & 7);
                    const int v = acc[am][bn][rg];
                    if (oh < OH && ow < OW && v > m) m = v;
                }
            int o = __shfl_xor(m, 16); if (o > m) m = o;
            o = __shfl_xor(m, 32); if (o > m) m = o;
            if (lane < 16) sred[w][bn][l15] = m;
        }
        __syncthreads();
        if (tid < BN * 16) {
            const int bn = tid >> 4, l = tid & 15;
            int mm = sred[0][bn][l];
            #pragma unroll
            for (int i = 1; i < WM * WN; ++i) { const int o = sred[i][bn][l]; if (o > mm) mm = o; }
            const float y = (float)mm * (1.f / 16384.f);
            const float v = (float)wqi(y) * 0.0078125f;
            atomicMax(&feat[n * 32 + (blk_oct0 + bn) * 16 + l], encf(v));
        }
    } else if constexpr (MODE == 3) {
        #pragma unroll
        for (int am = 0; am < 2; ++am)
        #pragma unroll
        for (int bn = 0; bn < BN; ++bn)
        #pragma unroll
        for (int rg = 0; rg < 4; ++rg) {
            const int sp = wm * 32 + am * 16 + g * 4 + rg;
            const int oh = oh0 + (sp >> 3), ow = ow0 + (sp & 7);
            const int oc = (blk_oct0 + wn * BN + bn) * 16 + l15;
            if (oh < OH && ow < OW && oc < OCv) {
                ps[(((size_t)slice * 8 + n) * OH * OW + (size_t)oh * OW + ow) * OCv + oc] = acc[am][bn][rg];
            }
        }
    } else {
        #pragma unroll
        for (int am = 0; am < 2; ++am)
        #pragma unroll
        for (int bn = 0; bn < BN; ++bn)
        #pragma unroll
        for (int rg = 0; rg < 4; ++rg) {
            const int sp = wm * 32 + am * 16 + g * 4 + rg;
            const int oh = oh0 + (sp >> 3), ow = ow0 + (sp & 7);
            const int oc = (blk_oct0 + wn * BN + bn) * 16 + l15;
            if (oh < OH && ow < OW && oc < OCv) {
                const size_t pixo = (size_t)(n * OH + oh) * OW + ow;
                const float y = (float)acc[am][bn][rg] * (1.f / 16384.f);
                dst[pixo * dstr + dch + oc] = (signed char)wqi(y);
            }
        }
    }
}

extern "C" void kernel_launch(void* const* d_in, const int* in_sizes, int n_in,
                              void* d_out, int out_size, void* d_ws, size_t ws_size,
                              hipStream_t stream)
{
    (void)in_sizes; (void)n_in; (void)out_size; (void)ws_size;
    const float* x = (const float*)d_in[0];
    const float* wfc = (const float*)d_in[16];
    float* out = (float*)d_out;

    char* ws = (char*)d_ws;
    size_t off = 0;
    auto alloc = [&](size_t bytes) { char* p = ws + off; off += (bytes + 255) & ~(size_t)255; return p; };

    // {w0 idx, OC0, w1 idx, OC1, CinW, K, noct, nch64u, ndup, gsz(=BN)}
    struct PH { int i0, OC0, i1, OC1, CinW, K, noct, nch64u, ndup, gsz; };
    static const PH ph[11] = {
        {2, 128, -1, 0,  64, 3,  8, 1, 1, 2},   // 0 conv2
        {3, 256, -1, 0, 128, 3, 16, 2, 1, 2},   // 1 conv3
        {4, 512, -1, 0, 256, 3, 32, 4, 1, 2},   // 2 conv4
        {5, 512, -1, 0, 512, 3, 32, 8, 1, 2},   // 3 r11
        {6, 512, -1, 0, 512, 3, 32, 8, 1, 2},   // 4 r12
        {7, 512, -1, 0, 512, 3, 32, 8, 2, 2},   // 5 r21 (2 digit copies)
        {8, 512, -1, 0, 512, 3, 32, 8, 1, 2},   // 6 r22
        {9, 128, 12, 32, 512, 4, 10, 8, 3, 2},  // 7 L3 = wd3|wu43 (3 digit copies)
        {10, 64, 13, 32, 416, 4,  6, 7, 1, 2},  // 8 L2 = wd2|wu32
        {11,  4, 14, 32, 224, 4,  3, 4, 1, 3},  // 9 L1 = wd1|wu21 (+12 zero oc)
        {15, 32, -1, 0, 100, 4,  2, 2, 1, 2}};  // 10 u10

    PackArgs pa;
    int bacc = 0;
    uint4* wp[11];
    for (int i = 0; i < 11; ++i) {
        const int nch64 = ph[i].nch64u * ph[i].ndup;
        const int nel = nch64 * ph[i].K * ph[i].K * ph[i].noct * 64;
        wp[i] = (uint4*)alloc((size_t)nel * 16);
        pa.d[i].w0 = (const float*)d_in[ph[i].i0];
        pa.d[i].w1 = (ph[i].i1 >= 0) ? (const float*)d_in[ph[i].i1] : nullptr;
        pa.d[i].dst = wp[i];
        pa.d[i].OC0 = ph[i].OC0; pa.d[i].OC1 = ph[i].OC1;
        pa.d[i].CinW = ph[i].CinW; pa.d[i].K = ph[i].K; pa.d[i].noct = ph[i].noct;
        pa.d[i].nch64u = ph[i].nch64u; pa.d[i].ndup = ph[i].ndup;
        pa.d[i].gsz = ph[i].gsz;
        pa.bofs[i] = bacc;
        bacc += ph[i].noct * ph[i].nch64u;
    }
    pa.bofs[11] = bacc;

    signed char* cat1b = (signed char*)alloc((size_t)8*128*128*112);  // c1|d1|f2|pad12
    signed char* cat2b = (signed char*)alloc((size_t)8*64*64*224);    // c2|d2|f3
    signed char* cat3b = (signed char*)alloc((size_t)8*32*32*416);    // c3|d3|f4
    signed char* c4b   = (signed char*)alloc((size_t)8*16*16*512);
    signed char* r11b  = (signed char*)alloc((size_t)8*16*16*512);    // also r21 out
    signed char* r12d  = (signed char*)alloc((size_t)8*16*16*1024);   // r12 digits hi|lo
    short*       r12j  = (short*)alloc((size_t)8*16*16*512 * 2);      // r12 as i16 j (gate res)
    signed char* r22d  = (signed char*)alloc((size_t)8*16*16*1536);   // r22 digits j2|j1|j0
    int*         psum  = (int*)alloc((size_t)4*8*16*16*512 * 4);      // K-split partials (~17MB)
    unsigned*    featb = (unsigned*)alloc(256 * 4);
    uint4*       zbuf  = (uint4*)alloc(1024);

    k_packall<<<dim3((unsigned)bacc), dim3(256), 0, stream>>>(pa);
    k_init<<<dim3(1), dim3(256), 0, stream>>>(featb, zbuf);
    k_conv1<<<dim3(256, 8), dim3(256), 0, stream>>>(x, (const float*)d_in[1], cat1b);

    const signed char* zb = (const signed char*)zbuf;
    const void* nv = nullptr;

    // conv2: cat1 ch0..64 -> cat2 ch0..128   NT=64 NOCG=2 total=1024  ORD0
    k_mconv<3,2,2,2,2,64,1,0><<<dim3(1024), 256, 0, stream>>>(
        cat1b,64,112, 128,1, wp[0],1, cat2b,224,0, nullptr,nullptr, zb,
        128,64,64,8, 1, 64,2,128, 0);
    // conv3: cat2 -> cat3 ch0..256           NT=16 NOCG=4 total=512  ORD0
    k_mconv<3,2,2,2,2,64,2,0><<<dim3(512), 256, 0, stream>>>(
        cat2b,128,224, 64,1, wp[1],2, cat3b,416,0, nullptr,nullptr, zb,
        256,32,32,4, 2, 16,4,64, 0);
    // conv4 -> psum (4-way K-split, BN2)     NT=4 NOCG=8 NSLC=4 total=1024  ORD1
    k_mconv<3,2,2,2,2,64,1,3><<<dim3(1024), 256, 0, stream>>>(
        cat3b,256,416, 32,1, wp[2],4, nullptr,0,0, nullptr,(int*)psum, zb,
        512,16,16,2, 1, 4,8,128, 1);
    k_comb<0><<<dim3(1024), 256, 0, stream>>>(psum,1,4, 2048,512, 1.0/16384.0, c4b,512,0, nv,0, nullptr,0,nullptr);
    // r11 (WM4, BN2, 4-way K-split, one-shot CHQ128)  NT=2 NOCG=16 NSLC=4 total=1024  ORD1
    k_mconv<3,1,4,1,2,128,1,3><<<dim3(1024), 256, 0, stream>>>(
        c4b,512,512, 16,1, wp[3],8, nullptr,0,0, nullptr,psum, zb,
        512,16,16,2, 1, 2,16,128, 1);
    k_comb<0><<<dim3(1024), 256, 0, stream>>>(psum,1,4, 2048,512, 1.0/16384.0, r11b,512,0, nv,0, nullptr,0,nullptr);
    // r12 conv -> psum (2-way), gate in comb
    k_mconv<3,1,4,1,2,64,3,3><<<dim3(512), 256, 0, stream>>>(
        r11b,512,512, 16,1, wp[4],8, nullptr,0,0, nullptr,psum, zb,
        512,16,16,2, 4, 2,16,64, 1);
    k_comb<1><<<dim3(1024), 256, 0, stream>>>(psum,1,2, 2048,512, 1.0/16384.0, nullptr,0,0, c4b,512, r12d,1024,r12j);
    // r21: digits input, 4 slices = 2 digits x 2
    k_mconv<3,1,4,1,2,64,2,3><<<dim3(1024), 256, 0, stream>>>(
        r12d,1024,1024, 16,1, wp[5],16, nullptr,0,0, nullptr,psum, zb,
        512,16,16,2, 4, 2,16,128, 1);
    k_comb<0><<<dim3(1024), 256, 0, stream>>>(psum,2,2, 2048,512, 1.0/2097152.0, r11b,512,0, nv,0, nullptr,0,nullptr);
    // r22 conv -> psum (2-way), gate in comb (3 digits)
    k_mconv<3,1,4,1,2,64,3,3><<<dim3(512), 256, 0, stream>>>(
        r11b,512,512, 16,1, wp[6],8, nullptr,0,0, nullptr,psum, zb,
        512,16,16,2, 4, 2,16,64, 1);
    k_comb<2><<<dim3(1024), 256, 0, stream>>>(psum,1,2, 2048,512, 1.0/16384.0, nullptr,0,0, r12j,512, r22d,1536,nullptr);
    // L3: [d3|f4], WM4 BN2, 3 digit-slices   NT=8 NOCG=5 NSLC=3 total=960  ORD1
    k_mconv<4,1,4,1,2,64,2,3><<<dim3(960), 256, 0, stream>>>(
        r22d,1536,1536, 16,10, wp[7],24, nullptr,0,0, nullptr,psum, zb,
        160,32,32,4, 8, 8,5,120, 1);
    k_comb<0><<<dim3(1280), 256, 0, stream>>>(psum,3,1, 8192,160, 1.0/268435456.0, cat3b,416,256, nv,0, nullptr,0,nullptr);
    // L2: [d2|f3] from cat3 -> cat2 ch 128..224   WM4 BN2: NT=32 NOCG=3 total=768 ORD0
    k_mconv<4,1,4,1,2,64,2,0><<<dim3(768), 256, 0, stream>>>(
        cat3b,416,416, 32,18, wp[8],7, cat2b,224,128, nullptr,nullptr, zb,
        96,64,64,8, 7, 32,3,96, 0);
    // L1: [d1|f2|pad] from cat2 -> cat1 ch 64..112   WM4 BN3: NT=128 NOCG=1 total=1024 ORD0
    k_mconv<4,1,4,1,3,64,2,0><<<dim3(1024), 256, 0, stream>>>(
        cat2b,224,224, 64,34, wp[9],4, cat1b,112,64, nullptr,nullptr, zb,
        48,128,128,16, 4, 128,1,128, 0);
    // u10 + fused global max-pool: one-shot CHQ128  WM4 BN2: NT=561 total=4488 ORD0
    k_mconv<4,1,4,1,2,128,1,2><<<dim3(4488), 256, 0, stream>>>(
        cat1b,112,112, 128,66, wp[10],2, nullptr,0,0, featb,nullptr, zb,
        32,257,257,33, 1, 561,1,561, 0);
    // FC
    k_fc<<<dim3(1), dim3(64), 0, stream>>>(featb, wfc, out);
}

// Round 15
// 298.140 us; speedup vs baseline: 2.5554x; 1.1048x over previous
//
#include <hip/hip_runtime.h>

#define DEV __device__ __forceinline__

typedef __attribute__((ext_vector_type(4))) int i32x4;

// qi = 128*wq8(y) as int
DEV int wqi(float y) {
    int q = (int)rintf(y * 128.0f);
    return q < -127 ? -127 : (q > 127 ? 127 : q);
}
DEV unsigned encf(float f) { unsigned u = __float_as_uint(f); return (u & 0x80000000u) ? ~u : (u | 0x80000000u); }
DEV float decf(unsigned u) { return (u & 0x80000000u) ? __uint_as_float(u ^ 0x80000000u) : __uint_as_float(~u); }
DEV float wq8f(float x) {
    float q = rintf(x * 128.0f) * 0.0078125f;
    return fminf(fmaxf(q, -0.9921875f), 0.9921875f);
}

// async global->LDS, 16B per lane, dest = uniform base + lane*16 (linear)
#define GLOAD16(g, l) __builtin_amdgcn_global_load_lds( \
    (const __attribute__((address_space(1))) void*)(g), \
    (__attribute__((address_space(3))) void*)(l), 16, 0, 0)

// ---------------- i8 weight pack, LDS-staged coalesced transpose ----------------
struct PackDesc {
    const float* w0; const float* w1; uint4* dst;
    int OC0, OC1, CinW, K, noct, nch64u, ndup, gsz;
};
struct PackArgs { PackDesc d[11]; int bofs[12]; };

__global__ void __launch_bounds__(256) k_packall(PackArgs a) {
    __shared__ unsigned char sb[16 * (64 * 16 + 4)];
    const int b = blockIdx.x;
    int i = 0;
    #pragma unroll
    for (int j = 1; j < 11; ++j) if (b >= a.bofs[j]) i = j;
    const PackDesc D = a.d[i];
    const int b2 = b - a.bofs[i];
    const int oct = b2 % D.noct;
    const int ch64u = b2 / D.noct;
    const int K2 = D.K * D.K;
    const int NCHT = D.nch64u * D.ndup;
    const int row_elems = 64 * K2;
    const int SSTR = row_elems + 4;
    const int QR = row_elems / 4;
    const int NQ = 16 * QR;
    const int cin0 = ch64u * 64;
    const int tid = threadIdx.x;
    const int og = oct / D.gsz, ol = oct % D.gsz;

    for (int q = tid; q < NQ; q += 256) {
        const int r = q / QR, j = q - r * QR;
        const int oc = oct * 16 + r;
        const float* src = nullptr; int oci = 0;
        if (oc < D.OC0) { src = D.w0; oci = oc; }
        else if (oc < D.OC0 + D.OC1) { src = D.w1; oci = oc - D.OC0; }
        const int e0 = j * 4;
        float v[4] = {0.f, 0.f, 0.f, 0.f};
        if (src != nullptr) {
            const float* p = src + ((size_t)oci * D.CinW + cin0) * K2 + e0;
            const int cin_last = cin0 + (e0 + 3) / K2;
            if (cin_last < D.CinW) {
                const float4 f4 = *(const float4*)p;
                v[0] = f4.x; v[1] = f4.y; v[2] = f4.z; v[3] = f4.w;
            } else {
                #pragma unroll
                for (int e = 0; e < 4; ++e) {
                    const int cin = cin0 + (e0 + e) / K2;
                    if (cin < D.CinW) v[e] = p[e];
                }
            }
        }
        unsigned pk = 0;
        #pragma unroll
        for (int e = 0; e < 4; ++e) pk |= ((unsigned)(wqi(v[e]) & 255)) << (e * 8);
        *(unsigned*)&sb[r * SSTR + e0] = pk;
    }
    __syncthreads();

    const int outN = K2 * 64;
    for (int idx = tid; idx < outN; idx += 256) {
        const int kpos = idx >> 6, lane = idx & 63;
        const int l15 = lane & 15, g = lane >> 4;
        unsigned wd[4] = {0u, 0u, 0u, 0u};
        #pragma unroll
        for (int e = 0; e < 16; ++e) {
            const unsigned bval = sb[l15 * SSTR + (g * 16 + e) * K2 + kpos];
            wd[e >> 2] |= bval << ((e & 3) * 8);
        }
        uint4 u; u.x = wd[0]; u.y = wd[1]; u.z = wd[2]; u.w = wd[3];
        for (int d = 0; d < D.ndup; ++d) {
            const int ch64 = ch64u + d * D.nch64u;
            D.dst[((size_t)((og * NCHT + ch64) * K2 + kpos) * D.gsz + ol) * 64 + lane] = u;
        }
    }
}

// ---------------- zero-fill of cat-buffer channel slices (decoder pad regions) ----------------
__global__ void __launch_bounds__(256) k_zfill(uint4* __restrict__ p, int npix, int stride_u4,
                                               int off_u4, int cnt, int total) {
    const int idx = blockIdx.x * 256 + threadIdx.x;
    if (idx >= total) return;
    const int pix = idx / cnt, j = idx - pix * cnt;
    uint4 z; z.x = z.y = z.z = z.w = 0u;
    p[(size_t)pix * stride_u4 + off_u4 + j] = z;
}

// ---------------- conv1: LDS-tiled f32 vector conv (exact chain), i8 out ----------------
__global__ void __launch_bounds__(256) k_conv1(const float* __restrict__ x, const float* __restrict__ w1,
                                               signed char* __restrict__ cat1) {
    __shared__ float sw2[36][64];
    __shared__ float sin_[4][17][17];
    const int tid = threadIdx.x;
    const int n = blockIdx.y;
    const int oh0 = (blockIdx.x >> 4) * 8, ow0 = (blockIdx.x & 15) * 8;
    for (int i = tid; i < 2304; i += 256) sw2[i % 36][i / 36] = wq8f(w1[i]);
    const int ih0 = oh0 * 2 - 1, iw0 = ow0 * 2 - 1;
    for (int i = tid; i < 4 * 289; i += 256) {
        const int c = i / 289, rem = i % 289, r = rem / 17, cc = rem % 17;
        const int ih = ih0 + r, iw = iw0 + cc;
        float v = 0.f;
        if ((unsigned)ih < 256u && (unsigned)iw < 256u) v = x[((size_t)(n * 4 + c) * 256 + ih) * 256 + iw];
        sin_[c][r][cc] = v;
    }
    __syncthreads();
    const int sp = tid & 63, ocg = tid >> 6;
    const int oh = sp >> 3, ow = sp & 7;
    float acc[16];
    #pragma unroll
    for (int j = 0; j < 16; ++j) acc[j] = 0.f;
    #pragma unroll
    for (int c = 0; c < 4; ++c)
    #pragma unroll
    for (int kh = 0; kh < 3; ++kh)
    #pragma unroll
    for (int kw = 0; kw < 3; ++kw) {
        const float v = sin_[c][oh * 2 + kh][ow * 2 + kw];
        const float4* wp4 = (const float4*)&sw2[c * 9 + kh * 3 + kw][ocg * 16];
        #pragma unroll
        for (int q = 0; q < 4; ++q) {
            const float4 wv = wp4[q];
            acc[q * 4 + 0] = fmaf(v, wv.x, acc[q * 4 + 0]);
            acc[q * 4 + 1] = fmaf(v, wv.y, acc[q * 4 + 1]);
            acc[q * 4 + 2] = fmaf(v, wv.z, acc[q * 4 + 2]);
            acc[q * 4 + 3] = fmaf(v, wv.w, acc[q * 4 + 3]);
        }
    }
    const size_t pix = ((size_t)(n * 128) + oh0 + oh) * 128 + ow0 + ow;
    unsigned wd[4] = {0u, 0u, 0u, 0u};
    #pragma unroll
    for (int j = 0; j < 16; ++j)
        wd[j >> 2] |= ((unsigned)(wqi(acc[j]) & 255)) << ((j & 3) * 8);
    uint4 u; u.x = wd[0]; u.y = wd[1]; u.z = wd[2]; u.w = wd[3];
    *(uint4*)(cat1 + pix * 112 + ocg * 16) = u;
}

// feat init: 0.0f is exact (omitted u10 outputs are identically wq8(0)=0)
__global__ void k_init(unsigned* __restrict__ feat, uint4* __restrict__ zbuf) {
    feat[threadIdx.x] = encf(0.0f);
    if (threadIdx.x < 64) { uint4 z; z.x = z.y = z.z = z.w = 0u; zbuf[threadIdx.x] = z; }
}

__global__ void k_fc(const unsigned* __restrict__ feat, const float* __restrict__ wfc,
                     float* __restrict__ out) {
    int n = threadIdx.x;
    if (n < 8) {
        float s = 0.f;
        for (int c = 0; c < 32; ++c) s += decf(feat[n * 32 + c]) * wq8f(wfc[c]);
        out[n] = wq8f(s);
    }
}

// ---------------- K-split partial combiner (D digits x G same-scale groups) ----------------
// Region-limited: pixels with oh outside [r0,r1] or ow outside [c0,c1] are skipped
// (their dst was zero-filled; their psum was never computed).
template<int CMODE>
__global__ void __launch_bounds__(256) k_comb(const int* __restrict__ ps, int D, int G,
                                              int NP, int OC, double inv,
                                              signed char* __restrict__ dst, int dstr, int dch,
                                              const void* __restrict__ res, int rstr,
                                              signed char* __restrict__ dhl, int dhlstr,
                                              short* __restrict__ dj,
                                              int ohw, int OWW, int r0, int r1, int c0, int c1) {
    const int t = blockIdx.x * 256 + threadIdx.x;
    const int opc = OC / 4;
    const int total = NP * opc;
    if (t >= total) return;
    const int pix = t / opc, oc0 = (t - pix * opc) * 4;
    const int sp = pix % ohw;
    const int oh = sp / OWW, ow = sp - oh * OWW;
    if (oh < r0 || oh > r1 || ow < c0 || ow > c1) return;
    const size_t base = (size_t)pix * OC + oc0;
    const size_t NPOC = (size_t)NP * OC;
    long v[4] = {0, 0, 0, 0};
    int sidx = 0;
    for (int d = 0; d < D; ++d) {
        long s0 = 0, s1 = 0, s2 = 0, s3 = 0;
        for (int g = 0; g < G; ++g, ++sidx) {
            const int4 p = *(const int4*)(ps + sidx * NPOC + base);
            s0 += p.x; s1 += p.y; s2 += p.z; s3 += p.w;
        }
        v[0] = v[0] * 256 + s0; v[1] = v[1] * 256 + s1;
        v[2] = v[2] * 256 + s2; v[3] = v[3] * 256 + s3;
    }
    if constexpr (CMODE == 0) {
        unsigned pk = 0;
        #pragma unroll
        for (int j = 0; j < 4; ++j)
            pk |= (unsigned)(wqi((float)((double)v[j] * inv)) & 255) << (j * 8);
        *(unsigned*)(dst + (size_t)pix * dstr + dch + oc0) = pk;
    } else {
        #pragma unroll
        for (int j = 0; j < 4; ++j) {
            const int qi = wqi((float)((double)v[j] * inv));
            const int oc = oc0 + j;
            if constexpr (CMODE == 1) {
                const int rv = (int)((const signed char*)res)[(size_t)pix * rstr + oc];
                const int jj = (128 - qi) * rv;
                const int d0 = ((jj + 128) & 255) - 128;
                const int t1 = (jj - d0) >> 8;
                dhl[(size_t)pix * dhlstr + oc] = (signed char)t1;
                dhl[(size_t)pix * dhlstr + 512 + oc] = (signed char)d0;
                dj[(size_t)pix * 512 + oc] = (short)jj;
            } else {
                const int rv = (int)((const short*)res)[(size_t)pix * rstr + oc];
                const int jj = (128 - qi) * rv;
                const int d0 = ((jj + 128) & 255) - 128;
                const int t1 = (jj - d0) >> 8;
                const int d1 = ((t1 + 128) & 255) - 128;
                const int d2 = (t1 - d1) >> 8;
                dhl[(size_t)pix * dhlstr + oc] = (signed char)d2;
                dhl[(size_t)pix * dhlstr + 512 + oc] = (signed char)d1;
                dhl[(size_t)pix * dhlstr + 1024 + oc] = (signed char)d0;
            }
        }
    }
}

// ---------------- implicit-GEMM i8 MFMA conv ----------------
// Tile origin offset (ohb,owb) restricts computation to the nonzero output region
// of pad-heavy decoder convs (outputs elsewhere are exactly 0 and pre-zero-filled).
template<int K, int STR, int WM, int WN, int BN, int CHQ, int NBUF, int MODE>
__global__ void __launch_bounds__(256) k_mconv(
    const signed char* __restrict__ s0, int Ctot, int st0,
    int S, int padeff,
    const uint4* __restrict__ wqp, int nchtot,
    signed char* __restrict__ dst, int dstr, int dch,
    unsigned* __restrict__ feat, int* __restrict__ ps,
    const signed char* __restrict__ zbuf,
    int OCv, int OH, int OW, int TILES_W, int nch,
    int NT, int NOCG, int swzq, int ORD, int ohb, int owb)
{
    constexpr int TH = WM * 4;
    constexpr int RH = (TH - 1) * STR + K, RW = 7 * STR + K;
    constexpr int UNITS = CHQ / 16;
    constexpr int UPPS = UNITS + 1;
    constexpr int NKC = CHQ / 64;
    constexpr int K2 = K * K;
    constexpr int NUS = RH * RW * UPPS;
    constexpr int ROUNDS = (NUS + 255) / 256;
    constexpr int NUPS = ROUNDS * 256;
    constexpr int AHEAD = NBUF - 1;
    __shared__ uint4 lds[NBUF * NUPS];
    __shared__ int sred[4][2][16];

    const int tid = threadIdx.x, lane = tid & 63, w = tid >> 6;
    const int wm = w % WM, wn = w / WM;
    const int l15 = lane & 15, g = lane >> 4;

    const int b = blockIdx.x;
    const int work = (b & 7) * swzq + (b >> 3);
    int tile, n, ocg, slice;
    if (ORD == 0) {
        ocg = work % NOCG; const int t2 = work / NOCG;
        tile = t2 % NT; const int t3 = t2 / NT;
        n = t3 & 7; slice = t3 >> 3;
    } else {
        tile = work % NT; const int t2 = work / NT;
        n = t2 & 7; const int t3 = t2 >> 3;
        ocg = t3 % NOCG; slice = t3 / NOCG;
    }
    const int cin_off = slice * nch * CHQ;
    const int group = ocg * WN + wn;

    const int tileh = tile / TILES_W, tilew = tile % TILES_W;
    const int oh0 = ohb + tileh * TH, ow0 = owb + tilew * 8;
    const int ih0 = oh0 * STR - padeff, iw0 = ow0 * STR - padeff;
    const int blk_oct0 = ocg * (WN * BN);

    int pixb[2];
    #pragma unroll
    for (int am = 0; am < 2; ++am) {
        const int sp = wm * 32 + am * 16 + l15;
        pixb[am] = ((sp >> 3) * STR) * RW + (sp & 7) * STR;
    }

    // hoisted staging addresses: per-rd base pointer + channel-limit
    int climit[ROUNDS];
    const signed char* gpb[ROUNDS];
    #pragma unroll
    for (int rd = 0; rd < ROUNDS; ++rd) {
        const int d = rd * 256 + tid;
        int cl = -1;
        const signed char* gb = zbuf;
        if (d < NUS) {
            const int pix = d / UPPS;
            const int u = d - pix * UPPS;
            const int r = pix / RW, c = pix - r * RW;
            const int ih = ih0 + r, iw = iw0 + c;
            if (u < UNITS && (unsigned)ih < (unsigned)S && (unsigned)iw < (unsigned)S) {
                cl = Ctot - cin_off - u * 16;
                gb = s0 + (((size_t)n * S + ih) * S + iw) * st0 + cin_off + u * 16;
            }
        }
        climit[rd] = cl; gpb[rd] = gb;
    }

    i32x4 acc[2][BN];
    #pragma unroll
    for (int am = 0; am < 2; ++am)
        #pragma unroll
        for (int bn = 0; bn < BN; ++bn) acc[am][bn] = (i32x4){0, 0, 0, 0};

    auto issue = [&](int ch, int buf) {
        uint4* lb = &lds[buf * NUPS];
        const int chv = ch * CHQ;
        #pragma unroll
        for (int rd = 0; rd < ROUNDS; ++rd) {
            const signed char* gp = (chv < climit[rd]) ? (gpb[rd] + chv) : zbuf;
            GLOAD16(gp, lb + rd * 256 + (tid & ~63));
        }
    };

    #pragma unroll
    for (int i = 0; i < AHEAD; ++i) if (i < nch) issue(i, i % NBUF);

    for (int ch = 0; ch < nch; ++ch) {
        if (ch + AHEAD < nch) issue(ch + AHEAD, (ch + AHEAD) % NBUF);
        const int infl = (nch - 1 - ch < AHEAD) ? nch - 1 - ch : AHEAD;
        if (infl >= 2)      __builtin_amdgcn_s_waitcnt(0xF70 | (2 * ROUNDS));
        else if (infl == 1) __builtin_amdgcn_s_waitcnt(0xF70 | ROUNDS);
        else                __builtin_amdgcn_s_waitcnt(0xF70);
        __builtin_amdgcn_s_barrier();
        __builtin_amdgcn_sched_barrier(0);
        const int bufo = (ch % NBUF) * NUPS;
        const int pb0 = bufo + pixb[0] * UPPS + g;
        const int pb1 = bufo + pixb[1] * UPPS + g;
        const uint4* wrow = wqp + ((size_t)(group * nchtot + (slice * nch + ch) * NKC) * K2 * BN) * 64 + lane;
        #pragma unroll
        for (int kpos = 0; kpos < K2; ++kpos) {
            const int kh = kpos / K, kw = kpos % K;
            const int po = (kh * RW + kw) * UPPS;
            #pragma unroll
            for (int kc = 0; kc < NKC; ++kc) {
                i32x4 bfr[BN];
                #pragma unroll
                for (int bn = 0; bn < BN; ++bn) {
                    union { uint4 u; i32x4 v; } bu;
                    bu.u = wrow[(kc * K2 * BN + kpos * BN + bn) * 64];
                    bfr[bn] = bu.v;
                }
                union { uint4 u; i32x4 v; } a0, a1;
                a0.u = lds[pb0 + po + kc * 4];
                a1.u = lds[pb1 + po + kc * 4];
                #pragma unroll
                for (int bn = 0; bn < BN; ++bn) {
                    acc[0][bn] = __builtin_amdgcn_mfma_i32_16x16x64_i8(a0.v, bfr[bn], acc[0][bn], 0, 0, 0);
                    acc[1][bn] = __builtin_amdgcn_mfma_i32_16x16x64_i8(a1.v, bfr[bn], acc[1][bn], 0, 0, 0);
                }
            }
        }
        __builtin_amdgcn_sched_barrier(0);
        __builtin_amdgcn_s_barrier();
    }

    if constexpr (MODE == 2) {
        #pragma unroll
        for (int bn = 0; bn < BN; ++bn) {
            int m = (int)0x80000000;
            #pragma unroll
            for (int am = 0; am < 2; ++am)
                #pragma unroll
                for (int rg = 0; rg < 4; ++rg) {
                    const int sp = wm * 32 + am * 16 + g * 4 + rg;
                    const int oh = oh0 + (sp >> 3), ow = ow0 + (sp & 7);
                    const int v = acc[am][bn][rg];
                    if (oh < OH && ow < OW && v > m) m = v;
                }
            int o = __shfl_xor(m, 16); if (o > m) m = o;
            o = __shfl_xor(m, 32); if (o > m) m = o;
            if (lane < 16) sred[w][bn][l15] = m;
        }
        __syncthreads();
        if (tid < BN * 16) {
            const int bn = tid >> 4, l = tid & 15;
            int mm = sred[0][bn][l];
            #pragma unroll
            for (int i = 1; i < WM * WN; ++i) { const int o = sred[i][bn][l]; if (o > mm) mm = o; }
            const float y = (float)mm * (1.f / 16384.f);
            const float v = (float)wqi(y) * 0.0078125f;
            atomicMax(&feat[n * 32 + (blk_oct0 + bn) * 16 + l], encf(v));
        }
    } else if constexpr (MODE == 3) {
        #pragma unroll
        for (int am = 0; am < 2; ++am)
        #pragma unroll
        for (int bn = 0; bn < BN; ++bn)
        #pragma unroll
        for (int rg = 0; rg < 4; ++rg) {
            const int sp = wm * 32 + am * 16 + g * 4 + rg;
            const int oh = oh0 + (sp >> 3), ow = ow0 + (sp & 7);
            const int oc = (blk_oct0 + wn * BN + bn) * 16 + l15;
            if (oh < OH && ow < OW && oc < OCv) {
                ps[(((size_t)slice * 8 + n) * OH * OW + (size_t)oh * OW + ow) * OCv + oc] = acc[am][bn][rg];
            }
        }
    } else {
        #pragma unroll
        for (int am = 0; am < 2; ++am)
        #pragma unroll
        for (int bn = 0; bn < BN; ++bn)
        #pragma unroll
        for (int rg = 0; rg < 4; ++rg) {
            const int sp = wm * 32 + am * 16 + g * 4 + rg;
            const int oh = oh0 + (sp >> 3), ow = ow0 + (sp & 7);
            const int oc = (blk_oct0 + wn * BN + bn) * 16 + l15;
            if (oh < OH && ow < OW && oc < OCv) {
                const size_t pixo = (size_t)(n * OH + oh) * OW + ow;
                const float y = (float)acc[am][bn][rg] * (1.f / 16384.f);
                dst[pixo * dstr + dch + oc] = (signed char)wqi(y);
            }
        }
    }
}

extern "C" void kernel_launch(void* const* d_in, const int* in_sizes, int n_in,
                              void* d_out, int out_size, void* d_ws, size_t ws_size,
                              hipStream_t stream)
{
    (void)in_sizes; (void)n_in; (void)out_size; (void)ws_size;
    const float* x = (const float*)d_in[0];
    const float* wfc = (const float*)d_in[16];
    float* out = (float*)d_out;

    char* ws = (char*)d_ws;
    size_t off = 0;
    auto alloc = [&](size_t bytes) { char* p = ws + off; off += (bytes + 255) & ~(size_t)255; return p; };

    // {w0 idx, OC0, w1 idx, OC1, CinW, K, noct, nch64u, ndup, gsz(=BN)}
    struct PH { int i0, OC0, i1, OC1, CinW, K, noct, nch64u, ndup, gsz; };
    static const PH ph[11] = {
        {2, 128, -1, 0,  64, 3,  8, 1, 1, 2},   // 0 conv2
        {3, 256, -1, 0, 128, 3, 16, 2, 1, 2},   // 1 conv3
        {4, 512, -1, 0, 256, 3, 32, 4, 1, 2},   // 2 conv4
        {5, 512, -1, 0, 512, 3, 32, 8, 1, 2},   // 3 r11
        {6, 512, -1, 0, 512, 3, 32, 8, 1, 2},   // 4 r12
        {7, 512, -1, 0, 512, 3, 32, 8, 2, 2},   // 5 r21 (2 digit copies)
        {8, 512, -1, 0, 512, 3, 32, 8, 1, 2},   // 6 r22
        {9, 128, 12, 32, 512, 4, 10, 8, 3, 2},  // 7 L3 = wd3|wu43 (3 digit copies)
        {10, 64, 13, 32, 416, 4,  6, 7, 1, 2},  // 8 L2 = wd2|wu32
        {11,  4, 14, 32, 224, 4,  3, 4, 1, 3},  // 9 L1 = wd1|wu21 (+12 zero oc)
        {15, 32, -1, 0, 100, 4,  2, 2, 1, 2}};  // 10 u10

    PackArgs pa;
    int bacc = 0;
    uint4* wp[11];
    for (int i = 0; i < 11; ++i) {
        const int nch64 = ph[i].nch64u * ph[i].ndup;
        const int nel = nch64 * ph[i].K * ph[i].K * ph[i].noct * 64;
        wp[i] = (uint4*)alloc((size_t)nel * 16);
        pa.d[i].w0 = (const float*)d_in[ph[i].i0];
        pa.d[i].w1 = (ph[i].i1 >= 0) ? (const float*)d_in[ph[i].i1] : nullptr;
        pa.d[i].dst = wp[i];
        pa.d[i].OC0 = ph[i].OC0; pa.d[i].OC1 = ph[i].OC1;
        pa.d[i].CinW = ph[i].CinW; pa.d[i].K = ph[i].K; pa.d[i].noct = ph[i].noct;
        pa.d[i].nch64u = ph[i].nch64u; pa.d[i].ndup = ph[i].ndup;
        pa.d[i].gsz = ph[i].gsz;
        pa.bofs[i] = bacc;
        bacc += ph[i].noct * ph[i].nch64u;
    }
    pa.bofs[11] = bacc;

    signed char* cat1b = (signed char*)alloc((size_t)8*128*128*112);  // c1|d1|f2|pad12
    signed char* cat2b = (signed char*)alloc((size_t)8*64*64*224);    // c2|d2|f3
    signed char* cat3b = (signed char*)alloc((size_t)8*32*32*416);    // c3|d3|f4
    signed char* c4b   = (signed char*)alloc((size_t)8*16*16*512);
    signed char* r11b  = (signed char*)alloc((size_t)8*16*16*512);    // also r21 out
    signed char* r12d  = (signed char*)alloc((size_t)8*16*16*1024);   // r12 digits hi|lo
    short*       r12j  = (short*)alloc((size_t)8*16*16*512 * 2);      // r12 as i16 j (gate res)
    signed char* r22d  = (signed char*)alloc((size_t)8*16*16*1536);   // r22 digits j2|j1|j0
    int*         psum  = (int*)alloc((size_t)4*8*16*16*512 * 4);      // K-split partials (~17MB)
    unsigned*    featb = (unsigned*)alloc(256 * 4);
    uint4*       zbuf  = (uint4*)alloc(1024);

    k_packall<<<dim3((unsigned)bacc), dim3(256), 0, stream>>>(pa);
    k_init<<<dim3(1), dim3(256), 0, stream>>>(featb, zbuf);
    // zero-fill decoder output slices (outputs there are exactly 0)
    k_zfill<<<dim3((131072*3 + 255)/256), 256, 0, stream>>>((uint4*)cat1b, 131072, 7, 4, 3, 131072*3);
    k_zfill<<<dim3((32768*6 + 255)/256), 256, 0, stream>>>((uint4*)cat2b, 32768, 14, 8, 6, 32768*6);
    k_zfill<<<dim3((8192*10 + 255)/256), 256, 0, stream>>>((uint4*)cat3b, 8192, 26, 16, 10, 8192*10);
    k_conv1<<<dim3(256, 8), dim3(256), 0, stream>>>(x, (const float*)d_in[1], cat1b);

    const signed char* zb = (const signed char*)zbuf;
    const void* nv = nullptr;
    const int BIG = 1 << 30;

    // conv2: cat1 ch0..64 -> cat2 ch0..128   NT=64 NOCG=2 total=1024  ORD0
    k_mconv<3,2,2,2,2,64,1,0><<<dim3(1024), 256, 0, stream>>>(
        cat1b,64,112, 128,1, wp[0],1, cat2b,224,0, nullptr,nullptr, zb,
        128,64,64,8, 1, 64,2,128, 0, 0,0);
    // conv3: cat2 -> cat3 ch0..256           NT=16 NOCG=4 total=512  ORD0
    k_mconv<3,2,2,2,2,64,2,0><<<dim3(512), 256, 0, stream>>>(
        cat2b,128,224, 64,1, wp[1],2, cat3b,416,0, nullptr,nullptr, zb,
        256,32,32,4, 2, 16,4,64, 0, 0,0);
    // conv4 -> psum (4-way K-split, BN2)     NT=4 NOCG=8 NSLC=4 total=1024  ORD1
    k_mconv<3,2,2,2,2,64,1,3><<<dim3(1024), 256, 0, stream>>>(
        cat3b,256,416, 32,1, wp[2],4, nullptr,0,0, nullptr,(int*)psum, zb,
        512,16,16,2, 1, 4,8,128, 1, 0,0);
    k_comb<0><<<dim3(1024), 256, 0, stream>>>(psum,1,4, 2048,512, 1.0/16384.0, c4b,512,0, nv,0, nullptr,0,nullptr,
        256,16, 0,BIG,0,BIG);
    // r11 (WM4, BN2, 4-way K-split, one-shot CHQ128)  NT=2 NOCG=16 NSLC=4 total=1024  ORD1
    k_mconv<3,1,4,1,2,128,1,3><<<dim3(1024), 256, 0, stream>>>(
        c4b,512,512, 16,1, wp[3],8, nullptr,0,0, nullptr,psum, zb,
        512,16,16,2, 1, 2,16,128, 1, 0,0);
    k_comb<0><<<dim3(1024), 256, 0, stream>>>(psum,1,4, 2048,512, 1.0/16384.0, r11b,512,0, nv,0, nullptr,0,nullptr,
        256,16, 0,BIG,0,BIG);
    // r12 conv -> psum (2-way), gate in comb
    k_mconv<3,1,4,1,2,64,3,3><<<dim3(512), 256, 0, stream>>>(
        r11b,512,512, 16,1, wp[4],8, nullptr,0,0, nullptr,psum, zb,
        512,16,16,2, 4, 2,16,64, 1, 0,0);
    k_comb<1><<<dim3(1024), 256, 0, stream>>>(psum,1,2, 2048,512, 1.0/16384.0, nullptr,0,0, c4b,512, r12d,1024,r12j,
        256,16, 0,BIG,0,BIG);
    // r21: digits input, 4 slices = 2 digits x 2
    k_mconv<3,1,4,1,2,64,2,3><<<dim3(1024), 256, 0, stream>>>(
        r12d,1024,1024, 16,1, wp[5],16, nullptr,0,0, nullptr,psum, zb,
        512,16,16,2, 4, 2,16,128, 1, 0,0);
    k_comb<0><<<dim3(1024), 256, 0, stream>>>(psum,2,2, 2048,512, 1.0/2097152.0, r11b,512,0, nv,0, nullptr,0,nullptr,
        256,16, 0,BIG,0,BIG);
    // r22 conv -> psum (2-way), gate in comb (3 digits)
    k_mconv<3,1,4,1,2,64,3,3><<<dim3(512), 256, 0, stream>>>(
        r11b,512,512, 16,1, wp[6],8, nullptr,0,0, nullptr,psum, zb,
        512,16,16,2, 4, 2,16,64, 1, 0,0);
    k_comb<2><<<dim3(1024), 256, 0, stream>>>(psum,1,2, 2048,512, 1.0/16384.0, nullptr,0,0, r12j,512, r22d,1536,nullptr,
        256,16, 0,BIG,0,BIG);
    // L3: [d3|f4], region oh,ow in [7,25]: NT=6 (2x3), TILES_W=3, origin (7,7)
    // grid = 6*5*3*8 = 720, swzq=90
    k_mconv<4,1,4,1,2,64,2,3><<<dim3(720), 256, 0, stream>>>(
        r22d,1536,1536, 16,10, wp[7],24, nullptr,0,0, nullptr,psum, zb,
        160,32,32,3, 8, 6,5,90, 1, 7,7);
    k_comb<0><<<dim3(1280), 256, 0, stream>>>(psum,3,1, 8192,160, 1.0/268435456.0, cat3b,416,256, nv,0, nullptr,0,nullptr,
        1024,32, 7,25,7,25);
    // L2: [d2|f3], region [15,49]: NT=15 (3x5), TILES_W=5, origin (15,15)
    // grid = 15*3*8 = 360, swzq=45
    k_mconv<4,1,4,1,2,64,2,0><<<dim3(360), 256, 0, stream>>>(
        cat3b,416,416, 32,18, wp[8],7, cat2b,224,128, nullptr,nullptr, zb,
        96,64,64,5, 7, 15,3,45, 0, 15,15);
    // L1: [d1|f2|pad], region [31,97]: NT=45 (5x9), TILES_W=9, origin (31,31)
    // grid = 45*1*8 = 360, swzq=45
    k_mconv<4,1,4,1,3,64,2,0><<<dim3(360), 256, 0, stream>>>(
        cat2b,224,224, 64,34, wp[9],4, cat1b,112,64, nullptr,nullptr, zb,
        48,128,128,9, 4, 45,1,45, 0, 31,31);
    // u10 + fused global max-pool, region [63,197]: NT=153 (9x17), TILES_W=17, origin (63,63)
    // grid = 153*8 = 1224, swzq=153
    k_mconv<4,1,4,1,2,128,1,2><<<dim3(1224), 256, 0, stream>>>(
        cat1b,112,112, 128,66, wp[10],2, nullptr,0,0, featb,nullptr, zb,
        32,257,257,17, 1, 153,1,153, 0, 63,63);
    // FC
    k_fc<<<dim3(1), dim3(64), 0, stream>>>(featb, wfc, out);
}